// Round 4
// baseline (2031.262 us; speedup 1.0000x reference)
//
#include <hip/hip_runtime.h>
#include <math.h>

#define NIx 32
#define NOx 2
#define NUx 10
#define NHx 1024
#define NBx 16384
#define MIx 138
#define EPSQ 1e-4f
#define BNEPS 1e-5f
#define ITERS 30
#define SLOPE 0.2f
#define SIGMA_C 0.1f

// workspace layout (float offsets)
#define QM_OFF 0       // 10 rows x 12 (padded)
#define G_OFF 128      // 144 rows x 12 (padded, zero pad rows/cols)
#define H_OFF 1856     // 144
#define A1_OFF 2048    // 1024
#define C1_OFF 3072    // 1024
#define B2P_OFF 4096   // 10 (pad to 4112)
#define S1_OFF 4112    // 1024
#define SQ1_OFF 5136   // 1024
#define S2_OFF 6160    // 10 (pad 16)
#define SQ2_OFF 6176   // 10 (pad to 6208)
#define PRAW_OFF 6208  // 16384*10
#define ZERO_LEN (6208 - S1_OFF)

__device__ __forceinline__ float frcp(float x){ return __builtin_amdgcn_rcpf(x); }
__device__ __forceinline__ float frsq(float x){ return __builtin_amdgcn_rsqf(x); }
__device__ __forceinline__ float lrelu(float x){ return x > 0.0f ? x : SLOPE * x; }

// ---- DPP 16-lane reductions (VALU, no LDS pipe) ----
// xor1 = quad_perm[1,0,3,2] (0xB1), xor2 = quad_perm[2,3,0,1] (0x4E),
// then row_ror:4 (0x124) + row_ror:8 (0x128) complete the 16-lane all-reduce.
template<int CTRL>
__device__ __forceinline__ float dpp_mov(float x){
    int y = __builtin_amdgcn_update_dpp(0, __float_as_int(x), CTRL, 0xF, 0xF, true);
    return __int_as_float(y);
}
__device__ __forceinline__ float red16_add(float x){
    x += dpp_mov<0xB1>(x);
    x += dpp_mov<0x4E>(x);
    x += dpp_mov<0x124>(x);
    x += dpp_mov<0x128>(x);
    return x;
}
__device__ __forceinline__ float red16_min(float x){
    x = fminf(x, dpp_mov<0xB1>(x));
    x = fminf(x, dpp_mov<0x4E>(x));
    x = fminf(x, dpp_mov<0x124>(x));
    x = fminf(x, dpp_mov<0x128>(x));
    return x;
}

// ---------- build Q_hat, G, h (one block); also zeroes the stats accumulators ----------
__global__ __launch_bounds__(256) void k_build(const float* L, const float* LP, const float* LR,
                                               const float* A, const float* Bm,
                                               const float* u0, const float* s0, float* ws){
    __shared__ float sL[1024], sLP[1024], sA[1024], sQ[1024], sP[1024];
    __shared__ float sPow[4][64];   // [power][i*2+c]
    __shared__ float sBh[128*10];
    __shared__ float sQB[128*10];
    __shared__ float sR[3];
    int t = threadIdx.x;
    for (int idx = t; idx < ZERO_LEN; idx += 256) ws[S1_OFF + idx] = 0.0f;  // stats zero (was k_zero)
    for (int idx = t; idx < 1024; idx += 256){
        int i = idx >> 5, j = idx & 31;
        sL[idx]  = (j <= i) ? L[idx]  : 0.0f;
        sLP[idx] = (j <= i) ? LP[idx] : 0.0f;
        sA[idx]  = A[idx];
    }
    if (t < 64) sPow[0][t] = Bm[t];
    if (t == 0){
        float a = LR[0], b = LR[2], c = LR[3];   // tril: [[a,0],[b,c]]
        sR[0] = a*a + EPSQ; sR[1] = a*b; sR[2] = b*b + c*c + EPSQ;
    }
    __syncthreads();
    for (int idx = t; idx < 1024; idx += 256){
        int i = idx >> 5, j = idx & 31;
        float q = 0.0f, p = 0.0f;
        for (int k = 0; k < 32; ++k){
            q = fmaf(sL[i*32+k],  sL[j*32+k],  q);
            p = fmaf(sLP[i*32+k], sLP[j*32+k], p);
        }
        if (i == j){ q += EPSQ; p += EPSQ; }
        sQ[idx] = q; sP[idx] = p;
    }
    for (int kp = 1; kp < 4; ++kp){
        __syncthreads();
        if (t < 64){
            int i = t >> 1, c = t & 1;
            float a = 0.0f;
            for (int j = 0; j < 32; ++j) a = fmaf(sA[i*32+j], sPow[kp-1][j*2+c], a);
            sPow[kp][t] = a;
        }
    }
    __syncthreads();
    for (int idx = t; idx < 1280; idx += 256){
        int r = idx / 10, c = idx % 10;
        int bi = r >> 5, ri = r & 31, bj = c >> 1, cj = c & 1;
        sBh[idx] = (bj <= bi) ? sPow[bi-bj][ri*2+cj] : 0.0f;
    }
    __syncthreads();
    for (int idx = t; idx < 1280; idx += 256){
        int r = idx / 10, c = idx % 10;
        int bi = r >> 5, ri = r & 31;
        const float* Qd = (bi < 3) ? sQ : sP;
        float a = 0.0f;
        for (int k = 0; k < 32; ++k) a = fmaf(Qd[ri*32+k], sBh[(bi*32+k)*10+c], a);
        sQB[idx] = a;
    }
    __syncthreads();
    if (t < 120){
        int i = t / 12, j = t % 12;
        float a = 0.0f;
        if (j < 10){
            for (int r = 0; r < 128; ++r) a = fmaf(sBh[r*10+i], sQB[r*10+j], a);
            if ((i >> 1) == (j >> 1)) a += sR[(i&1)+(j&1)];
        }
        ws[QM_OFF + t] = a;
    }
    for (int idx = t; idx < 144*12; idx += 256){
        int m = idx / 12, i = idx % 12;
        float v = 0.0f;
        if (i < 10 && m < MIx) v = (m < 10) ? ((i == m) ? 1.0f : 0.0f) : sBh[(m-10)*10 + i];
        ws[G_OFF + idx] = v;
    }
    for (int m = t; m < 144; m += 256){
        float hv = 0.0f;
        if (m < MIx){
            hv = s0[m];
            if (m < 10) hv += u0[m];
            else { for (int i = 0; i < 10; ++i) hv = fmaf(sBh[(m-10)*10+i], u0[i], hv); }
        }
        ws[H_OFF + m] = hv;
    }
}

// ---------- BN1 stats: h1 = lrelu(x@W1^T + b1), accumulate per-col sum/sumsq ----------
__global__ __launch_bounds__(256) void k_stats1(const float* x, const float* w1, const float* b1, float* ws){
    __shared__ float xs[256*32];
    int t = threadIdx.x;
    int rb = blockIdx.x >> 2;
    int cb = blockIdx.x & 3;
    int r0 = rb * 256;
    int c = cb * 256 + t;
    const float4* xg4 = (const float4*)(x + (size_t)r0 * 32);
    float4* xs4 = (float4*)xs;
    for (int i = t; i < 2048; i += 256) xs4[i] = xg4[i];
    const float4* wg4 = (const float4*)(w1 + (size_t)c * 32);
    float4 wr[8];
    #pragma unroll
    for (int q = 0; q < 8; ++q) wr[q] = wg4[q];
    float bc = b1[c];
    __syncthreads();
    const float4* xr4 = (const float4*)xs;
    float sum = 0.0f, sq = 0.0f;
    for (int r = 0; r < 256; ++r){
        float a0 = 0, a1 = 0, a2 = 0, a3 = 0;
        #pragma unroll
        for (int q = 0; q < 8; ++q){
            float4 v = xr4[r*8 + q];
            a0 = fmaf(v.x, wr[q].x, a0);
            a1 = fmaf(v.y, wr[q].y, a1);
            a2 = fmaf(v.z, wr[q].z, a2);
            a3 = fmaf(v.w, wr[q].w, a3);
        }
        float h = lrelu((a0 + a1) + (a2 + a3) + bc);
        sum += h; sq = fmaf(h, h, sq);
    }
    atomicAdd(&ws[S1_OFF + c], sum);
    atomicAdd(&ws[SQ1_OFF + c], sq);
}

// ---------- finalize BN1 affine + fold into fc2 bias ----------
__global__ __launch_bounds__(256) void k_fin1(const float* g1, const float* bb1,
                                              const float* w2, const float* b2, float* ws){
    int t = threadIdx.x;
    for (int k = t; k < 1024; k += 256){
        float mu  = ws[S1_OFF + k] * (1.0f/16384.0f);
        float var = ws[SQ1_OFF + k] * (1.0f/16384.0f) - mu*mu;
        float a1 = g1[k] / sqrtf(var + BNEPS);
        ws[A1_OFF + k] = a1;
        ws[C1_OFF + k] = bb1[k] - mu * a1;
    }
    __syncthreads();
    if (t < 10){
        float a = b2[t];
        for (int k = 0; k < 1024; ++k) a = fmaf(ws[C1_OFF + k], w2[t*1024 + k], a);
        ws[B2P_OFF + t] = a;
    }
}

// ---------- fc2: p_raw = lrelu((h1*a1)@W2^T + b2'), + BN2 stats ----------
__global__ __launch_bounds__(256) void k_fc2(const float* x, const float* w1, const float* b1,
                                             const float* w2, float* ws){
    __shared__ float ws1[128*32];     // W1 chunk [kl][c]
    __shared__ float w2t[128*12];     // W2 chunk transposed, padded to 12
    __shared__ float sab[128*2];      // (a1, b1) per kl
    int t = threadIdx.x;
    int r0 = blockIdx.x * 64;
    int r = t & 63;
    int q = t >> 6;                   // wave id: k-quarter
    const float4* xg4 = (const float4*)(x + (size_t)(r0 + r) * 32);
    float4 xr[8];
    #pragma unroll
    for (int i = 0; i < 8; ++i) xr[i] = xg4[i];
    float acc[10];
    #pragma unroll
    for (int j = 0; j < 10; ++j) acc[j] = 0.0f;

    for (int kc = 0; kc < 1024; kc += 128){
        __syncthreads();
        const float4* w1g = (const float4*)(w1 + (size_t)kc * 32);
        float4* ws14 = (float4*)ws1;
        for (int i = t; i < 1024; i += 256) ws14[i] = w1g[i];
        for (int i = t; i < 1280; i += 256){
            int kl = i & 127, j = i >> 7;
            w2t[kl*12 + j] = w2[j*1024 + kc + kl];
        }
        if (t < 256){ int kl = t >> 1, j = 10 + (t & 1); w2t[kl*12 + j] = 0.0f; }
        if (t < 128){ sab[t*2] = ws[A1_OFF + kc + t]; sab[t*2+1] = b1[kc + t]; }
        __syncthreads();
        const float4* w1r = (const float4*)ws1;
        const float4* w2r = (const float4*)w2t;
        const float2* abr = (const float2*)sab;
        #pragma unroll 4
        for (int kk = 0; kk < 32; ++kk){
            int kl = q*32 + kk;
            float a0 = 0, a1 = 0, a2 = 0, a3 = 0;
            #pragma unroll
            for (int qq = 0; qq < 8; ++qq){
                float4 wv = w1r[kl*8 + qq];
                float4 xv = xr[qq];
                a0 = fmaf(xv.x, wv.x, a0);
                a1 = fmaf(xv.y, wv.y, a1);
                a2 = fmaf(xv.z, wv.z, a2);
                a3 = fmaf(xv.w, wv.w, a3);
            }
            float2 ab = abr[kl];
            float h = lrelu((a0 + a1) + (a2 + a3) + ab.y) * ab.x;
            float4 wa = w2r[kl*3+0], wb = w2r[kl*3+1], wc = w2r[kl*3+2];
            acc[0] = fmaf(h, wa.x, acc[0]); acc[1] = fmaf(h, wa.y, acc[1]);
            acc[2] = fmaf(h, wa.z, acc[2]); acc[3] = fmaf(h, wa.w, acc[3]);
            acc[4] = fmaf(h, wb.x, acc[4]); acc[5] = fmaf(h, wb.y, acc[5]);
            acc[6] = fmaf(h, wb.z, acc[6]); acc[7] = fmaf(h, wb.w, acc[7]);
            acc[8] = fmaf(h, wc.x, acc[8]); acc[9] = fmaf(h, wc.y, acc[9]);
        }
    }
    __syncthreads();
    float* pacc = ws1;   // reuse LDS
    #pragma unroll
    for (int j = 0; j < 10; ++j) pacc[(q*64 + r)*10 + j] = acc[j];
    __syncthreads();
    if (t < 64){
        float pv[10];
        #pragma unroll
        for (int j = 0; j < 10; ++j){
            float a = ws[B2P_OFF + j];
            a += pacc[t*10+j] + pacc[(64+t)*10+j] + pacc[(128+t)*10+j] + pacc[(192+t)*10+j];
            pv[j] = lrelu(a);
        }
        #pragma unroll
        for (int j = 0; j < 10; ++j) ws[PRAW_OFF + (size_t)(r0 + t)*10 + j] = pv[j];
        float sv[10], qv[10];
        #pragma unroll
        for (int j = 0; j < 10; ++j){ sv[j] = pv[j]; qv[j] = pv[j]*pv[j]; }
        #pragma unroll
        for (int m = 1; m < 64; m <<= 1){
            #pragma unroll
            for (int j = 0; j < 10; ++j){
                sv[j] += __shfl_xor(sv[j], m);
                qv[j] += __shfl_xor(qv[j], m);
            }
        }
        if (t == 0){
            #pragma unroll
            for (int j = 0; j < 10; ++j){
                atomicAdd(&ws[S2_OFF + j], sv[j]);
                atomicAdd(&ws[SQ2_OFF + j], qv[j]);
            }
        }
    }
}

// ---------- batched IPM, sparsity-aware, 64-thread single-wave blocks ----------
// 16 lanes/element, 4 elements/block. Slot k=0..7: B_hat row 10+16k+lg, col bound
// 2*(k/2+1) (compile-time). Slot 8: identity row lg (lanes 0..9), analytic.
// G rows in registers (40 floats, loaded once). pv + h in LDS (register relief:
// round-3 VGPR=188 -> 2 waves/SIMD; target <=170 for 3 waves/SIMD).
#define TIX(i,j) ((i)*((i)+1)/2 + (j))

#define STEPA(K, B, g) { \
    float sk = s[K], lk = lam[K]; \
    float r = sk - hhp[(K)*16]; \
    float w = lk * frcp(sk); \
    sl = fmaf(sk, lk, sl); \
    _Pragma("unroll") \
    for (int i = 0; i < B; ++i){ \
        lamG[i] = fmaf(lk, g[i], lamG[i]); \
        r = fmaf(z[i], g[i], r); \
    } \
    rp[K] = r; \
    _Pragma("unroll") \
    for (int i = 0; i < B; ++i){ \
        float wgi = w * g[i]; \
        _Pragma("unroll") \
        for (int j = 0; j <= i; ++j) Hm[TIX(i,j)] = fmaf(wgi, g[j], Hm[TIX(i,j)]); \
    } }

#define STEPB(K, B, g) { \
    float sk = s[K], lk = lam[K]; \
    float isk = frcp(sk); \
    float rc = fmaf(sk, lk, -smu); \
    float coef = isk * fmaf(lk, rp[K], -rc); \
    _Pragma("unroll") \
    for (int i = 0; i < B; ++i) racc[i] = fmaf(coef, g[i], racc[i]); }

#define STEPC(K, B, g) { \
    float dot = 0.0f; \
    _Pragma("unroll") \
    for (int i = 0; i < B; ++i) dot = fmaf(dz[i], g[i], dot); \
    float dsk = -rp[K] - dot; \
    float sk = s[K], lk = lam[K]; \
    float isk = frcp(sk); \
    float rc = fmaf(sk, lk, -smu); \
    float dlk = -(rc + lk * dsk) * isk; \
    ds_[K] = dsk; dl_[K] = dlk; \
    float r1 = (dsk < 0.0f) ? sk * frcp(-dsk) : 3.0e38f; \
    float r2 = (dlk < 0.0f) ? lk * frcp(-dlk) : 3.0e38f; \
    amin = fminf(amin, fminf(r1, r2)); }

#define LDG(g, c, B) { _Pragma("unroll") for (int i = 0; i < B; ++i) g[i] = GB[(c)*12 + i]; }

__global__ __launch_bounds__(64, 3) void k_ipm(const float* ws, const float* g2v, const float* bb2, float* out){
    __shared__ __align__(16) float sQm[120];
    __shared__ __align__(16) float sPV[4*12];   // pv per element (BN2 folded)
    __shared__ float sHH[128];                  // h rows 10..137: sHH[k*16+lg]
    int t = threadIdx.x;
    for (int i = t; i < 120; i += 64) sQm[i] = ws[QM_OFF + i];
    for (int i = t; i < 128; i += 64) sHH[i] = ws[H_OFF + 10 + i];
    if (t < 40){
        int e = t / 10, i = t - e*10;
        float mu  = ws[S2_OFF + i] * (1.0f/16384.0f);
        float var = ws[SQ2_OFF + i] * (1.0f/16384.0f) - mu*mu;
        float a2 = g2v[i] / sqrtf(var + BNEPS);
        float c2 = bb2[i] - mu * a2;
        int el = blockIdx.x * 4 + e;
        sPV[e*12 + i] = fmaf(ws[PRAW_OFF + (size_t)el*10 + i], a2, c2);
    }
    __syncthreads();

    int lg = t & 15;
    int eidx = t >> 4;
    int elem = blockIdx.x * 4 + eidx;
    const float* GB = ws + G_OFF;
    const float* hhp = sHH + lg;
    const float4* sQm4 = (const float4*)sQm;

    // --- persistent per-lane G rows (sparsity-packed) ---
    float g0[2], g1[2], g2r[4], g3[4], g4[6], g5[6], g6[8], g7[8];
    {
        int c = 10 + lg;   LDG(g0, c, 2);
        c = 10 + 16 + lg;  LDG(g1, c, 2);
        c = 10 + 32 + lg;  LDG(g2r, c, 4);
        c = 10 + 48 + lg;  LDG(g3, c, 4);
        c = 10 + 64 + lg;  LDG(g4, c, 6);
        c = 10 + 80 + lg;  LDG(g5, c, 6);
        c = 10 + 96 + lg;  LDG(g6, c, 8);
        c = 10 + 112 + lg; LDG(g7, c, 8);
    }
    float h8 = (lg < 10) ? ws[H_OFF + lg] : 1.0f;

    float z[10];
    #pragma unroll
    for (int i = 0; i < 10; ++i) z[i] = 0.0f;
    float s[9], lam[9], rp[9];
    #pragma unroll
    for (int k = 0; k < 9; ++k){ s[k] = 1.0f; lam[k] = 1.0f; }
    lam[8] = (lg < 10) ? 1.0f : 0.0f;

    #pragma unroll 1
    for (int it = 0; it < ITERS; ++it){
        float lamG[8], Hm[55], sl = 0.0f;
        #pragma unroll
        for (int i = 0; i < 8; ++i) lamG[i] = 0.0f;
        #pragma unroll
        for (int i = 0; i < 36; ++i) Hm[i] = 0.0f;   // only tri(8) live in loop A
        // ---- loop A (B_hat rows, compile-time col bounds)
        STEPA(0, 2, g0)  STEPA(1, 2, g1)
        STEPA(2, 4, g2r) STEPA(3, 4, g3)
        STEPA(4, 6, g4)  STEPA(5, 6, g5)
        STEPA(6, 8, g6)  STEPA(7, 8, g7)
        // ---- identity row (slot 8)
        float zs = z[0];
        #pragma unroll
        for (int i = 1; i < 10; ++i) zs = (lg == i) ? z[i] : zs;
        float w8;
        {
            float sk = s[8], lk = lam[8];
            rp[8] = zs + sk - h8;
            sl = fmaf(sk, lk, sl);
            w8 = lk * frcp(sk);
        }
        // ---- DPP all-reduce over the 16-lane group (VALU, no LDS pipe)
        #pragma unroll
        for (int i = 0; i < 36; ++i) Hm[i] = red16_add(Hm[i]);
        #pragma unroll
        for (int i = 0; i < 8; ++i) lamG[i] = red16_add(lamG[i]);
        sl = red16_add(sl);
        float smu = SIGMA_C * sl * (1.0f/138.0f);
        // ---- identity contributions (broadcast from lanes 0..9)
        float lamG8 = __shfl(lam[8], 8, 16);
        float lamG9 = __shfl(lam[8], 9, 16);
        #pragma unroll
        for (int m = 0; m < 8; ++m) lamG[m] += __shfl(lam[8], m, 16);
        #pragma unroll
        for (int m = 0; m < 8; ++m) Hm[TIX(m,m)] += __shfl(w8, m, 16);
        float Hd8 = __shfl(w8, 8, 16);
        float Hd9 = __shfl(w8, 9, 16);
        // ---- rd = p + lamG + Qz; H rows 0..7 += Q, rows 8,9 assigned fresh
        float rd[10];
        {
            const float4* pv4 = (const float4*)(sPV + eidx*12);
            float4 pa = pv4[0], pb = pv4[1];
            const float2* pv2 = (const float2*)(sPV + eidx*12 + 8);
            float2 pc = pv2[0];
            rd[0]=pa.x+lamG[0]; rd[1]=pa.y+lamG[1]; rd[2]=pa.z+lamG[2]; rd[3]=pa.w+lamG[3];
            rd[4]=pb.x+lamG[4]; rd[5]=pb.y+lamG[5]; rd[6]=pb.z+lamG[6]; rd[7]=pb.w+lamG[7];
            rd[8]=pc.x+lamG8;   rd[9]=pc.y+lamG9;
        }
        #pragma unroll
        for (int j = 0; j < 10; ++j){
            float4 qa = sQm4[j*3+0], qb = sQm4[j*3+1], qc = sQm4[j*3+2];
            float q[10] = {qa.x,qa.y,qa.z,qa.w, qb.x,qb.y,qb.z,qb.w, qc.x,qc.y};
            float zj = z[j];
            #pragma unroll
            for (int i = 0; i < 10; ++i) rd[i] = fmaf(zj, q[i], rd[i]);
            if (j < 8){
                #pragma unroll
                for (int i = 0; i <= j; ++i) Hm[TIX(j,i)] += q[i];
            } else {
                #pragma unroll
                for (int i = 0; i <= j; ++i) Hm[TIX(j,i)] = q[i];
            }
        }
        Hm[TIX(8,8)] += Hd8;
        Hm[TIX(9,9)] += Hd9;
        // ---- loop B: rhs
        float racc[8];
        #pragma unroll
        for (int i = 0; i < 8; ++i) racc[i] = 0.0f;
        STEPB(0, 2, g0)  STEPB(1, 2, g1)
        STEPB(2, 4, g2r) STEPB(3, 4, g3)
        STEPB(4, 6, g4)  STEPB(5, 6, g5)
        STEPB(6, 8, g6)  STEPB(7, 8, g7)
        float coef8;
        {
            float sk = s[8], lk = lam[8];
            float isk = frcp(sk);
            float rc = fmaf(sk, lk, -smu);
            coef8 = isk * fmaf(lk, rp[8], -rc);
            coef8 = (lg < 10) ? coef8 : 0.0f;
        }
        #pragma unroll
        for (int i = 0; i < 8; ++i) racc[i] = red16_add(racc[i]);
        float rhs[10];
        #pragma unroll
        for (int m = 0; m < 8; ++m) racc[m] += __shfl(coef8, m, 16);
        float racc8 = __shfl(coef8, 8, 16);
        float racc9 = __shfl(coef8, 9, 16);
        #pragma unroll
        for (int i = 0; i < 8; ++i) rhs[i] = -(rd[i] + racc[i]);
        rhs[8] = -(rd[8] + racc8); rhs[9] = -(rd[9] + racc9);
        // ---- Cholesky (reciprocal diag in place)
        #pragma unroll
        for (int j = 0; j < 10; ++j){
            float d = Hm[TIX(j,j)];
            #pragma unroll
            for (int k2 = 0; k2 < j; ++k2){ float v = Hm[TIX(j,k2)]; d = fmaf(-v, v, d); }
            d = fmaxf(d, 1e-30f);
            float rinv = frsq(d);
            Hm[TIX(j,j)] = rinv;
            #pragma unroll
            for (int i = j+1; i < 10; ++i){
                float v2 = Hm[TIX(i,j)];
                #pragma unroll
                for (int k2 = 0; k2 < j; ++k2) v2 = fmaf(-Hm[TIX(i,k2)], Hm[TIX(j,k2)], v2);
                Hm[TIX(i,j)] = v2 * rinv;
            }
        }
        #pragma unroll
        for (int i = 0; i < 10; ++i){
            float v2 = rhs[i];
            #pragma unroll
            for (int k2 = 0; k2 < i; ++k2) v2 = fmaf(-Hm[TIX(i,k2)], rhs[k2], v2);
            rhs[i] = v2 * Hm[TIX(i,i)];
        }
        float dz[10];
        #pragma unroll
        for (int i = 9; i >= 0; --i){
            float v2 = rhs[i];
            #pragma unroll
            for (int k2 = i+1; k2 < 10; ++k2) v2 = fmaf(-Hm[TIX(k2,i)], dz[k2], v2);
            dz[i] = v2 * Hm[TIX(i,i)];
        }
        // ---- loop C: steps + alpha
        float ds_[9], dl_[9];
        float amin = 3.0e38f;
        STEPC(0, 2, g0)  STEPC(1, 2, g1)
        STEPC(2, 4, g2r) STEPC(3, 4, g3)
        STEPC(4, 6, g4)  STEPC(5, 6, g5)
        STEPC(6, 8, g6)  STEPC(7, 8, g7)
        {
            float dzs = dz[0];
            #pragma unroll
            for (int i = 1; i < 10; ++i) dzs = (lg == i) ? dz[i] : dzs;
            float dsk = -rp[8] - dzs;
            bool val = lg < 10;
            dsk = val ? dsk : 0.0f;
            float sk = s[8], lk = lam[8];
            float isk = frcp(sk);
            float rc = fmaf(sk, lk, -smu);
            float dlk = -(rc + lk * dsk) * isk;
            dlk = val ? dlk : 0.0f;
            ds_[8] = dsk; dl_[8] = dlk;
            float r1 = (dsk < 0.0f) ? sk * frcp(-dsk) : 3.0e38f;
            float r2 = (dlk < 0.0f) ? lk * frcp(-dlk) : 3.0e38f;
            amin = fminf(amin, fminf(r1, r2));
        }
        amin = red16_min(amin);
        float alpha = fminf(1.0f, 0.99f * amin);
        // ---- updates
        #pragma unroll
        for (int i = 0; i < 10; ++i) z[i] = fmaf(alpha, dz[i], z[i]);
        #pragma unroll
        for (int k = 0; k < 9; ++k){
            s[k]   = fmaf(alpha, ds_[k], s[k]);
            lam[k] = fmaf(alpha, dl_[k], lam[k]);
        }
    }
    if (lg == 0) out[elem] = z[0];
}

extern "C" void kernel_launch(void* const* d_in, const int* in_sizes, int n_in,
                              void* d_out, int out_size, void* d_ws, size_t ws_size,
                              hipStream_t stream){
    const float* x   = (const float*)d_in[0];
    const float* w1  = (const float*)d_in[1];
    const float* b1  = (const float*)d_in[2];
    const float* w2  = (const float*)d_in[3];
    const float* b2  = (const float*)d_in[4];
    const float* g1  = (const float*)d_in[5];
    const float* bb1 = (const float*)d_in[6];
    const float* g2  = (const float*)d_in[7];
    const float* bb2 = (const float*)d_in[8];
    const float* L   = (const float*)d_in[9];
    const float* LP  = (const float*)d_in[10];
    const float* LR  = (const float*)d_in[11];
    const float* A   = (const float*)d_in[12];
    const float* Bm  = (const float*)d_in[13];
    const float* u0  = (const float*)d_in[14];
    const float* s0  = (const float*)d_in[15];
    float* ws  = (float*)d_ws;
    float* out = (float*)d_out;

    hipLaunchKernelGGL(k_build,  dim3(1),    dim3(256), 0, stream, L, LP, LR, A, Bm, u0, s0, ws);
    hipLaunchKernelGGL(k_stats1, dim3(256),  dim3(256), 0, stream, x, w1, b1, ws);
    hipLaunchKernelGGL(k_fin1,   dim3(1),    dim3(256), 0, stream, g1, bb1, w2, b2, ws);
    hipLaunchKernelGGL(k_fc2,    dim3(256),  dim3(256), 0, stream, x, w1, b1, w2, ws);
    hipLaunchKernelGGL(k_ipm,    dim3(4096), dim3(64),  0, stream, ws, g2, bb2, out);
}

// Round 5
// 645.871 us; speedup vs baseline: 3.1450x; 3.1450x over previous
//
#include <hip/hip_runtime.h>
#include <math.h>

#define NIx 32
#define NOx 2
#define NUx 10
#define NHx 1024
#define NBx 16384
#define MIx 138
#define EPSQ 1e-4f
#define BNEPS 1e-5f
#define ITERS 30
#define SLOPE 0.2f
#define SIGMA_C 0.1f

// workspace layout (float offsets)
#define QM_OFF 0       // 10 rows x 12 (padded)
#define G_OFF 128      // 144 rows x 12 (padded, zero pad rows/cols)
#define H_OFF 1856     // 144
#define A1_OFF 2048    // 1024
#define C1_OFF 3072    // 1024
#define B2P_OFF 4096   // 10 (pad to 4112)
#define S1_OFF 4112    // 1024
#define SQ1_OFF 5136   // 1024
#define S2_OFF 6160    // 10 (pad 16)
#define SQ2_OFF 6176   // 10 (pad to 6208)
#define PRAW_OFF 6208  // 16384*10
#define ZERO_LEN (6208 - S1_OFF)

__device__ __forceinline__ float frcp(float x){ return __builtin_amdgcn_rcpf(x); }
__device__ __forceinline__ float frsq(float x){ return __builtin_amdgcn_rsqf(x); }
__device__ __forceinline__ float lrelu(float x){ return x > 0.0f ? x : SLOPE * x; }

// ---- DPP 16-lane reductions (VALU, no LDS pipe) ----
template<int CTRL>
__device__ __forceinline__ float dpp_mov(float x){
    int y = __builtin_amdgcn_update_dpp(0, __float_as_int(x), CTRL, 0xF, 0xF, true);
    return __int_as_float(y);
}
__device__ __forceinline__ float red16_add(float x){
    x += dpp_mov<0xB1>(x);
    x += dpp_mov<0x4E>(x);
    x += dpp_mov<0x124>(x);
    x += dpp_mov<0x128>(x);
    return x;
}
__device__ __forceinline__ float red16_min(float x){
    x = fminf(x, dpp_mov<0xB1>(x));
    x = fminf(x, dpp_mov<0x4E>(x));
    x = fminf(x, dpp_mov<0x124>(x));
    x = fminf(x, dpp_mov<0x128>(x));
    return x;
}

// ---------- build Q_hat, G, h (one block); also zeroes the stats accumulators ----------
__global__ __launch_bounds__(256) void k_build(const float* L, const float* LP, const float* LR,
                                               const float* A, const float* Bm,
                                               const float* u0, const float* s0, float* ws){
    __shared__ float sL[1024], sLP[1024], sA[1024], sQ[1024], sP[1024];
    __shared__ float sPow[4][64];   // [power][i*2+c]
    __shared__ float sBh[128*10];
    __shared__ float sQB[128*10];
    __shared__ float sR[3];
    int t = threadIdx.x;
    for (int idx = t; idx < ZERO_LEN; idx += 256) ws[S1_OFF + idx] = 0.0f;
    for (int idx = t; idx < 1024; idx += 256){
        int i = idx >> 5, j = idx & 31;
        sL[idx]  = (j <= i) ? L[idx]  : 0.0f;
        sLP[idx] = (j <= i) ? LP[idx] : 0.0f;
        sA[idx]  = A[idx];
    }
    if (t < 64) sPow[0][t] = Bm[t];
    if (t == 0){
        float a = LR[0], b = LR[2], c = LR[3];   // tril: [[a,0],[b,c]]
        sR[0] = a*a + EPSQ; sR[1] = a*b; sR[2] = b*b + c*c + EPSQ;
    }
    __syncthreads();
    for (int idx = t; idx < 1024; idx += 256){
        int i = idx >> 5, j = idx & 31;
        float q = 0.0f, p = 0.0f;
        for (int k = 0; k < 32; ++k){
            q = fmaf(sL[i*32+k],  sL[j*32+k],  q);
            p = fmaf(sLP[i*32+k], sLP[j*32+k], p);
        }
        if (i == j){ q += EPSQ; p += EPSQ; }
        sQ[idx] = q; sP[idx] = p;
    }
    for (int kp = 1; kp < 4; ++kp){
        __syncthreads();
        if (t < 64){
            int i = t >> 1, c = t & 1;
            float a = 0.0f;
            for (int j = 0; j < 32; ++j) a = fmaf(sA[i*32+j], sPow[kp-1][j*2+c], a);
            sPow[kp][t] = a;
        }
    }
    __syncthreads();
    for (int idx = t; idx < 1280; idx += 256){
        int r = idx / 10, c = idx % 10;
        int bi = r >> 5, ri = r & 31, bj = c >> 1, cj = c & 1;
        sBh[idx] = (bj <= bi) ? sPow[bi-bj][ri*2+cj] : 0.0f;
    }
    __syncthreads();
    for (int idx = t; idx < 1280; idx += 256){
        int r = idx / 10, c = idx % 10;
        int bi = r >> 5, ri = r & 31;
        const float* Qd = (bi < 3) ? sQ : sP;
        float a = 0.0f;
        for (int k = 0; k < 32; ++k) a = fmaf(Qd[ri*32+k], sBh[(bi*32+k)*10+c], a);
        sQB[idx] = a;
    }
    __syncthreads();
    if (t < 120){
        int i = t / 12, j = t % 12;
        float a = 0.0f;
        if (j < 10){
            for (int r = 0; r < 128; ++r) a = fmaf(sBh[r*10+i], sQB[r*10+j], a);
            if ((i >> 1) == (j >> 1)) a += sR[(i&1)+(j&1)];
        }
        ws[QM_OFF + t] = a;
    }
    for (int idx = t; idx < 144*12; idx += 256){
        int m = idx / 12, i = idx % 12;
        float v = 0.0f;
        if (i < 10 && m < MIx) v = (m < 10) ? ((i == m) ? 1.0f : 0.0f) : sBh[(m-10)*10 + i];
        ws[G_OFF + idx] = v;
    }
    for (int m = t; m < 144; m += 256){
        float hv = 0.0f;
        if (m < MIx){
            hv = s0[m];
            if (m < 10) hv += u0[m];
            else { for (int i = 0; i < 10; ++i) hv = fmaf(sBh[(m-10)*10+i], u0[i], hv); }
        }
        ws[H_OFF + m] = hv;
    }
}

// ---------- BN1 stats: h1 = lrelu(x@W1^T + b1), accumulate per-col sum/sumsq ----------
__global__ __launch_bounds__(256) void k_stats1(const float* x, const float* w1, const float* b1, float* ws){
    __shared__ float xs[256*32];
    int t = threadIdx.x;
    int rb = blockIdx.x >> 2;
    int cb = blockIdx.x & 3;
    int r0 = rb * 256;
    int c = cb * 256 + t;
    const float4* xg4 = (const float4*)(x + (size_t)r0 * 32);
    float4* xs4 = (float4*)xs;
    for (int i = t; i < 2048; i += 256) xs4[i] = xg4[i];
    const float4* wg4 = (const float4*)(w1 + (size_t)c * 32);
    float4 wr[8];
    #pragma unroll
    for (int q = 0; q < 8; ++q) wr[q] = wg4[q];
    float bc = b1[c];
    __syncthreads();
    const float4* xr4 = (const float4*)xs;
    float sum = 0.0f, sq = 0.0f;
    for (int r = 0; r < 256; ++r){
        float a0 = 0, a1 = 0, a2 = 0, a3 = 0;
        #pragma unroll
        for (int q = 0; q < 8; ++q){
            float4 v = xr4[r*8 + q];
            a0 = fmaf(v.x, wr[q].x, a0);
            a1 = fmaf(v.y, wr[q].y, a1);
            a2 = fmaf(v.z, wr[q].z, a2);
            a3 = fmaf(v.w, wr[q].w, a3);
        }
        float h = lrelu((a0 + a1) + (a2 + a3) + bc);
        sum += h; sq = fmaf(h, h, sq);
    }
    atomicAdd(&ws[S1_OFF + c], sum);
    atomicAdd(&ws[SQ1_OFF + c], sq);
}

// ---------- finalize BN1 affine + fold into fc2 bias ----------
__global__ __launch_bounds__(256) void k_fin1(const float* g1, const float* bb1,
                                              const float* w2, const float* b2, float* ws){
    int t = threadIdx.x;
    for (int k = t; k < 1024; k += 256){
        float mu  = ws[S1_OFF + k] * (1.0f/16384.0f);
        float var = ws[SQ1_OFF + k] * (1.0f/16384.0f) - mu*mu;
        float a1 = g1[k] / sqrtf(var + BNEPS);
        ws[A1_OFF + k] = a1;
        ws[C1_OFF + k] = bb1[k] - mu * a1;
    }
    __syncthreads();
    if (t < 10){
        float a = b2[t];
        for (int k = 0; k < 1024; ++k) a = fmaf(ws[C1_OFF + k], w2[t*1024 + k], a);
        ws[B2P_OFF + t] = a;
    }
}

// ---------- fc2: p_raw = lrelu((h1*a1)@W2^T + b2'), + BN2 stats ----------
__global__ __launch_bounds__(256) void k_fc2(const float* x, const float* w1, const float* b1,
                                             const float* w2, float* ws){
    __shared__ float ws1[128*32];     // W1 chunk [kl][c]
    __shared__ float w2t[128*12];     // W2 chunk transposed, padded to 12
    __shared__ float sab[128*2];      // (a1, b1) per kl
    int t = threadIdx.x;
    int r0 = blockIdx.x * 64;
    int r = t & 63;
    int q = t >> 6;                   // wave id: k-quarter
    const float4* xg4 = (const float4*)(x + (size_t)(r0 + r) * 32);
    float4 xr[8];
    #pragma unroll
    for (int i = 0; i < 8; ++i) xr[i] = xg4[i];
    float acc[10];
    #pragma unroll
    for (int j = 0; j < 10; ++j) acc[j] = 0.0f;

    for (int kc = 0; kc < 1024; kc += 128){
        __syncthreads();
        const float4* w1g = (const float4*)(w1 + (size_t)kc * 32);
        float4* ws14 = (float4*)ws1;
        for (int i = t; i < 1024; i += 256) ws14[i] = w1g[i];
        for (int i = t; i < 1280; i += 256){
            int kl = i & 127, j = i >> 7;
            w2t[kl*12 + j] = w2[j*1024 + kc + kl];
        }
        if (t < 256){ int kl = t >> 1, j = 10 + (t & 1); w2t[kl*12 + j] = 0.0f; }
        if (t < 128){ sab[t*2] = ws[A1_OFF + kc + t]; sab[t*2+1] = b1[kc + t]; }
        __syncthreads();
        const float4* w1r = (const float4*)ws1;
        const float4* w2r = (const float4*)w2t;
        const float2* abr = (const float2*)sab;
        #pragma unroll 4
        for (int kk = 0; kk < 32; ++kk){
            int kl = q*32 + kk;
            float a0 = 0, a1 = 0, a2 = 0, a3 = 0;
            #pragma unroll
            for (int qq = 0; qq < 8; ++qq){
                float4 wv = w1r[kl*8 + qq];
                float4 xv = xr[qq];
                a0 = fmaf(xv.x, wv.x, a0);
                a1 = fmaf(xv.y, wv.y, a1);
                a2 = fmaf(xv.z, wv.z, a2);
                a3 = fmaf(xv.w, wv.w, a3);
            }
            float2 ab = abr[kl];
            float h = lrelu((a0 + a1) + (a2 + a3) + ab.y) * ab.x;
            float4 wa = w2r[kl*3+0], wb = w2r[kl*3+1], wc = w2r[kl*3+2];
            acc[0] = fmaf(h, wa.x, acc[0]); acc[1] = fmaf(h, wa.y, acc[1]);
            acc[2] = fmaf(h, wa.z, acc[2]); acc[3] = fmaf(h, wa.w, acc[3]);
            acc[4] = fmaf(h, wb.x, acc[4]); acc[5] = fmaf(h, wb.y, acc[5]);
            acc[6] = fmaf(h, wb.z, acc[6]); acc[7] = fmaf(h, wb.w, acc[7]);
            acc[8] = fmaf(h, wc.x, acc[8]); acc[9] = fmaf(h, wc.y, acc[9]);
        }
    }
    __syncthreads();
    float* pacc = ws1;   // reuse LDS
    #pragma unroll
    for (int j = 0; j < 10; ++j) pacc[(q*64 + r)*10 + j] = acc[j];
    __syncthreads();
    if (t < 64){
        float pv[10];
        #pragma unroll
        for (int j = 0; j < 10; ++j){
            float a = ws[B2P_OFF + j];
            a += pacc[t*10+j] + pacc[(64+t)*10+j] + pacc[(128+t)*10+j] + pacc[(192+t)*10+j];
            pv[j] = lrelu(a);
        }
        #pragma unroll
        for (int j = 0; j < 10; ++j) ws[PRAW_OFF + (size_t)(r0 + t)*10 + j] = pv[j];
        float sv[10], qv[10];
        #pragma unroll
        for (int j = 0; j < 10; ++j){ sv[j] = pv[j]; qv[j] = pv[j]*pv[j]; }
        #pragma unroll
        for (int m = 1; m < 64; m <<= 1){
            #pragma unroll
            for (int j = 0; j < 10; ++j){
                sv[j] += __shfl_xor(sv[j], m);
                qv[j] += __shfl_xor(qv[j], m);
            }
        }
        if (t == 0){
            #pragma unroll
            for (int j = 0; j < 10; ++j){
                atomicAdd(&ws[S2_OFF + j], sv[j]);
                atomicAdd(&ws[SQ2_OFF + j], qv[j]);
            }
        }
    }
}

// ---------- batched IPM, sparsity-aware, 64-thread single-wave blocks ----------
// 16 lanes/element, 4 elements/block. Slot k=0..7: B_hat row 10+16k+lg, col bound
// 2*(k/2+1) (compile-time). Slot 8: identity row lg (lanes 0..9), analytic.
// G rows in registers (40 floats, loaded once). pv/h/rp in LDS for VGPR<=170
// (3 waves/SIMD). NOTE: do NOT use launch_bounds min-waves arg — round-4 showed
// it slashes VGPR to 84 and spills 5.5 GB to scratch.
#define TIX(i,j) ((i)*((i)+1)/2 + (j))

#define STEPA(K, B, g) { \
    float sk = s[K], lk = lam[K]; \
    float r = sk - hhp[(K)*16]; \
    float w = lk * frcp(sk); \
    sl = fmaf(sk, lk, sl); \
    _Pragma("unroll") \
    for (int i = 0; i < B; ++i){ \
        lamG[i] = fmaf(lk, g[i], lamG[i]); \
        r = fmaf(z[i], g[i], r); \
    } \
    sRPp[K] = r; \
    _Pragma("unroll") \
    for (int i = 0; i < B; ++i){ \
        float wgi = w * g[i]; \
        _Pragma("unroll") \
        for (int j = 0; j <= i; ++j) Hm[TIX(i,j)] = fmaf(wgi, g[j], Hm[TIX(i,j)]); \
    } }

#define STEPB(K, B, g) { \
    float rpk = sRPp[K]; \
    float sk = s[K], lk = lam[K]; \
    float isk = frcp(sk); \
    float rc = fmaf(sk, lk, -smu); \
    float coef = isk * fmaf(lk, rpk, -rc); \
    _Pragma("unroll") \
    for (int i = 0; i < B; ++i) racc[i] = fmaf(coef, g[i], racc[i]); }

#define STEPC(K, B, g) { \
    float rpk = sRPp[K]; \
    float dot = 0.0f; \
    _Pragma("unroll") \
    for (int i = 0; i < B; ++i) dot = fmaf(dz[i], g[i], dot); \
    float dsk = -rpk - dot; \
    float sk = s[K], lk = lam[K]; \
    float isk = frcp(sk); \
    float rc = fmaf(sk, lk, -smu); \
    float dlk = -(rc + lk * dsk) * isk; \
    ds_[K] = dsk; dl_[K] = dlk; \
    float r1 = (dsk < 0.0f) ? sk * frcp(-dsk) : 3.0e38f; \
    float r2 = (dlk < 0.0f) ? lk * frcp(-dlk) : 3.0e38f; \
    amin = fminf(amin, fminf(r1, r2)); }

#define LDG(g, c, B) { _Pragma("unroll") for (int i = 0; i < B; ++i) g[i] = GB[(c)*12 + i]; }

__global__ __launch_bounds__(64) void k_ipm(const float* ws, const float* g2v, const float* bb2, float* out){
    __shared__ __align__(16) float sQm[120];
    __shared__ __align__(16) float sPV[4*12];   // pv per element (BN2 folded)
    __shared__ float sHH[128];                  // h rows 10..137: sHH[k*16+lg]
    __shared__ float sRP[64*9];                 // rp slots 0..7 (+slot8 unused), stride 9 (conflict-free)
    int t = threadIdx.x;
    for (int i = t; i < 120; i += 64) sQm[i] = ws[QM_OFF + i];
    for (int i = t; i < 128; i += 64) sHH[i] = ws[H_OFF + 10 + i];
    if (t < 40){
        int e = t / 10, i = t - e*10;
        float mu  = ws[S2_OFF + i] * (1.0f/16384.0f);
        float var = ws[SQ2_OFF + i] * (1.0f/16384.0f) - mu*mu;
        float a2 = g2v[i] / sqrtf(var + BNEPS);
        float c2 = bb2[i] - mu * a2;
        int el = blockIdx.x * 4 + e;
        sPV[e*12 + i] = fmaf(ws[PRAW_OFF + (size_t)el*10 + i], a2, c2);
    }
    __syncthreads();

    int lg = t & 15;
    int eidx = t >> 4;
    int elem = blockIdx.x * 4 + eidx;
    const float* GB = ws + G_OFF;
    const float* hhp = sHH + lg;
    float* sRPp = sRP + t * 9;
    const float4* sQm4 = (const float4*)sQm;

    // --- persistent per-lane G rows (sparsity-packed) ---
    float g0[2], g1[2], g2r[4], g3[4], g4[6], g5[6], g6[8], g7[8];
    {
        int c = 10 + lg;   LDG(g0, c, 2);
        c = 10 + 16 + lg;  LDG(g1, c, 2);
        c = 10 + 32 + lg;  LDG(g2r, c, 4);
        c = 10 + 48 + lg;  LDG(g3, c, 4);
        c = 10 + 64 + lg;  LDG(g4, c, 6);
        c = 10 + 80 + lg;  LDG(g5, c, 6);
        c = 10 + 96 + lg;  LDG(g6, c, 8);
        c = 10 + 112 + lg; LDG(g7, c, 8);
    }
    float h8 = (lg < 10) ? ws[H_OFF + lg] : 1.0f;

    float z[10];
    #pragma unroll
    for (int i = 0; i < 10; ++i) z[i] = 0.0f;
    float s[9], lam[9];
    #pragma unroll
    for (int k = 0; k < 9; ++k){ s[k] = 1.0f; lam[k] = 1.0f; }
    lam[8] = (lg < 10) ? 1.0f : 0.0f;

    #pragma unroll 1
    for (int it = 0; it < ITERS; ++it){
        float lamG[8], Hm[55], sl = 0.0f, rp8;
        #pragma unroll
        for (int i = 0; i < 8; ++i) lamG[i] = 0.0f;
        #pragma unroll
        for (int i = 0; i < 36; ++i) Hm[i] = 0.0f;   // only tri(8) live in loop A
        // ---- loop A (B_hat rows, compile-time col bounds)
        STEPA(0, 2, g0)  STEPA(1, 2, g1)
        STEPA(2, 4, g2r) STEPA(3, 4, g3)
        STEPA(4, 6, g4)  STEPA(5, 6, g5)
        STEPA(6, 8, g6)  STEPA(7, 8, g7)
        // ---- identity row (slot 8)
        float zs = z[0];
        #pragma unroll
        for (int i = 1; i < 10; ++i) zs = (lg == i) ? z[i] : zs;
        float w8;
        {
            float sk = s[8], lk = lam[8];
            rp8 = zs + sk - h8;
            sl = fmaf(sk, lk, sl);
            w8 = lk * frcp(sk);
        }
        // ---- DPP all-reduce over the 16-lane group (VALU, no LDS pipe)
        #pragma unroll
        for (int i = 0; i < 36; ++i) Hm[i] = red16_add(Hm[i]);
        #pragma unroll
        for (int i = 0; i < 8; ++i) lamG[i] = red16_add(lamG[i]);
        sl = red16_add(sl);
        float smu = SIGMA_C * sl * (1.0f/138.0f);
        // ---- identity contributions (broadcast from lanes 0..9)
        float lamG8 = __shfl(lam[8], 8, 16);
        float lamG9 = __shfl(lam[8], 9, 16);
        #pragma unroll
        for (int m = 0; m < 8; ++m) lamG[m] += __shfl(lam[8], m, 16);
        #pragma unroll
        for (int m = 0; m < 8; ++m) Hm[TIX(m,m)] += __shfl(w8, m, 16);
        float Hd8 = __shfl(w8, 8, 16);
        float Hd9 = __shfl(w8, 9, 16);
        // ---- rd = p + lamG + Qz; H rows 0..7 += Q, rows 8,9 assigned fresh
        float rd[10];
        {
            const float4* pv4 = (const float4*)(sPV + eidx*12);
            float4 pa = pv4[0], pb = pv4[1];
            const float2* pv2 = (const float2*)(sPV + eidx*12 + 8);
            float2 pc = pv2[0];
            rd[0]=pa.x+lamG[0]; rd[1]=pa.y+lamG[1]; rd[2]=pa.z+lamG[2]; rd[3]=pa.w+lamG[3];
            rd[4]=pb.x+lamG[4]; rd[5]=pb.y+lamG[5]; rd[6]=pb.z+lamG[6]; rd[7]=pb.w+lamG[7];
            rd[8]=pc.x+lamG8;   rd[9]=pc.y+lamG9;
        }
        #pragma unroll
        for (int j = 0; j < 10; ++j){
            float4 qa = sQm4[j*3+0], qb = sQm4[j*3+1], qc = sQm4[j*3+2];
            float q[10] = {qa.x,qa.y,qa.z,qa.w, qb.x,qb.y,qb.z,qb.w, qc.x,qc.y};
            float zj = z[j];
            #pragma unroll
            for (int i = 0; i < 10; ++i) rd[i] = fmaf(zj, q[i], rd[i]);
            if (j < 8){
                #pragma unroll
                for (int i = 0; i <= j; ++i) Hm[TIX(j,i)] += q[i];
            } else {
                #pragma unroll
                for (int i = 0; i <= j; ++i) Hm[TIX(j,i)] = q[i];
            }
        }
        Hm[TIX(8,8)] += Hd8;
        Hm[TIX(9,9)] += Hd9;
        // ---- loop B: rhs
        float racc[8];
        #pragma unroll
        for (int i = 0; i < 8; ++i) racc[i] = 0.0f;
        STEPB(0, 2, g0)  STEPB(1, 2, g1)
        STEPB(2, 4, g2r) STEPB(3, 4, g3)
        STEPB(4, 6, g4)  STEPB(5, 6, g5)
        STEPB(6, 8, g6)  STEPB(7, 8, g7)
        float coef8;
        {
            float sk = s[8], lk = lam[8];
            float isk = frcp(sk);
            float rc = fmaf(sk, lk, -smu);
            coef8 = isk * fmaf(lk, rp8, -rc);
            coef8 = (lg < 10) ? coef8 : 0.0f;
        }
        #pragma unroll
        for (int i = 0; i < 8; ++i) racc[i] = red16_add(racc[i]);
        float rhs[10];
        #pragma unroll
        for (int m = 0; m < 8; ++m) racc[m] += __shfl(coef8, m, 16);
        float racc8 = __shfl(coef8, 8, 16);
        float racc9 = __shfl(coef8, 9, 16);
        #pragma unroll
        for (int i = 0; i < 8; ++i) rhs[i] = -(rd[i] + racc[i]);
        rhs[8] = -(rd[8] + racc8); rhs[9] = -(rd[9] + racc9);
        // ---- Cholesky (reciprocal diag in place)
        #pragma unroll
        for (int j = 0; j < 10; ++j){
            float d = Hm[TIX(j,j)];
            #pragma unroll
            for (int k2 = 0; k2 < j; ++k2){ float v = Hm[TIX(j,k2)]; d = fmaf(-v, v, d); }
            d = fmaxf(d, 1e-30f);
            float rinv = frsq(d);
            Hm[TIX(j,j)] = rinv;
            #pragma unroll
            for (int i = j+1; i < 10; ++i){
                float v2 = Hm[TIX(i,j)];
                #pragma unroll
                for (int k2 = 0; k2 < j; ++k2) v2 = fmaf(-Hm[TIX(i,k2)], Hm[TIX(j,k2)], v2);
                Hm[TIX(i,j)] = v2 * rinv;
            }
        }
        #pragma unroll
        for (int i = 0; i < 10; ++i){
            float v2 = rhs[i];
            #pragma unroll
            for (int k2 = 0; k2 < i; ++k2) v2 = fmaf(-Hm[TIX(i,k2)], rhs[k2], v2);
            rhs[i] = v2 * Hm[TIX(i,i)];
        }
        float dz[10];
        #pragma unroll
        for (int i = 9; i >= 0; --i){
            float v2 = rhs[i];
            #pragma unroll
            for (int k2 = i+1; k2 < 10; ++k2) v2 = fmaf(-Hm[TIX(k2,i)], dz[k2], v2);
            dz[i] = v2 * Hm[TIX(i,i)];
        }
        // ---- loop C: steps + alpha
        float ds_[9], dl_[9];
        float amin = 3.0e38f;
        STEPC(0, 2, g0)  STEPC(1, 2, g1)
        STEPC(2, 4, g2r) STEPC(3, 4, g3)
        STEPC(4, 6, g4)  STEPC(5, 6, g5)
        STEPC(6, 8, g6)  STEPC(7, 8, g7)
        {
            float dzs = dz[0];
            #pragma unroll
            for (int i = 1; i < 10; ++i) dzs = (lg == i) ? dz[i] : dzs;
            float dsk = -rp8 - dzs;
            bool val = lg < 10;
            dsk = val ? dsk : 0.0f;
            float sk = s[8], lk = lam[8];
            float isk = frcp(sk);
            float rc = fmaf(sk, lk, -smu);
            float dlk = -(rc + lk * dsk) * isk;
            dlk = val ? dlk : 0.0f;
            ds_[8] = dsk; dl_[8] = dlk;
            float r1 = (dsk < 0.0f) ? sk * frcp(-dsk) : 3.0e38f;
            float r2 = (dlk < 0.0f) ? lk * frcp(-dlk) : 3.0e38f;
            amin = fminf(amin, fminf(r1, r2));
        }
        amin = red16_min(amin);
        float alpha = fminf(1.0f, 0.99f * amin);
        // ---- updates
        #pragma unroll
        for (int i = 0; i < 10; ++i) z[i] = fmaf(alpha, dz[i], z[i]);
        #pragma unroll
        for (int k = 0; k < 9; ++k){
            s[k]   = fmaf(alpha, ds_[k], s[k]);
            lam[k] = fmaf(alpha, dl_[k], lam[k]);
        }
    }
    if (lg == 0) out[elem] = z[0];
}

extern "C" void kernel_launch(void* const* d_in, const int* in_sizes, int n_in,
                              void* d_out, int out_size, void* d_ws, size_t ws_size,
                              hipStream_t stream){
    const float* x   = (const float*)d_in[0];
    const float* w1  = (const float*)d_in[1];
    const float* b1  = (const float*)d_in[2];
    const float* w2  = (const float*)d_in[3];
    const float* b2  = (const float*)d_in[4];
    const float* g1  = (const float*)d_in[5];
    const float* bb1 = (const float*)d_in[6];
    const float* g2  = (const float*)d_in[7];
    const float* bb2 = (const float*)d_in[8];
    const float* L   = (const float*)d_in[9];
    const float* LP  = (const float*)d_in[10];
    const float* LR  = (const float*)d_in[11];
    const float* A   = (const float*)d_in[12];
    const float* Bm  = (const float*)d_in[13];
    const float* u0  = (const float*)d_in[14];
    const float* s0  = (const float*)d_in[15];
    float* ws  = (float*)d_ws;
    float* out = (float*)d_out;

    hipLaunchKernelGGL(k_build,  dim3(1),    dim3(256), 0, stream, L, LP, LR, A, Bm, u0, s0, ws);
    hipLaunchKernelGGL(k_stats1, dim3(256),  dim3(256), 0, stream, x, w1, b1, ws);
    hipLaunchKernelGGL(k_fin1,   dim3(1),    dim3(256), 0, stream, g1, bb1, w2, b2, ws);
    hipLaunchKernelGGL(k_fc2,    dim3(256),  dim3(256), 0, stream, x, w1, b1, w2, ws);
    hipLaunchKernelGGL(k_ipm,    dim3(4096), dim3(64),  0, stream, ws, g2, bb2, out);
}

// Round 6
// 620.226 us; speedup vs baseline: 3.2750x; 1.0413x over previous
//
#include <hip/hip_runtime.h>
#include <math.h>

#define NIx 32
#define NOx 2
#define NUx 10
#define NHx 1024
#define NBx 16384
#define MIx 138
#define EPSQ 1e-4f
#define BNEPS 1e-5f
#define ITERS 30
#define SLOPE 0.2f
#define SIGMA_C 0.1f

// workspace layout (float offsets)
#define QM_OFF 0       // 10 rows x 12 (padded)
#define G_OFF 128      // 144 rows x 12 (padded, zero pad rows/cols)
#define H_OFF 1856     // 144
#define A1_OFF 2048    // 1024
#define C1_OFF 3072    // 1024
#define B2P_OFF 4096   // 10 (pad to 4112)
#define S1_OFF 4112    // 1024
#define SQ1_OFF 5136   // 1024
#define S2_OFF 6160    // 10 (pad 16)
#define SQ2_OFF 6176   // 10 (pad to 6208)
#define PRAW_OFF 6208  // 16384*10
#define WTAB_OFF (PRAW_OFF + 16384*10)   // 1024 x 12: {w2[j][kl] j=0..9, a1[kl], b1[kl]}
#define ZERO_LEN (6208 - S1_OFF)

__device__ __forceinline__ float frcp(float x){ return __builtin_amdgcn_rcpf(x); }
__device__ __forceinline__ float frsq(float x){ return __builtin_amdgcn_rsqf(x); }
__device__ __forceinline__ float lrelu(float x){ return x > 0.0f ? x : SLOPE * x; }

// ---- DPP 16-lane reductions (VALU, no LDS pipe) ----
template<int CTRL>
__device__ __forceinline__ float dpp_mov(float x){
    int y = __builtin_amdgcn_update_dpp(0, __float_as_int(x), CTRL, 0xF, 0xF, true);
    return __int_as_float(y);
}
__device__ __forceinline__ float red16_add(float x){
    x += dpp_mov<0xB1>(x);
    x += dpp_mov<0x4E>(x);
    x += dpp_mov<0x124>(x);
    x += dpp_mov<0x128>(x);
    return x;
}
__device__ __forceinline__ float red16_min(float x){
    x = fminf(x, dpp_mov<0xB1>(x));
    x = fminf(x, dpp_mov<0x4E>(x));
    x = fminf(x, dpp_mov<0x124>(x));
    x = fminf(x, dpp_mov<0x128>(x));
    return x;
}

// ---------- build Q_hat, G, h (one block); also zeroes the stats accumulators ----------
__global__ __launch_bounds__(256) void k_build(const float* L, const float* LP, const float* LR,
                                               const float* A, const float* Bm,
                                               const float* u0, const float* s0, float* ws){
    __shared__ float sL[1024], sLP[1024], sA[1024], sQ[1024], sP[1024];
    __shared__ float sPow[4][64];   // [power][i*2+c]
    __shared__ float sBh[128*10];
    __shared__ float sQB[128*10];
    __shared__ float sR[3];
    int t = threadIdx.x;
    for (int idx = t; idx < ZERO_LEN; idx += 256) ws[S1_OFF + idx] = 0.0f;
    for (int idx = t; idx < 1024; idx += 256){
        int i = idx >> 5, j = idx & 31;
        sL[idx]  = (j <= i) ? L[idx]  : 0.0f;
        sLP[idx] = (j <= i) ? LP[idx] : 0.0f;
        sA[idx]  = A[idx];
    }
    if (t < 64) sPow[0][t] = Bm[t];
    if (t == 0){
        float a = LR[0], b = LR[2], c = LR[3];   // tril: [[a,0],[b,c]]
        sR[0] = a*a + EPSQ; sR[1] = a*b; sR[2] = b*b + c*c + EPSQ;
    }
    __syncthreads();
    for (int idx = t; idx < 1024; idx += 256){
        int i = idx >> 5, j = idx & 31;
        float q = 0.0f, p = 0.0f;
        for (int k = 0; k < 32; ++k){
            q = fmaf(sL[i*32+k],  sL[j*32+k],  q);
            p = fmaf(sLP[i*32+k], sLP[j*32+k], p);
        }
        if (i == j){ q += EPSQ; p += EPSQ; }
        sQ[idx] = q; sP[idx] = p;
    }
    for (int kp = 1; kp < 4; ++kp){
        __syncthreads();
        if (t < 64){
            int i = t >> 1, c = t & 1;
            float a = 0.0f;
            for (int j = 0; j < 32; ++j) a = fmaf(sA[i*32+j], sPow[kp-1][j*2+c], a);
            sPow[kp][t] = a;
        }
    }
    __syncthreads();
    for (int idx = t; idx < 1280; idx += 256){
        int r = idx / 10, c = idx % 10;
        int bi = r >> 5, ri = r & 31, bj = c >> 1, cj = c & 1;
        sBh[idx] = (bj <= bi) ? sPow[bi-bj][ri*2+cj] : 0.0f;
    }
    __syncthreads();
    for (int idx = t; idx < 1280; idx += 256){
        int r = idx / 10, c = idx % 10;
        int bi = r >> 5, ri = r & 31;
        const float* Qd = (bi < 3) ? sQ : sP;
        float a = 0.0f;
        for (int k = 0; k < 32; ++k) a = fmaf(Qd[ri*32+k], sBh[(bi*32+k)*10+c], a);
        sQB[idx] = a;
    }
    __syncthreads();
    if (t < 120){
        int i = t / 12, j = t % 12;
        float a = 0.0f;
        if (j < 10){
            for (int r = 0; r < 128; ++r) a = fmaf(sBh[r*10+i], sQB[r*10+j], a);
            if ((i >> 1) == (j >> 1)) a += sR[(i&1)+(j&1)];
        }
        ws[QM_OFF + t] = a;
    }
    for (int idx = t; idx < 144*12; idx += 256){
        int m = idx / 12, i = idx % 12;
        float v = 0.0f;
        if (i < 10 && m < MIx) v = (m < 10) ? ((i == m) ? 1.0f : 0.0f) : sBh[(m-10)*10 + i];
        ws[G_OFF + idx] = v;
    }
    for (int m = t; m < 144; m += 256){
        float hv = 0.0f;
        if (m < MIx){
            hv = s0[m];
            if (m < 10) hv += u0[m];
            else { for (int i = 0; i < 10; ++i) hv = fmaf(sBh[(m-10)*10+i], u0[i], hv); }
        }
        ws[H_OFF + m] = hv;
    }
}

// ---------- BN1 stats: h1 = lrelu(x@W1^T + b1), per-col sum/sumsq ----------
// x rows read via wave-uniform broadcast loads (L2-served, no LDS pipe).
__global__ __launch_bounds__(256) void k_stats1(const float* x, const float* w1, const float* b1, float* ws){
    int t = threadIdx.x;
    int rb = blockIdx.x >> 2;        // 128 row-groups of 128 rows
    int cb = blockIdx.x & 3;         // 4 col-groups of 256 cols
    int c = cb * 256 + t;
    const float4* wg4 = (const float4*)(w1 + (size_t)c * 32);
    float4 wr[8];
    #pragma unroll
    for (int q = 0; q < 8; ++q) wr[q] = wg4[q];
    float bc = b1[c];
    int r0 = rb * 128;
    float sum = 0.0f, sq = 0.0f;
    #pragma unroll 2
    for (int r = 0; r < 128; ++r){
        const float4* xr4 = (const float4*)(x + (size_t)(r0 + r) * 32);
        float a0 = 0, a1 = 0, a2 = 0, a3 = 0;
        #pragma unroll
        for (int q = 0; q < 8; ++q){
            float4 v = xr4[q];
            a0 = fmaf(v.x, wr[q].x, a0);
            a1 = fmaf(v.y, wr[q].y, a1);
            a2 = fmaf(v.z, wr[q].z, a2);
            a3 = fmaf(v.w, wr[q].w, a3);
        }
        float h = lrelu((a0 + a1) + (a2 + a3) + bc);
        sum += h; sq = fmaf(h, h, sq);
    }
    atomicAdd(&ws[S1_OFF + c], sum);
    atomicAdd(&ws[SQ1_OFF + c], sq);
}

// ---------- finalize BN1 affine, fold fc2 bias, build packed wtab ----------
__global__ __launch_bounds__(256) void k_fin1(const float* g1, const float* bb1,
                                              const float* w2, const float* b2,
                                              const float* b1, float* ws){
    int t = threadIdx.x;
    for (int k = t; k < 1024; k += 256){
        float mu  = ws[S1_OFF + k] * (1.0f/16384.0f);
        float var = ws[SQ1_OFF + k] * (1.0f/16384.0f) - mu*mu;
        float a1 = g1[k] / sqrtf(var + BNEPS);
        ws[A1_OFF + k] = a1;
        ws[C1_OFF + k] = bb1[k] - mu * a1;
    }
    __syncthreads();
    if (t < 10){
        float a = b2[t];
        for (int k = 0; k < 1024; ++k) a = fmaf(ws[C1_OFF + k], w2[t*1024 + k], a);
        ws[B2P_OFF + t] = a;
    }
    // wtab[kl*12 + j]: j<10 -> w2[j][kl]; j==10 -> a1[kl]; j==11 -> b1[kl]
    for (int idx = t; idx < 1024*12; idx += 256){
        int kl = idx / 12, j = idx - kl*12;
        float v;
        if (j < 10)      v = w2[j*1024 + kl];
        else if (j == 10) v = ws[A1_OFF + kl];
        else              v = b1[kl];
        ws[WTAB_OFF + idx] = v;
    }
}

// ---------- fc2: p_raw = lrelu((h1n)@W2^T + b2'), + BN2 stats ----------
// No LDS staging: w1 rows + wtab rows are wave-uniform broadcast loads.
// 512 threads = 8 waves; wave q owns k-eighth [q*128, q*128+128); 64 rows/block.
__global__ __launch_bounds__(512) void k_fc2(const float* x, const float* w1, float* ws){
    __shared__ float pacc[512*10];   // 20 KB
    int t = threadIdx.x;
    int r = t & 63;
    int q = t >> 6;                  // 0..7
    int row = blockIdx.x * 64 + r;
    const float4* xg4 = (const float4*)(x + (size_t)row * 32);
    float4 xr[8];
    #pragma unroll
    for (int i = 0; i < 8; ++i) xr[i] = xg4[i];
    float acc[10];
    #pragma unroll
    for (int j = 0; j < 10; ++j) acc[j] = 0.0f;
    const float4* w1g = (const float4*)w1;
    const float4* wt  = (const float4*)(ws + WTAB_OFF);
    #pragma unroll 2
    for (int kk = 0; kk < 128; ++kk){
        int kl = q*128 + kk;         // wave-uniform
        float a0 = 0, a1 = 0, a2 = 0, a3 = 0;
        #pragma unroll
        for (int i = 0; i < 8; ++i){
            float4 wv = w1g[kl*8 + i];
            float4 xv = xr[i];
            a0 = fmaf(xv.x, wv.x, a0);
            a1 = fmaf(xv.y, wv.y, a1);
            a2 = fmaf(xv.z, wv.z, a2);
            a3 = fmaf(xv.w, wv.w, a3);
        }
        float4 t0 = wt[kl*3+0], t1 = wt[kl*3+1], t2 = wt[kl*3+2];
        float h = lrelu((a0 + a1) + (a2 + a3) + t2.w) * t2.z;
        acc[0] = fmaf(h, t0.x, acc[0]); acc[1] = fmaf(h, t0.y, acc[1]);
        acc[2] = fmaf(h, t0.z, acc[2]); acc[3] = fmaf(h, t0.w, acc[3]);
        acc[4] = fmaf(h, t1.x, acc[4]); acc[5] = fmaf(h, t1.y, acc[5]);
        acc[6] = fmaf(h, t1.z, acc[6]); acc[7] = fmaf(h, t1.w, acc[7]);
        acc[8] = fmaf(h, t2.x, acc[8]); acc[9] = fmaf(h, t2.y, acc[9]);
    }
    #pragma unroll
    for (int j = 0; j < 10; ++j) pacc[t*10 + j] = acc[j];
    __syncthreads();
    if (t < 64){
        float pv[10];
        #pragma unroll
        for (int j = 0; j < 10; ++j){
            float a = ws[B2P_OFF + j];
            #pragma unroll
            for (int w = 0; w < 8; ++w) a += pacc[(w*64 + t)*10 + j];
            pv[j] = lrelu(a);
        }
        #pragma unroll
        for (int j = 0; j < 10; ++j) ws[PRAW_OFF + (size_t)(blockIdx.x*64 + t)*10 + j] = pv[j];
        float sv[10], qv[10];
        #pragma unroll
        for (int j = 0; j < 10; ++j){ sv[j] = pv[j]; qv[j] = pv[j]*pv[j]; }
        #pragma unroll
        for (int m = 1; m < 64; m <<= 1){
            #pragma unroll
            for (int j = 0; j < 10; ++j){
                sv[j] += __shfl_xor(sv[j], m);
                qv[j] += __shfl_xor(qv[j], m);
            }
        }
        if (t == 0){
            #pragma unroll
            for (int j = 0; j < 10; ++j){
                atomicAdd(&ws[S2_OFF + j], sv[j]);
                atomicAdd(&ws[SQ2_OFF + j], qv[j]);
            }
        }
    }
}

// ---------- batched IPM ----------
// 16 lanes/element, 4 elements/block (64-thread single-wave blocks).
// Identity-row contributions folded PRE-reduce via cndmask (no ds_bpermute
// broadcasts in the hot loop); rhs built directly (no rd[] array).
#define TIX(i,j) ((i)*((i)+1)/2 + (j))

#define STEPA(K, B, g) { \
    float sk = s[K], lk = lam[K]; \
    float r = sk - hhp[(K)*16]; \
    float w = lk * frcp(sk); \
    sl = fmaf(sk, lk, sl); \
    _Pragma("unroll") \
    for (int i = 0; i < B; ++i){ \
        lamG[i] = fmaf(lk, g[i], lamG[i]); \
        r = fmaf(z[i], g[i], r); \
    } \
    sRPp[K] = r; \
    _Pragma("unroll") \
    for (int i = 0; i < B; ++i){ \
        float wgi = w * g[i]; \
        _Pragma("unroll") \
        for (int j = 0; j <= i; ++j) Hm[TIX(i,j)] = fmaf(wgi, g[j], Hm[TIX(i,j)]); \
    } }

#define STEPB(K, B, g) { \
    float rpk = sRPp[K]; \
    float sk = s[K], lk = lam[K]; \
    float isk = frcp(sk); \
    float rc = fmaf(sk, lk, -smu); \
    float coef = isk * fmaf(lk, rpk, -rc); \
    _Pragma("unroll") \
    for (int i = 0; i < B; ++i) racc[i] = fmaf(coef, g[i], racc[i]); }

#define STEPC(K, B, g) { \
    float rpk = sRPp[K]; \
    float dot = 0.0f; \
    _Pragma("unroll") \
    for (int i = 0; i < B; ++i) dot = fmaf(dz[i], g[i], dot); \
    float dsk = -rpk - dot; \
    float sk = s[K], lk = lam[K]; \
    float isk = frcp(sk); \
    float rc = fmaf(sk, lk, -smu); \
    float dlk = -(rc + lk * dsk) * isk; \
    ds_[K] = dsk; dl_[K] = dlk; \
    float r1 = (dsk < 0.0f) ? sk * frcp(-dsk) : 3.0e38f; \
    float r2 = (dlk < 0.0f) ? lk * frcp(-dlk) : 3.0e38f; \
    amin = fminf(amin, fminf(r1, r2)); }

#define LDG(g, c, B) { _Pragma("unroll") for (int i = 0; i < B; ++i) g[i] = GB[(c)*12 + i]; }

__global__ __launch_bounds__(64) void k_ipm(const float* ws, const float* g2v, const float* bb2, float* out){
    __shared__ __align__(16) float sQm[120];
    __shared__ __align__(16) float sPV[4*12];
    __shared__ float sHH[128];
    __shared__ float sRP[64*9];
    int t = threadIdx.x;
    for (int i = t; i < 120; i += 64) sQm[i] = ws[QM_OFF + i];
    for (int i = t; i < 128; i += 64) sHH[i] = ws[H_OFF + 10 + i];
    if (t < 40){
        int e = t / 10, i = t - e*10;
        float mu  = ws[S2_OFF + i] * (1.0f/16384.0f);
        float var = ws[SQ2_OFF + i] * (1.0f/16384.0f) - mu*mu;
        float a2 = g2v[i] / sqrtf(var + BNEPS);
        float c2 = bb2[i] - mu * a2;
        int el = blockIdx.x * 4 + e;
        sPV[e*12 + i] = fmaf(ws[PRAW_OFF + (size_t)el*10 + i], a2, c2);
    }
    __syncthreads();

    int lg = t & 15;
    int eidx = t >> 4;
    int elem = blockIdx.x * 4 + eidx;
    const float* GB = ws + G_OFF;
    const float* hhp = sHH + lg;
    float* sRPp = sRP + t * 9;
    const float4* sQm4 = (const float4*)sQm;

    float g0[2], g1[2], g2r[4], g3[4], g4[6], g5[6], g6[8], g7[8];
    {
        int c = 10 + lg;   LDG(g0, c, 2);
        c = 10 + 16 + lg;  LDG(g1, c, 2);
        c = 10 + 32 + lg;  LDG(g2r, c, 4);
        c = 10 + 48 + lg;  LDG(g3, c, 4);
        c = 10 + 64 + lg;  LDG(g4, c, 6);
        c = 10 + 80 + lg;  LDG(g5, c, 6);
        c = 10 + 96 + lg;  LDG(g6, c, 8);
        c = 10 + 112 + lg; LDG(g7, c, 8);
    }
    float h8 = (lg < 10) ? ws[H_OFF + lg] : 1.0f;

    float z[10];
    #pragma unroll
    for (int i = 0; i < 10; ++i) z[i] = 0.0f;
    float s[9], lam[9];
    #pragma unroll
    for (int k = 0; k < 9; ++k){ s[k] = 1.0f; lam[k] = 1.0f; }
    lam[8] = (lg < 10) ? 1.0f : 0.0f;

    #pragma unroll 1
    for (int it = 0; it < ITERS; ++it){
        float lamG[8], Hm[55], sl = 0.0f, rp8;
        #pragma unroll
        for (int i = 0; i < 8; ++i) lamG[i] = 0.0f;
        #pragma unroll
        for (int i = 0; i < 36; ++i) Hm[i] = 0.0f;
        // ---- loop A (B_hat rows, compile-time col bounds)
        STEPA(0, 2, g0)  STEPA(1, 2, g1)
        STEPA(2, 4, g2r) STEPA(3, 4, g3)
        STEPA(4, 6, g4)  STEPA(5, 6, g5)
        STEPA(6, 8, g6)  STEPA(7, 8, g7)
        // ---- identity row (slot 8)
        float zs = z[0];
        #pragma unroll
        for (int i = 1; i < 10; ++i) zs = (lg == i) ? z[i] : zs;
        float w8;
        {
            float sk = s[8], lk = lam[8];
            rp8 = zs + sk - h8;
            sl = fmaf(sk, lk, sl);
            w8 = lk * frcp(sk);
        }
        // ---- fold identity contributions pre-reduce (cndmask, no broadcasts)
        float lamG8 = (lg == 8) ? lam[8] : 0.0f;
        float lamG9 = (lg == 9) ? lam[8] : 0.0f;
        #pragma unroll
        for (int i = 0; i < 8; ++i) lamG[i] += (lg == i) ? lam[8] : 0.0f;
        #pragma unroll
        for (int i = 0; i < 8; ++i) Hm[TIX(i,i)] += (lg == i) ? w8 : 0.0f;
        float d88 = (lg == 8) ? w8 : 0.0f;
        float d99 = (lg == 9) ? w8 : 0.0f;
        // ---- DPP all-reduce over the 16-lane group
        #pragma unroll
        for (int i = 0; i < 36; ++i) Hm[i] = red16_add(Hm[i]);
        #pragma unroll
        for (int i = 0; i < 8; ++i) lamG[i] = red16_add(lamG[i]);
        lamG8 = red16_add(lamG8); lamG9 = red16_add(lamG9);
        d88 = red16_add(d88);     d99 = red16_add(d99);
        sl = red16_add(sl);
        float smu = SIGMA_C * sl * (1.0f/138.0f);
        // ---- loop B: racc (+identity fold pre-reduce)
        float racc[8];
        #pragma unroll
        for (int i = 0; i < 8; ++i) racc[i] = 0.0f;
        STEPB(0, 2, g0)  STEPB(1, 2, g1)
        STEPB(2, 4, g2r) STEPB(3, 4, g3)
        STEPB(4, 6, g4)  STEPB(5, 6, g5)
        STEPB(6, 8, g6)  STEPB(7, 8, g7)
        float coef8;
        {
            float sk = s[8], lk = lam[8];
            float isk = frcp(sk);
            float rc = fmaf(sk, lk, -smu);
            coef8 = isk * fmaf(lk, rp8, -rc);
            coef8 = (lg < 10) ? coef8 : 0.0f;
        }
        #pragma unroll
        for (int i = 0; i < 8; ++i) racc[i] += (lg == i) ? coef8 : 0.0f;
        float racc8 = (lg == 8) ? coef8 : 0.0f;
        float racc9 = (lg == 9) ? coef8 : 0.0f;
        #pragma unroll
        for (int i = 0; i < 8; ++i) racc[i] = red16_add(racc[i]);
        racc8 = red16_add(racc8); racc9 = red16_add(racc9);
        // ---- rhs base = -(p + lamG + racc), then Q-pass subtracts Qz
        float rhs[10];
        {
            const float4* pv4 = (const float4*)(sPV + eidx*12);
            float4 pa = pv4[0], pb = pv4[1];
            const float2* pv2 = (const float2*)(sPV + eidx*12 + 8);
            float2 pc = pv2[0];
            rhs[0] = -(pa.x + lamG[0] + racc[0]); rhs[1] = -(pa.y + lamG[1] + racc[1]);
            rhs[2] = -(pa.z + lamG[2] + racc[2]); rhs[3] = -(pa.w + lamG[3] + racc[3]);
            rhs[4] = -(pb.x + lamG[4] + racc[4]); rhs[5] = -(pb.y + lamG[5] + racc[5]);
            rhs[6] = -(pb.z + lamG[6] + racc[6]); rhs[7] = -(pb.w + lamG[7] + racc[7]);
            rhs[8] = -(pc.x + lamG8 + racc8);     rhs[9] = -(pc.y + lamG9 + racc9);
        }
        #pragma unroll
        for (int j = 0; j < 10; ++j){
            float4 qa = sQm4[j*3+0], qb = sQm4[j*3+1], qc = sQm4[j*3+2];
            float q[10] = {qa.x,qa.y,qa.z,qa.w, qb.x,qb.y,qb.z,qb.w, qc.x,qc.y};
            float zj = z[j];
            #pragma unroll
            for (int i = 0; i < 10; ++i) rhs[i] = fmaf(-zj, q[i], rhs[i]);
            if (j < 8){
                #pragma unroll
                for (int i = 0; i <= j; ++i) Hm[TIX(j,i)] += q[i];
            } else {
                #pragma unroll
                for (int i = 0; i <= j; ++i) Hm[TIX(j,i)] = q[i];
            }
        }
        Hm[TIX(8,8)] += d88;
        Hm[TIX(9,9)] += d99;
        // ---- Cholesky (reciprocal diag in place)
        #pragma unroll
        for (int j = 0; j < 10; ++j){
            float d = Hm[TIX(j,j)];
            #pragma unroll
            for (int k2 = 0; k2 < j; ++k2){ float v = Hm[TIX(j,k2)]; d = fmaf(-v, v, d); }
            d = fmaxf(d, 1e-30f);
            float rinv = frsq(d);
            Hm[TIX(j,j)] = rinv;
            #pragma unroll
            for (int i = j+1; i < 10; ++i){
                float v2 = Hm[TIX(i,j)];
                #pragma unroll
                for (int k2 = 0; k2 < j; ++k2) v2 = fmaf(-Hm[TIX(i,k2)], Hm[TIX(j,k2)], v2);
                Hm[TIX(i,j)] = v2 * rinv;
            }
        }
        #pragma unroll
        for (int i = 0; i < 10; ++i){
            float v2 = rhs[i];
            #pragma unroll
            for (int k2 = 0; k2 < i; ++k2) v2 = fmaf(-Hm[TIX(i,k2)], rhs[k2], v2);
            rhs[i] = v2 * Hm[TIX(i,i)];
        }
        float dz[10];
        #pragma unroll
        for (int i = 9; i >= 0; --i){
            float v2 = rhs[i];
            #pragma unroll
            for (int k2 = i+1; k2 < 10; ++k2) v2 = fmaf(-Hm[TIX(k2,i)], dz[k2], v2);
            dz[i] = v2 * Hm[TIX(i,i)];
        }
        // ---- loop C: steps + alpha
        float ds_[9], dl_[9];
        float amin = 3.0e38f;
        STEPC(0, 2, g0)  STEPC(1, 2, g1)
        STEPC(2, 4, g2r) STEPC(3, 4, g3)
        STEPC(4, 6, g4)  STEPC(5, 6, g5)
        STEPC(6, 8, g6)  STEPC(7, 8, g7)
        {
            float dzs = dz[0];
            #pragma unroll
            for (int i = 1; i < 10; ++i) dzs = (lg == i) ? dz[i] : dzs;
            float dsk = -rp8 - dzs;
            bool val = lg < 10;
            dsk = val ? dsk : 0.0f;
            float sk = s[8], lk = lam[8];
            float isk = frcp(sk);
            float rc = fmaf(sk, lk, -smu);
            float dlk = -(rc + lk * dsk) * isk;
            dlk = val ? dlk : 0.0f;
            ds_[8] = dsk; dl_[8] = dlk;
            float r1 = (dsk < 0.0f) ? sk * frcp(-dsk) : 3.0e38f;
            float r2 = (dlk < 0.0f) ? lk * frcp(-dlk) : 3.0e38f;
            amin = fminf(amin, fminf(r1, r2));
        }
        amin = red16_min(amin);
        float alpha = fminf(1.0f, 0.99f * amin);
        // ---- updates
        #pragma unroll
        for (int i = 0; i < 10; ++i) z[i] = fmaf(alpha, dz[i], z[i]);
        #pragma unroll
        for (int k = 0; k < 9; ++k){
            s[k]   = fmaf(alpha, ds_[k], s[k]);
            lam[k] = fmaf(alpha, dl_[k], lam[k]);
        }
    }
    if (lg == 0) out[elem] = z[0];
}

extern "C" void kernel_launch(void* const* d_in, const int* in_sizes, int n_in,
                              void* d_out, int out_size, void* d_ws, size_t ws_size,
                              hipStream_t stream){
    const float* x   = (const float*)d_in[0];
    const float* w1  = (const float*)d_in[1];
    const float* b1  = (const float*)d_in[2];
    const float* w2  = (const float*)d_in[3];
    const float* b2  = (const float*)d_in[4];
    const float* g1  = (const float*)d_in[5];
    const float* bb1 = (const float*)d_in[6];
    const float* g2  = (const float*)d_in[7];
    const float* bb2 = (const float*)d_in[8];
    const float* L   = (const float*)d_in[9];
    const float* LP  = (const float*)d_in[10];
    const float* LR  = (const float*)d_in[11];
    const float* A   = (const float*)d_in[12];
    const float* Bm  = (const float*)d_in[13];
    const float* u0  = (const float*)d_in[14];
    const float* s0  = (const float*)d_in[15];
    float* ws  = (float*)d_ws;
    float* out = (float*)d_out;

    hipLaunchKernelGGL(k_build,  dim3(1),    dim3(256), 0, stream, L, LP, LR, A, Bm, u0, s0, ws);
    hipLaunchKernelGGL(k_stats1, dim3(512),  dim3(256), 0, stream, x, w1, b1, ws);
    hipLaunchKernelGGL(k_fin1,   dim3(1),    dim3(256), 0, stream, g1, bb1, w2, b2, b1, ws);
    hipLaunchKernelGGL(k_fc2,    dim3(256),  dim3(512), 0, stream, x, w1, ws);
    hipLaunchKernelGGL(k_ipm,    dim3(4096), dim3(64),  0, stream, ws, g2, bb2, out);
}

// Round 7
// 585.141 us; speedup vs baseline: 3.4714x; 1.0600x over previous
//
#include <hip/hip_runtime.h>
#include <math.h>

#define NIx 32
#define NOx 2
#define NUx 10
#define NHx 1024
#define NBx 16384
#define MIx 138
#define EPSQ 1e-4f
#define BNEPS 1e-5f
#define ITERS 30
#define SLOPE 0.2f
#define SIGMA_C 0.1f

// workspace layout (float offsets). Total 180736 floats = 723 KB (<= proven size).
// P1 (stats1 partials) lifetime ends at k_fin1; PRAW born at k_fc2 -> OVERLAP them.
#define QM_OFF 0        // 120 (pad 128)
#define G_OFF 128       // 144 x 12
#define H_OFF 1856      // 144 (pad 2048)
#define A1_OFF 2048     // 1024
#define C1_OFF 3072     // 1024
#define B2P_OFF 4096    // 10 (pad 16)
#define A2_OFF 4112     // 10 (pad 16)
#define C2_OFF 4128     // 10 (pad to 4160)
#define P2_OFF 4160     // 16 buffers x 20 (sum[10],sq[10]) = 320 (pad 448 -> 4608)
#define WTAB_OFF 4608   // 1024 x 12 -> 16896
#define P1S_OFF 16896   // 16 buffers x 1024 col-sums     (dies at k_fin1)
#define P1Q_OFF 33280   // 16 buffers x 1024 col-sumsq -> 49664
#define PRAW_OFF 16896  // 16384 x 10 -> 180736 (overlaps P1; lifetime-disjoint)

__device__ __forceinline__ float frcp(float x){ return __builtin_amdgcn_rcpf(x); }
__device__ __forceinline__ float frsq(float x){ return __builtin_amdgcn_rsqf(x); }
__device__ __forceinline__ float lrelu(float x){ return x > 0.0f ? x : SLOPE * x; }

// ---- DPP 16-lane reductions (VALU, no LDS pipe) ----
template<int CTRL>
__device__ __forceinline__ float dpp_mov(float x){
    int y = __builtin_amdgcn_update_dpp(0, __float_as_int(x), CTRL, 0xF, 0xF, true);
    return __int_as_float(y);
}
__device__ __forceinline__ float red16_add(float x){
    x += dpp_mov<0xB1>(x);
    x += dpp_mov<0x4E>(x);
    x += dpp_mov<0x124>(x);
    x += dpp_mov<0x128>(x);
    return x;
}
__device__ __forceinline__ float red16_max(float x){
    x = fmaxf(x, dpp_mov<0xB1>(x));
    x = fmaxf(x, dpp_mov<0x4E>(x));
    x = fmaxf(x, dpp_mov<0x124>(x));
    x = fmaxf(x, dpp_mov<0x128>(x));
    return x;
}

// ---------- build Q_hat, G, h (one block); zeroes partial-accumulator regions ----------
__global__ __launch_bounds__(256) void k_build(const float* L, const float* LP, const float* LR,
                                               const float* A, const float* Bm,
                                               const float* u0, const float* s0, float* ws){
    __shared__ float sL[1024], sLP[1024], sA[1024], sQ[1024], sP[1024];
    __shared__ float sPow[4][64];
    __shared__ float sBh[128*10];
    __shared__ float sQB[128*10];
    __shared__ float sR[3];
    int t = threadIdx.x;
    // zero P2 (448) + P1 (32768) partials, vectorized
    {
        float4 zz = {0,0,0,0};
        float4* p2 = (float4*)(ws + P2_OFF);
        for (int i = t; i < 112; i += 256) p2[i] = zz;
        float4* p1 = (float4*)(ws + P1S_OFF);
        for (int i = t; i < 8192; i += 256) p1[i] = zz;
    }
    for (int idx = t; idx < 1024; idx += 256){
        int i = idx >> 5, j = idx & 31;
        sL[idx]  = (j <= i) ? L[idx]  : 0.0f;
        sLP[idx] = (j <= i) ? LP[idx] : 0.0f;
        sA[idx]  = A[idx];
    }
    if (t < 64) sPow[0][t] = Bm[t];
    if (t == 0){
        float a = LR[0], b = LR[2], c = LR[3];   // tril: [[a,0],[b,c]]
        sR[0] = a*a + EPSQ; sR[1] = a*b; sR[2] = b*b + c*c + EPSQ;
    }
    __syncthreads();
    for (int idx = t; idx < 1024; idx += 256){
        int i = idx >> 5, j = idx & 31;
        float q = 0.0f, p = 0.0f;
        for (int k = 0; k < 32; ++k){
            q = fmaf(sL[i*32+k],  sL[j*32+k],  q);
            p = fmaf(sLP[i*32+k], sLP[j*32+k], p);
        }
        if (i == j){ q += EPSQ; p += EPSQ; }
        sQ[idx] = q; sP[idx] = p;
    }
    for (int kp = 1; kp < 4; ++kp){
        __syncthreads();
        if (t < 64){
            int i = t >> 1, c = t & 1;
            float a = 0.0f;
            for (int j = 0; j < 32; ++j) a = fmaf(sA[i*32+j], sPow[kp-1][j*2+c], a);
            sPow[kp][t] = a;
        }
    }
    __syncthreads();
    for (int idx = t; idx < 1280; idx += 256){
        int r = idx / 10, c = idx % 10;
        int bi = r >> 5, ri = r & 31, bj = c >> 1, cj = c & 1;
        sBh[idx] = (bj <= bi) ? sPow[bi-bj][ri*2+cj] : 0.0f;
    }
    __syncthreads();
    for (int idx = t; idx < 1280; idx += 256){
        int r = idx / 10, c = idx % 10;
        int bi = r >> 5, ri = r & 31;
        const float* Qd = (bi < 3) ? sQ : sP;
        float a = 0.0f;
        for (int k = 0; k < 32; ++k) a = fmaf(Qd[ri*32+k], sBh[(bi*32+k)*10+c], a);
        sQB[idx] = a;
    }
    __syncthreads();
    if (t < 120){
        int i = t / 12, j = t % 12;
        float a = 0.0f;
        if (j < 10){
            for (int r = 0; r < 128; ++r) a = fmaf(sBh[r*10+i], sQB[r*10+j], a);
            if ((i >> 1) == (j >> 1)) a += sR[(i&1)+(j&1)];
        }
        ws[QM_OFF + t] = a;
    }
    for (int idx = t; idx < 144*12; idx += 256){
        int m = idx / 12, i = idx % 12;
        float v = 0.0f;
        if (i < 10 && m < MIx) v = (m < 10) ? ((i == m) ? 1.0f : 0.0f) : sBh[(m-10)*10 + i];
        ws[G_OFF + idx] = v;
    }
    for (int m = t; m < 144; m += 256){
        float hv = 0.0f;
        if (m < MIx){
            hv = s0[m];
            if (m < 10) hv += u0[m];
            else { for (int i = 0; i < 10; ++i) hv = fmaf(sBh[(m-10)*10+i], u0[i], hv); }
        }
        ws[H_OFF + m] = hv;
    }
}

// ---------- BN1 stats: partial col sum/sumsq into 16 spread buffers (8-way contention) ----------
__global__ __launch_bounds__(256) void k_stats1(const float* x, const float* w1, const float* b1, float* ws){
    int t = threadIdx.x;
    int rb = blockIdx.x >> 2;        // 128 row-groups of 128 rows
    int cb = blockIdx.x & 3;         // 4 col-groups of 256 cols
    int c = cb * 256 + t;
    const float4* wg4 = (const float4*)(w1 + (size_t)c * 32);
    float4 wr[8];
    #pragma unroll
    for (int q = 0; q < 8; ++q) wr[q] = wg4[q];
    float bc = b1[c];
    int r0 = rb * 128;
    float sum = 0.0f, sq = 0.0f;
    #pragma unroll 2
    for (int r = 0; r < 128; ++r){
        const float4* xr4 = (const float4*)(x + (size_t)(r0 + r) * 32);
        float a0 = 0, a1 = 0, a2 = 0, a3 = 0;
        #pragma unroll
        for (int q = 0; q < 8; ++q){
            float4 v = xr4[q];
            a0 = fmaf(v.x, wr[q].x, a0);
            a1 = fmaf(v.y, wr[q].y, a1);
            a2 = fmaf(v.z, wr[q].z, a2);
            a3 = fmaf(v.w, wr[q].w, a3);
        }
        float h = lrelu((a0 + a1) + (a2 + a3) + bc);
        sum += h; sq = fmaf(h, h, sq);
    }
    int buf = (rb & 15) * 1024 + c;
    atomicAdd(&ws[P1S_OFF + buf], sum);
    atomicAdd(&ws[P1Q_OFF + buf], sq);
}

// ---------- finalize BN1 affine (reduce 16 partials), fold fc2 bias, build packed wtab ----------
__global__ __launch_bounds__(256) void k_fin1(const float* g1, const float* bb1,
                                              const float* w2, const float* b2,
                                              const float* b1, float* ws){
    int t = threadIdx.x;
    for (int k = t; k < 1024; k += 256){
        float ssum = 0.0f, qsum = 0.0f;
        #pragma unroll
        for (int b = 0; b < 16; ++b){
            ssum += ws[P1S_OFF + b*1024 + k];
            qsum += ws[P1Q_OFF + b*1024 + k];
        }
        float mu  = ssum * (1.0f/16384.0f);
        float var = qsum * (1.0f/16384.0f) - mu*mu;
        float a1 = g1[k] / sqrtf(var + BNEPS);
        ws[A1_OFF + k] = a1;
        ws[C1_OFF + k] = bb1[k] - mu * a1;
    }
    __syncthreads();
    if (t < 10){
        float a = b2[t];
        for (int k = 0; k < 1024; ++k) a = fmaf(ws[C1_OFF + k], w2[t*1024 + k], a);
        ws[B2P_OFF + t] = a;
    }
    // wtab[kl*12 + j]: j<10 -> w2[j][kl]; j==10 -> a1[kl]; j==11 -> b1[kl]
    for (int idx = t; idx < 1024*12; idx += 256){
        int kl = idx / 12, j = idx - kl*12;
        float v;
        if (j < 10)      v = w2[j*1024 + kl];
        else if (j == 10) v = ws[A1_OFF + kl];
        else              v = b1[kl];
        ws[WTAB_OFF + idx] = v;
    }
}

// ---------- fc2: p_raw + BN2 partial stats into 16 spread buffers ----------
__global__ __launch_bounds__(512) void k_fc2(const float* x, const float* w1, float* ws){
    __shared__ float pacc[512*10];   // 20 KB
    int t = threadIdx.x;
    int r = t & 63;
    int q = t >> 6;                  // 0..7
    int row = blockIdx.x * 64 + r;
    const float4* xg4 = (const float4*)(x + (size_t)row * 32);
    float4 xr[8];
    #pragma unroll
    for (int i = 0; i < 8; ++i) xr[i] = xg4[i];
    float acc[10];
    #pragma unroll
    for (int j = 0; j < 10; ++j) acc[j] = 0.0f;
    const float4* w1g = (const float4*)w1;
    const float4* wt  = (const float4*)(ws + WTAB_OFF);
    #pragma unroll 2
    for (int kk = 0; kk < 128; ++kk){
        int kl = q*128 + kk;         // wave-uniform
        float a0 = 0, a1 = 0, a2 = 0, a3 = 0;
        #pragma unroll
        for (int i = 0; i < 8; ++i){
            float4 wv = w1g[kl*8 + i];
            float4 xv = xr[i];
            a0 = fmaf(xv.x, wv.x, a0);
            a1 = fmaf(xv.y, wv.y, a1);
            a2 = fmaf(xv.z, wv.z, a2);
            a3 = fmaf(xv.w, wv.w, a3);
        }
        float4 t0 = wt[kl*3+0], t1 = wt[kl*3+1], t2 = wt[kl*3+2];
        float h = lrelu((a0 + a1) + (a2 + a3) + t2.w) * t2.z;
        acc[0] = fmaf(h, t0.x, acc[0]); acc[1] = fmaf(h, t0.y, acc[1]);
        acc[2] = fmaf(h, t0.z, acc[2]); acc[3] = fmaf(h, t0.w, acc[3]);
        acc[4] = fmaf(h, t1.x, acc[4]); acc[5] = fmaf(h, t1.y, acc[5]);
        acc[6] = fmaf(h, t1.z, acc[6]); acc[7] = fmaf(h, t1.w, acc[7]);
        acc[8] = fmaf(h, t2.x, acc[8]); acc[9] = fmaf(h, t2.y, acc[9]);
    }
    #pragma unroll
    for (int j = 0; j < 10; ++j) pacc[t*10 + j] = acc[j];
    __syncthreads();
    if (t < 64){
        float pv[10];
        #pragma unroll
        for (int j = 0; j < 10; ++j){
            float a = ws[B2P_OFF + j];
            #pragma unroll
            for (int w = 0; w < 8; ++w) a += pacc[(w*64 + t)*10 + j];
            pv[j] = lrelu(a);
        }
        #pragma unroll
        for (int j = 0; j < 10; ++j) ws[PRAW_OFF + (size_t)(blockIdx.x*64 + t)*10 + j] = pv[j];
        float sv[10], qv[10];
        #pragma unroll
        for (int j = 0; j < 10; ++j){ sv[j] = pv[j]; qv[j] = pv[j]*pv[j]; }
        #pragma unroll
        for (int m = 1; m < 64; m <<= 1){
            #pragma unroll
            for (int j = 0; j < 10; ++j){
                sv[j] += __shfl_xor(sv[j], m);
                qv[j] += __shfl_xor(qv[j], m);
            }
        }
        if (t == 0){
            int base = P2_OFF + (blockIdx.x & 15) * 20;   // 16 contributors/address
            #pragma unroll
            for (int j = 0; j < 10; ++j){
                atomicAdd(&ws[base + j], sv[j]);
                atomicAdd(&ws[base + 10 + j], qv[j]);
            }
        }
    }
}

// ---------- finalize BN2: reduce 16 partial buffers, precompute a2/c2 ----------
__global__ __launch_bounds__(64) void k_fin2(const float* g2v, const float* bb2, float* ws){
    int t = threadIdx.x;
    if (t < 10){
        float ssum = 0.0f, qsum = 0.0f;
        #pragma unroll
        for (int b = 0; b < 16; ++b){
            ssum += ws[P2_OFF + b*20 + t];
            qsum += ws[P2_OFF + b*20 + 10 + t];
        }
        float mu  = ssum * (1.0f/16384.0f);
        float var = qsum * (1.0f/16384.0f) - mu*mu;
        float a2 = g2v[t] / sqrtf(var + BNEPS);
        ws[A2_OFF + t] = a2;
        ws[C2_OFF + t] = bb2[t] - mu * a2;
    }
}

// ---------- batched IPM ----------
// 16 lanes/element, 4 elements/block. isk cached in LDS (-16 frcp/iter); alpha via
// max-of-inverse-ratios (-15 frcp, -16 cndmask/iter); g6/g7 in LDS with transient
// per-loop reloads (targets VGPR <=170 -> 3 waves/SIMD; round-6 was 184 -> 2).
#define TIX(i,j) ((i)*((i)+1)/2 + (j))

#define STEPA(K, B, g) { \
    float sk = s[K], lk = lam[K]; \
    float isk = frcp(sk); \
    float r = sk - hhp[(K)*16]; \
    float w = lk * isk; \
    sl = fmaf(sk, lk, sl); \
    _Pragma("unroll") \
    for (int i = 0; i < B; ++i){ \
        lamG[i] = fmaf(lk, g[i], lamG[i]); \
        r = fmaf(z[i], g[i], r); \
    } \
    sRPp[K] = r; sISp[K] = isk; \
    _Pragma("unroll") \
    for (int i = 0; i < B; ++i){ \
        float wgi = w * g[i]; \
        _Pragma("unroll") \
        for (int j = 0; j <= i; ++j) Hm[TIX(i,j)] = fmaf(wgi, g[j], Hm[TIX(i,j)]); \
    } }

#define STEPB(K, B, g) { \
    float rpk = sRPp[K]; \
    float isk = sISp[K]; \
    float sk = s[K], lk = lam[K]; \
    float rc = fmaf(sk, lk, -smu); \
    float coef = isk * fmaf(lk, rpk, -rc); \
    _Pragma("unroll") \
    for (int i = 0; i < B; ++i) racc[i] = fmaf(coef, g[i], racc[i]); }

#define STEPC(K, B, g) { \
    float rpk = sRPp[K]; \
    float isk = sISp[K]; \
    float dot = 0.0f; \
    _Pragma("unroll") \
    for (int i = 0; i < B; ++i) dot = fmaf(dz[i], g[i], dot); \
    float dsk = -rpk - dot; \
    float sk = s[K], lk = lam[K]; \
    float rc = fmaf(sk, lk, -smu); \
    float dlk = -(rc + lk * dsk) * isk; \
    ds_[K] = dsk; dl_[K] = dlk; \
    float ilk = frcp(lk); \
    ainv = fmaxf(ainv, fmaxf(-dsk * isk, -dlk * ilk)); }

#define LDG(g, c, B) { _Pragma("unroll") for (int i = 0; i < B; ++i) g[i] = GB[(c)*12 + i]; }

#define LOAD_G6(arr) float arr[8]; { const float4* _gq = (const float4*)(sG67 + t*16); \
    float4 _a = _gq[0], _b = _gq[1]; \
    arr[0]=_a.x; arr[1]=_a.y; arr[2]=_a.z; arr[3]=_a.w; arr[4]=_b.x; arr[5]=_b.y; arr[6]=_b.z; arr[7]=_b.w; }
#define LOAD_G7(arr) float arr[8]; { const float4* _gq = (const float4*)(sG67 + t*16); \
    float4 _a = _gq[2], _b = _gq[3]; \
    arr[0]=_a.x; arr[1]=_a.y; arr[2]=_a.z; arr[3]=_a.w; arr[4]=_b.x; arr[5]=_b.y; arr[6]=_b.z; arr[7]=_b.w; }

__global__ __launch_bounds__(64) void k_ipm(const float* ws, float* out){
    __shared__ __align__(16) float sQm[120];
    __shared__ __align__(16) float sPV[4*12];
    __shared__ float sHH[128];
    __shared__ float sRP[64*9];
    __shared__ float sIS[64*9];
    __shared__ __align__(16) float sG67[64*16];
    int t = threadIdx.x;
    for (int i = t; i < 120; i += 64) sQm[i] = ws[QM_OFF + i];
    for (int i = t; i < 128; i += 64) sHH[i] = ws[H_OFF + 10 + i];
    if (t < 40){
        int e = t / 10, i = t - e*10;
        int el = blockIdx.x * 4 + e;
        sPV[e*12 + i] = fmaf(ws[PRAW_OFF + (size_t)el*10 + i], ws[A2_OFF + i], ws[C2_OFF + i]);
    }

    int lg = t & 15;
    int eidx = t >> 4;
    int elem = blockIdx.x * 4 + eidx;
    const float* GB = ws + G_OFF;
    const float* hhp = sHH + lg;
    float* sRPp = sRP + t * 9;
    float* sISp = sIS + t * 9;
    const float4* sQm4 = (const float4*)sQm;

    float g0[2], g1[2], g2r[4], g3[4], g4[6], g5[6];
    {
        int c = 10 + lg;   LDG(g0, c, 2);
        c = 10 + 16 + lg;  LDG(g1, c, 2);
        c = 10 + 32 + lg;  LDG(g2r, c, 4);
        c = 10 + 48 + lg;  LDG(g3, c, 4);
        c = 10 + 64 + lg;  LDG(g4, c, 6);
        c = 10 + 80 + lg;  LDG(g5, c, 6);
        #pragma unroll
        for (int i = 0; i < 8; ++i) sG67[t*16 + i]     = GB[(10 + 96 + lg)*12 + i];
        #pragma unroll
        for (int i = 0; i < 8; ++i) sG67[t*16 + 8 + i] = GB[(10 + 112 + lg)*12 + i];
    }
    float h8 = (lg < 10) ? ws[H_OFF + lg] : 1.0f;
    __syncthreads();

    float z[10];
    #pragma unroll
    for (int i = 0; i < 10; ++i) z[i] = 0.0f;
    float s[9], lam[9];
    #pragma unroll
    for (int k = 0; k < 9; ++k){ s[k] = 1.0f; lam[k] = 1.0f; }
    lam[8] = (lg < 10) ? 1.0f : 0.0f;

    #pragma unroll 1
    for (int it = 0; it < ITERS; ++it){
        float lamG[8], Hm[55], sl = 0.0f, rp8;
        #pragma unroll
        for (int i = 0; i < 8; ++i) lamG[i] = 0.0f;
        #pragma unroll
        for (int i = 0; i < 36; ++i) Hm[i] = 0.0f;
        // ---- loop A (B_hat rows, compile-time col bounds)
        STEPA(0, 2, g0)  STEPA(1, 2, g1)
        STEPA(2, 4, g2r) STEPA(3, 4, g3)
        STEPA(4, 6, g4)  STEPA(5, 6, g5)
        { LOAD_G6(g6v) STEPA(6, 8, g6v) }
        { LOAD_G7(g7v) STEPA(7, 8, g7v) }
        // ---- identity row (slot 8)
        float zs = z[0];
        #pragma unroll
        for (int i = 1; i < 10; ++i) zs = (lg == i) ? z[i] : zs;
        float w8;
        {
            float sk = s[8], lk = lam[8];
            rp8 = zs + sk - h8;
            sl = fmaf(sk, lk, sl);
            w8 = lk * frcp(sk);
        }
        // ---- fold identity contributions pre-reduce
        float lamG8 = (lg == 8) ? lam[8] : 0.0f;
        float lamG9 = (lg == 9) ? lam[8] : 0.0f;
        #pragma unroll
        for (int i = 0; i < 8; ++i) lamG[i] += (lg == i) ? lam[8] : 0.0f;
        #pragma unroll
        for (int i = 0; i < 8; ++i) Hm[TIX(i,i)] += (lg == i) ? w8 : 0.0f;
        float d88 = (lg == 8) ? w8 : 0.0f;
        float d99 = (lg == 9) ? w8 : 0.0f;
        // ---- DPP all-reduce
        #pragma unroll
        for (int i = 0; i < 36; ++i) Hm[i] = red16_add(Hm[i]);
        #pragma unroll
        for (int i = 0; i < 8; ++i) lamG[i] = red16_add(lamG[i]);
        lamG8 = red16_add(lamG8); lamG9 = red16_add(lamG9);
        d88 = red16_add(d88);     d99 = red16_add(d99);
        sl = red16_add(sl);
        float smu = SIGMA_C * sl * (1.0f/138.0f);
        __asm__ __volatile__("" ::: "memory");   // force LDS reload (keep g6/g7 transient)
        // ---- loop B: racc
        float racc[8];
        #pragma unroll
        for (int i = 0; i < 8; ++i) racc[i] = 0.0f;
        STEPB(0, 2, g0)  STEPB(1, 2, g1)
        STEPB(2, 4, g2r) STEPB(3, 4, g3)
        STEPB(4, 6, g4)  STEPB(5, 6, g5)
        { LOAD_G6(g6v) STEPB(6, 8, g6v) }
        { LOAD_G7(g7v) STEPB(7, 8, g7v) }
        float coef8;
        {
            float sk = s[8], lk = lam[8];
            float isk = frcp(sk);
            float rc = fmaf(sk, lk, -smu);
            coef8 = isk * fmaf(lk, rp8, -rc);
            coef8 = (lg < 10) ? coef8 : 0.0f;
        }
        #pragma unroll
        for (int i = 0; i < 8; ++i) racc[i] += (lg == i) ? coef8 : 0.0f;
        float racc8 = (lg == 8) ? coef8 : 0.0f;
        float racc9 = (lg == 9) ? coef8 : 0.0f;
        #pragma unroll
        for (int i = 0; i < 8; ++i) racc[i] = red16_add(racc[i]);
        racc8 = red16_add(racc8); racc9 = red16_add(racc9);
        // ---- rhs base = -(p + lamG + racc); Q-pass subtracts Qz, H += Q
        float rhs[10];
        {
            const float4* pv4 = (const float4*)(sPV + eidx*12);
            float4 pa = pv4[0], pb = pv4[1];
            const float2* pv2 = (const float2*)(sPV + eidx*12 + 8);
            float2 pc = pv2[0];
            rhs[0] = -(pa.x + lamG[0] + racc[0]); rhs[1] = -(pa.y + lamG[1] + racc[1]);
            rhs[2] = -(pa.z + lamG[2] + racc[2]); rhs[3] = -(pa.w + lamG[3] + racc[3]);
            rhs[4] = -(pb.x + lamG[4] + racc[4]); rhs[5] = -(pb.y + lamG[5] + racc[5]);
            rhs[6] = -(pb.z + lamG[6] + racc[6]); rhs[7] = -(pb.w + lamG[7] + racc[7]);
            rhs[8] = -(pc.x + lamG8 + racc8);     rhs[9] = -(pc.y + lamG9 + racc9);
        }
        #pragma unroll
        for (int j = 0; j < 10; ++j){
            float4 qa = sQm4[j*3+0], qb = sQm4[j*3+1], qc = sQm4[j*3+2];
            float q[10] = {qa.x,qa.y,qa.z,qa.w, qb.x,qb.y,qb.z,qb.w, qc.x,qc.y};
            float zj = z[j];
            #pragma unroll
            for (int i = 0; i < 10; ++i) rhs[i] = fmaf(-zj, q[i], rhs[i]);
            if (j < 8){
                #pragma unroll
                for (int i = 0; i <= j; ++i) Hm[TIX(j,i)] += q[i];
            } else {
                #pragma unroll
                for (int i = 0; i <= j; ++i) Hm[TIX(j,i)] = q[i];
            }
        }
        Hm[TIX(8,8)] += d88;
        Hm[TIX(9,9)] += d99;
        // ---- Cholesky (reciprocal diag in place)
        #pragma unroll
        for (int j = 0; j < 10; ++j){
            float d = Hm[TIX(j,j)];
            #pragma unroll
            for (int k2 = 0; k2 < j; ++k2){ float v = Hm[TIX(j,k2)]; d = fmaf(-v, v, d); }
            d = fmaxf(d, 1e-30f);
            float rinv = frsq(d);
            Hm[TIX(j,j)] = rinv;
            #pragma unroll
            for (int i = j+1; i < 10; ++i){
                float v2 = Hm[TIX(i,j)];
                #pragma unroll
                for (int k2 = 0; k2 < j; ++k2) v2 = fmaf(-Hm[TIX(i,k2)], Hm[TIX(j,k2)], v2);
                Hm[TIX(i,j)] = v2 * rinv;
            }
        }
        #pragma unroll
        for (int i = 0; i < 10; ++i){
            float v2 = rhs[i];
            #pragma unroll
            for (int k2 = 0; k2 < i; ++k2) v2 = fmaf(-Hm[TIX(i,k2)], rhs[k2], v2);
            rhs[i] = v2 * Hm[TIX(i,i)];
        }
        float dz[10];
        #pragma unroll
        for (int i = 9; i >= 0; --i){
            float v2 = rhs[i];
            #pragma unroll
            for (int k2 = i+1; k2 < 10; ++k2) v2 = fmaf(-Hm[TIX(k2,i)], dz[k2], v2);
            dz[i] = v2 * Hm[TIX(i,i)];
        }
        __asm__ __volatile__("" ::: "memory");   // force LDS reload for loop C
        // ---- loop C: steps + alpha (max-of-inverse-ratios form)
        float ds_[9], dl_[9];
        float ainv = 0.0f;
        STEPC(0, 2, g0)  STEPC(1, 2, g1)
        STEPC(2, 4, g2r) STEPC(3, 4, g3)
        STEPC(4, 6, g4)  STEPC(5, 6, g5)
        { LOAD_G6(g6v) STEPC(6, 8, g6v) }
        { LOAD_G7(g7v) STEPC(7, 8, g7v) }
        {
            float dzs = dz[0];
            #pragma unroll
            for (int i = 1; i < 10; ++i) dzs = (lg == i) ? dz[i] : dzs;
            bool val = lg < 10;
            float dsk = val ? (-rp8 - dzs) : 0.0f;
            float sk = s[8], lk = lam[8];
            float isk = frcp(sk);
            float rc = fmaf(sk, lk, -smu);
            float dlk = -(rc + lk * dsk) * isk;
            dlk = val ? dlk : 0.0f;
            ds_[8] = dsk; dl_[8] = dlk;
            float cand = fmaxf(-dsk * isk, -dlk * frcp(lk));
            ainv = fmaxf(ainv, val ? cand : 0.0f);
        }
        ainv = red16_max(ainv);
        float alpha = fminf(1.0f, 0.99f * frcp(fmaxf(ainv, 1e-30f)));
        // ---- updates
        #pragma unroll
        for (int i = 0; i < 10; ++i) z[i] = fmaf(alpha, dz[i], z[i]);
        #pragma unroll
        for (int k = 0; k < 9; ++k){
            s[k]   = fmaf(alpha, ds_[k], s[k]);
            lam[k] = fmaf(alpha, dl_[k], lam[k]);
        }
    }
    if (lg == 0) out[elem] = z[0];
}

extern "C" void kernel_launch(void* const* d_in, const int* in_sizes, int n_in,
                              void* d_out, int out_size, void* d_ws, size_t ws_size,
                              hipStream_t stream){
    const float* x   = (const float*)d_in[0];
    const float* w1  = (const float*)d_in[1];
    const float* b1  = (const float*)d_in[2];
    const float* w2  = (const float*)d_in[3];
    const float* b2  = (const float*)d_in[4];
    const float* g1  = (const float*)d_in[5];
    const float* bb1 = (const float*)d_in[6];
    const float* g2  = (const float*)d_in[7];
    const float* bb2 = (const float*)d_in[8];
    const float* L   = (const float*)d_in[9];
    const float* LP  = (const float*)d_in[10];
    const float* LR  = (const float*)d_in[11];
    const float* A   = (const float*)d_in[12];
    const float* Bm  = (const float*)d_in[13];
    const float* u0  = (const float*)d_in[14];
    const float* s0  = (const float*)d_in[15];
    float* ws  = (float*)d_ws;
    float* out = (float*)d_out;

    hipLaunchKernelGGL(k_build,  dim3(1),    dim3(256), 0, stream, L, LP, LR, A, Bm, u0, s0, ws);
    hipLaunchKernelGGL(k_stats1, dim3(512),  dim3(256), 0, stream, x, w1, b1, ws);
    hipLaunchKernelGGL(k_fin1,   dim3(1),    dim3(256), 0, stream, g1, bb1, w2, b2, b1, ws);
    hipLaunchKernelGGL(k_fc2,    dim3(256),  dim3(512), 0, stream, x, w1, ws);
    hipLaunchKernelGGL(k_fin2,   dim3(1),    dim3(64),  0, stream, g2, bb2, ws);
    hipLaunchKernelGGL(k_ipm,    dim3(4096), dim3(64),  0, stream, ws, out);
}

// Round 8
// 548.643 us; speedup vs baseline: 3.7023x; 1.0665x over previous
//
#include <hip/hip_runtime.h>
#include <math.h>

#define NIx 32
#define NOx 2
#define NUx 10
#define NHx 1024
#define NBx 16384
#define MIx 138
#define EPSQ 1e-4f
#define BNEPS 1e-5f
#define ITERS 30
#define SLOPE 0.2f
#define SIGMA_C 0.1f

// workspace layout (float offsets). Max = 174400 floats = 697.6 KB (< proven 723 KB).
#define QM_OFF 0        // 120 (pad 128)
#define G_OFF 128       // 144 x 12 -> 1856
#define H_OFF 1856      // 144 (pad 2048)
#define P2_OFF 2048     // 16 bufs x 20 (sum[10],sq[10]) = 320 (pad 2368)
#define P1S_OFF 2368    // 4 bufs x 1024 col-sums
#define P1Q_OFF 6464    // 4 bufs x 1024 col-sumsq -> 10560
#define PRAW_OFF 10560  // 16384 x 10 -> 174400
// memset zeroes [P2_OFF, P1Q_OFF+4096) = floats 2048..10560

__device__ __forceinline__ float frcp(float x){ return __builtin_amdgcn_rcpf(x); }
__device__ __forceinline__ float frsq(float x){ return __builtin_amdgcn_rsqf(x); }
__device__ __forceinline__ float lrelu(float x){ return x > 0.0f ? x : SLOPE * x; }

// ---- DPP 16-lane reductions (VALU, no LDS pipe) ----
template<int CTRL>
__device__ __forceinline__ float dpp_mov(float x){
    int y = __builtin_amdgcn_update_dpp(0, __float_as_int(x), CTRL, 0xF, 0xF, true);
    return __int_as_float(y);
}
__device__ __forceinline__ float red16_add(float x){
    x += dpp_mov<0xB1>(x);
    x += dpp_mov<0x4E>(x);
    x += dpp_mov<0x124>(x);
    x += dpp_mov<0x128>(x);
    return x;
}
__device__ __forceinline__ float red16_max(float x){
    x = fmaxf(x, dpp_mov<0xB1>(x));
    x = fmaxf(x, dpp_mov<0x4E>(x));
    x = fmaxf(x, dpp_mov<0x124>(x));
    x = fmaxf(x, dpp_mov<0x128>(x));
    return x;
}

// ---------- merged: blocks 0..511 BN1-stats, block 512 QP-build (independent work) ----------
__global__ __launch_bounds__(256) void k_buildstats(const float* L, const float* LP, const float* LR,
                                                    const float* A, const float* Bm,
                                                    const float* u0, const float* s0,
                                                    const float* x, const float* w1, const float* b1,
                                                    float* ws){
    __shared__ float sL[1024], sLP[1024], sA[1024], sQ[1024], sP[1024];
    __shared__ float sPow[4][64];
    __shared__ float sBh[128*10];
    __shared__ float sQB[128*10];
    __shared__ float sR[3];
    int t = threadIdx.x;
    if (blockIdx.x < 512){
        // ---- BN1 stats path: partial col sum/sumsq into 4 spread buffers ----
        int rb = blockIdx.x >> 2;        // 128 row-groups of 128 rows
        int cb = blockIdx.x & 3;         // 4 col-groups of 256 cols
        int c = cb * 256 + t;
        const float4* wg4 = (const float4*)(w1 + (size_t)c * 32);
        float4 wr[8];
        #pragma unroll
        for (int q = 0; q < 8; ++q) wr[q] = wg4[q];
        float bc = b1[c];
        int r0 = rb * 128;
        float sum = 0.0f, sq = 0.0f;
        #pragma unroll 2
        for (int r = 0; r < 128; ++r){
            const float4* xr4 = (const float4*)(x + (size_t)(r0 + r) * 32);
            float a0 = 0, a1 = 0, a2 = 0, a3 = 0;
            #pragma unroll
            for (int q = 0; q < 8; ++q){
                float4 v = xr4[q];
                a0 = fmaf(v.x, wr[q].x, a0);
                a1 = fmaf(v.y, wr[q].y, a1);
                a2 = fmaf(v.z, wr[q].z, a2);
                a3 = fmaf(v.w, wr[q].w, a3);
            }
            float h = lrelu((a0 + a1) + (a2 + a3) + bc);
            sum += h; sq = fmaf(h, h, sq);
        }
        int buf = (rb & 3) * 1024 + c;
        atomicAdd(&ws[P1S_OFF + buf], sum);
        atomicAdd(&ws[P1Q_OFF + buf], sq);
        return;
    }
    // ---- QP build path (single block) ----
    for (int idx = t; idx < 1024; idx += 256){
        int i = idx >> 5, j = idx & 31;
        sL[idx]  = (j <= i) ? L[idx]  : 0.0f;
        sLP[idx] = (j <= i) ? LP[idx] : 0.0f;
        sA[idx]  = A[idx];
    }
    if (t < 64) sPow[0][t] = Bm[t];
    if (t == 0){
        float a = LR[0], b = LR[2], c = LR[3];   // tril: [[a,0],[b,c]]
        sR[0] = a*a + EPSQ; sR[1] = a*b; sR[2] = b*b + c*c + EPSQ;
    }
    __syncthreads();
    for (int idx = t; idx < 1024; idx += 256){
        int i = idx >> 5, j = idx & 31;
        float q = 0.0f, p = 0.0f;
        for (int k = 0; k < 32; ++k){
            q = fmaf(sL[i*32+k],  sL[j*32+k],  q);
            p = fmaf(sLP[i*32+k], sLP[j*32+k], p);
        }
        if (i == j){ q += EPSQ; p += EPSQ; }
        sQ[idx] = q; sP[idx] = p;
    }
    for (int kp = 1; kp < 4; ++kp){
        __syncthreads();
        if (t < 64){
            int i = t >> 1, c = t & 1;
            float a = 0.0f;
            for (int j = 0; j < 32; ++j) a = fmaf(sA[i*32+j], sPow[kp-1][j*2+c], a);
            sPow[kp][t] = a;
        }
    }
    __syncthreads();
    for (int idx = t; idx < 1280; idx += 256){
        int r = idx / 10, c = idx % 10;
        int bi = r >> 5, ri = r & 31, bj = c >> 1, cj = c & 1;
        sBh[idx] = (bj <= bi) ? sPow[bi-bj][ri*2+cj] : 0.0f;
    }
    __syncthreads();
    for (int idx = t; idx < 1280; idx += 256){
        int r = idx / 10, c = idx % 10;
        int bi = r >> 5, ri = r & 31;
        const float* Qd = (bi < 3) ? sQ : sP;
        float a = 0.0f;
        for (int k = 0; k < 32; ++k) a = fmaf(Qd[ri*32+k], sBh[(bi*32+k)*10+c], a);
        sQB[idx] = a;
    }
    __syncthreads();
    if (t < 120){
        int i = t / 12, j = t % 12;
        float a = 0.0f;
        if (j < 10){
            for (int r = 0; r < 128; ++r) a = fmaf(sBh[r*10+i], sQB[r*10+j], a);
            if ((i >> 1) == (j >> 1)) a += sR[(i&1)+(j&1)];
        }
        ws[QM_OFF + t] = a;
    }
    for (int idx = t; idx < 144*12; idx += 256){
        int m = idx / 12, i = idx % 12;
        float v = 0.0f;
        if (i < 10 && m < MIx) v = (m < 10) ? ((i == m) ? 1.0f : 0.0f) : sBh[(m-10)*10 + i];
        ws[G_OFF + idx] = v;
    }
    for (int m = t; m < 144; m += 256){
        float hv = 0.0f;
        if (m < MIx){
            hv = s0[m];
            if (m < 10) hv += u0[m];
            else { for (int i = 0; i < 10; ++i) hv = fmaf(sBh[(m-10)*10+i], u0[i], hv); }
        }
        ws[H_OFF + m] = hv;
    }
}

// ---------- fc2 with BN1-finalize folded in-block ----------
// Phase 1: a1/c1 from P1 partials into LDS (redundant per block — cheap).
// Main: h1n = lrelu(fc1)*a1 + c1 folded via one fma (no b2p needed; epilogue adds b2).
__global__ __launch_bounds__(512) void k_fc2(const float* x, const float* w1, const float* w2,
                                             const float* b1v, const float* b2v,
                                             const float* g1, const float* bb1, float* ws){
    __shared__ float sA1[1024], sC1[1024];
    __shared__ float pacc[512*10];   // 20 KB
    int t = threadIdx.x;
    #pragma unroll
    for (int k = t; k < 1024; k += 512){
        float ssum = 0.0f, qsum = 0.0f;
        #pragma unroll
        for (int b = 0; b < 4; ++b){
            ssum += ws[P1S_OFF + b*1024 + k];
            qsum += ws[P1Q_OFF + b*1024 + k];
        }
        float mu  = ssum * (1.0f/16384.0f);
        float var = qsum * (1.0f/16384.0f) - mu*mu;
        float a1 = g1[k] / sqrtf(var + BNEPS);
        sA1[k] = a1;
        sC1[k] = bb1[k] - mu * a1;
    }
    int r = t & 63;
    int q = t >> 6;                  // 0..7: wave owns k-eighth
    int row = blockIdx.x * 64 + r;
    const float4* xg4 = (const float4*)(x + (size_t)row * 32);
    float4 xr[8];
    #pragma unroll
    for (int i = 0; i < 8; ++i) xr[i] = xg4[i];
    float acc[10];
    #pragma unroll
    for (int j = 0; j < 10; ++j) acc[j] = 0.0f;
    const float4* w1g = (const float4*)w1;
    __syncthreads();
    #pragma unroll 2
    for (int kk = 0; kk < 128; ++kk){
        int kl = q*128 + kk;         // wave-uniform
        float a0 = 0, a1 = 0, a2 = 0, a3 = 0;
        #pragma unroll
        for (int i = 0; i < 8; ++i){
            float4 wv = w1g[kl*8 + i];
            float4 xv = xr[i];
            a0 = fmaf(xv.x, wv.x, a0);
            a1 = fmaf(xv.y, wv.y, a1);
            a2 = fmaf(xv.z, wv.z, a2);
            a3 = fmaf(xv.w, wv.w, a3);
        }
        float h = fmaf(lrelu((a0 + a1) + (a2 + a3) + b1v[kl]), sA1[kl], sC1[kl]);
        #pragma unroll
        for (int j = 0; j < 10; ++j) acc[j] = fmaf(h, w2[j*1024 + kl], acc[j]);
    }
    #pragma unroll
    for (int j = 0; j < 10; ++j) pacc[t*10 + j] = acc[j];
    __syncthreads();
    if (t < 64){
        float pv[10];
        #pragma unroll
        for (int j = 0; j < 10; ++j){
            float a = b2v[j];
            #pragma unroll
            for (int w = 0; w < 8; ++w) a += pacc[(w*64 + t)*10 + j];
            pv[j] = lrelu(a);
        }
        #pragma unroll
        for (int j = 0; j < 10; ++j) ws[PRAW_OFF + (size_t)(blockIdx.x*64 + t)*10 + j] = pv[j];
        float sv[10], qv[10];
        #pragma unroll
        for (int j = 0; j < 10; ++j){ sv[j] = pv[j]; qv[j] = pv[j]*pv[j]; }
        #pragma unroll
        for (int m = 1; m < 64; m <<= 1){
            #pragma unroll
            for (int j = 0; j < 10; ++j){
                sv[j] += __shfl_xor(sv[j], m);
                qv[j] += __shfl_xor(qv[j], m);
            }
        }
        if (t == 0){
            int base = P2_OFF + (blockIdx.x & 15) * 20;
            #pragma unroll
            for (int j = 0; j < 10; ++j){
                atomicAdd(&ws[base + j], sv[j]);
                atomicAdd(&ws[base + 10 + j], qv[j]);
            }
        }
    }
}

// ---------- batched IPM (BN2-finalize folded in-block) ----------
// 16 lanes/element, 4 elements/block. g6/g7 in LDS indexed by lg (16 rows, stride 20
// floats = conflict-free b128 phases + 4-way same-address broadcast; round-7's t*16
// layout caused 5.5e7 bank-conflict cycles). isk recomputed (trans pipe idle).
#define TIX(i,j) ((i)*((i)+1)/2 + (j))

#define STEPA(K, B, g) { \
    float sk = s[K], lk = lam[K]; \
    float isk = frcp(sk); \
    float r = sk - hhp[(K)*16]; \
    float w = lk * isk; \
    sl = fmaf(sk, lk, sl); \
    _Pragma("unroll") \
    for (int i = 0; i < B; ++i){ \
        lamG[i] = fmaf(lk, g[i], lamG[i]); \
        r = fmaf(z[i], g[i], r); \
    } \
    sRPp[K] = r; \
    _Pragma("unroll") \
    for (int i = 0; i < B; ++i){ \
        float wgi = w * g[i]; \
        _Pragma("unroll") \
        for (int j = 0; j <= i; ++j) Hm[TIX(i,j)] = fmaf(wgi, g[j], Hm[TIX(i,j)]); \
    } }

#define STEPB(K, B, g) { \
    float rpk = sRPp[K]; \
    float sk = s[K], lk = lam[K]; \
    float isk = frcp(sk); \
    float rc = fmaf(sk, lk, -smu); \
    float coef = isk * fmaf(lk, rpk, -rc); \
    _Pragma("unroll") \
    for (int i = 0; i < B; ++i) racc[i] = fmaf(coef, g[i], racc[i]); }

#define STEPC(K, B, g) { \
    float rpk = sRPp[K]; \
    float dot = 0.0f; \
    _Pragma("unroll") \
    for (int i = 0; i < B; ++i) dot = fmaf(dz[i], g[i], dot); \
    float dsk = -rpk - dot; \
    float sk = s[K], lk = lam[K]; \
    float isk = frcp(sk); \
    float rc = fmaf(sk, lk, -smu); \
    float dlk = -(rc + lk * dsk) * isk; \
    ds_[K] = dsk; dl_[K] = dlk; \
    float ilk = frcp(lk); \
    ainv = fmaxf(ainv, fmaxf(-dsk * isk, -dlk * ilk)); }

#define LDG(g, c, B) { _Pragma("unroll") for (int i = 0; i < B; ++i) g[i] = GB[(c)*12 + i]; }

#define LOAD_G6(arr) float arr[8]; { const float4* _gq = (const float4*)(sG67 + lg*20); \
    float4 _a = _gq[0], _b = _gq[1]; \
    arr[0]=_a.x; arr[1]=_a.y; arr[2]=_a.z; arr[3]=_a.w; arr[4]=_b.x; arr[5]=_b.y; arr[6]=_b.z; arr[7]=_b.w; }
#define LOAD_G7(arr) float arr[8]; { const float4* _gq = (const float4*)(sG67 + lg*20); \
    float4 _a = _gq[2], _b = _gq[3]; \
    arr[0]=_a.x; arr[1]=_a.y; arr[2]=_a.z; arr[3]=_a.w; arr[4]=_b.x; arr[5]=_b.y; arr[6]=_b.z; arr[7]=_b.w; }

__global__ __launch_bounds__(64) void k_ipm(const float* ws, const float* g2v, const float* bb2, float* out){
    __shared__ __align__(16) float sQm[120];
    __shared__ __align__(16) float sPV[4*12];
    __shared__ float sHH[128];
    __shared__ float sRP[64*9];
    __shared__ __align__(16) float sG67[16*20];
    __shared__ float sA2[10], sC2[10];
    int t = threadIdx.x;
    for (int i = t; i < 120; i += 64) sQm[i] = ws[QM_OFF + i];
    for (int i = t; i < 128; i += 64) sHH[i] = ws[H_OFF + 10 + i];
    if (t < 10){   // BN2 finalize (redundant per block — 320 loads, trivial)
        float ssum = 0.0f, qsum = 0.0f;
        #pragma unroll
        for (int b = 0; b < 16; ++b){
            ssum += ws[P2_OFF + b*20 + t];
            qsum += ws[P2_OFF + b*20 + 10 + t];
        }
        float mu  = ssum * (1.0f/16384.0f);
        float var = qsum * (1.0f/16384.0f) - mu*mu;
        float a2 = g2v[t] / sqrtf(var + BNEPS);
        sA2[t] = a2;
        sC2[t] = bb2[t] - mu * a2;
    }
    __syncthreads();

    int lg = t & 15;
    int eidx = t >> 4;
    int elem = blockIdx.x * 4 + eidx;
    const float* GB = ws + G_OFF;
    const float* hhp = sHH + lg;
    float* sRPp = sRP + t * 9;
    const float4* sQm4 = (const float4*)sQm;

    if (t < 40){
        int e = t / 10, i = t - e*10;
        int el = blockIdx.x * 4 + e;
        sPV[e*12 + i] = fmaf(ws[PRAW_OFF + (size_t)el*10 + i], sA2[i], sC2[i]);
    }
    if (t < 16){
        #pragma unroll
        for (int i = 0; i < 8; ++i) sG67[t*20 + i]     = GB[(10 + 96 + t)*12 + i];
        #pragma unroll
        for (int i = 0; i < 8; ++i) sG67[t*20 + 8 + i] = GB[(10 + 112 + t)*12 + i];
    }
    float g0[2], g1[2], g2r[4], g3[4], g4[6], g5[6];
    {
        int c = 10 + lg;   LDG(g0, c, 2);
        c = 10 + 16 + lg;  LDG(g1, c, 2);
        c = 10 + 32 + lg;  LDG(g2r, c, 4);
        c = 10 + 48 + lg;  LDG(g3, c, 4);
        c = 10 + 64 + lg;  LDG(g4, c, 6);
        c = 10 + 80 + lg;  LDG(g5, c, 6);
    }
    float h8 = (lg < 10) ? ws[H_OFF + lg] : 1.0f;
    __syncthreads();

    float z[10];
    #pragma unroll
    for (int i = 0; i < 10; ++i) z[i] = 0.0f;
    float s[9], lam[9];
    #pragma unroll
    for (int k = 0; k < 9; ++k){ s[k] = 1.0f; lam[k] = 1.0f; }
    lam[8] = (lg < 10) ? 1.0f : 0.0f;

    #pragma unroll 1
    for (int it = 0; it < ITERS; ++it){
        float lamG[8], Hm[55], sl = 0.0f, rp8;
        #pragma unroll
        for (int i = 0; i < 8; ++i) lamG[i] = 0.0f;
        #pragma unroll
        for (int i = 0; i < 36; ++i) Hm[i] = 0.0f;
        // ---- loop A (B_hat rows, compile-time col bounds)
        STEPA(0, 2, g0)  STEPA(1, 2, g1)
        STEPA(2, 4, g2r) STEPA(3, 4, g3)
        STEPA(4, 6, g4)  STEPA(5, 6, g5)
        { LOAD_G6(g6v) STEPA(6, 8, g6v) }
        { LOAD_G7(g7v) STEPA(7, 8, g7v) }
        // ---- identity row (slot 8)
        float zs = z[0];
        #pragma unroll
        for (int i = 1; i < 10; ++i) zs = (lg == i) ? z[i] : zs;
        float w8;
        {
            float sk = s[8], lk = lam[8];
            rp8 = zs + sk - h8;
            sl = fmaf(sk, lk, sl);
            w8 = lk * frcp(sk);
        }
        // ---- fold identity contributions pre-reduce
        float lamG8 = (lg == 8) ? lam[8] : 0.0f;
        float lamG9 = (lg == 9) ? lam[8] : 0.0f;
        #pragma unroll
        for (int i = 0; i < 8; ++i) lamG[i] += (lg == i) ? lam[8] : 0.0f;
        #pragma unroll
        for (int i = 0; i < 8; ++i) Hm[TIX(i,i)] += (lg == i) ? w8 : 0.0f;
        float d88 = (lg == 8) ? w8 : 0.0f;
        float d99 = (lg == 9) ? w8 : 0.0f;
        // ---- DPP all-reduce
        #pragma unroll
        for (int i = 0; i < 36; ++i) Hm[i] = red16_add(Hm[i]);
        #pragma unroll
        for (int i = 0; i < 8; ++i) lamG[i] = red16_add(lamG[i]);
        lamG8 = red16_add(lamG8); lamG9 = red16_add(lamG9);
        d88 = red16_add(d88);     d99 = red16_add(d99);
        sl = red16_add(sl);
        float smu = SIGMA_C * sl * (1.0f/138.0f);
        __asm__ __volatile__("" ::: "memory");   // keep g6/g7 transient (VGPR 88, round 7)
        // ---- loop B: racc
        float racc[8];
        #pragma unroll
        for (int i = 0; i < 8; ++i) racc[i] = 0.0f;
        STEPB(0, 2, g0)  STEPB(1, 2, g1)
        STEPB(2, 4, g2r) STEPB(3, 4, g3)
        STEPB(4, 6, g4)  STEPB(5, 6, g5)
        { LOAD_G6(g6v) STEPB(6, 8, g6v) }
        { LOAD_G7(g7v) STEPB(7, 8, g7v) }
        float coef8;
        {
            float sk = s[8], lk = lam[8];
            float isk = frcp(sk);
            float rc = fmaf(sk, lk, -smu);
            coef8 = isk * fmaf(lk, rp8, -rc);
            coef8 = (lg < 10) ? coef8 : 0.0f;
        }
        #pragma unroll
        for (int i = 0; i < 8; ++i) racc[i] += (lg == i) ? coef8 : 0.0f;
        float racc8 = (lg == 8) ? coef8 : 0.0f;
        float racc9 = (lg == 9) ? coef8 : 0.0f;
        #pragma unroll
        for (int i = 0; i < 8; ++i) racc[i] = red16_add(racc[i]);
        racc8 = red16_add(racc8); racc9 = red16_add(racc9);
        // ---- rhs base = -(p + lamG + racc); Q-pass subtracts Qz, H += Q
        float rhs[10];
        {
            const float4* pv4 = (const float4*)(sPV + eidx*12);
            float4 pa = pv4[0], pb = pv4[1];
            const float2* pv2 = (const float2*)(sPV + eidx*12 + 8);
            float2 pc = pv2[0];
            rhs[0] = -(pa.x + lamG[0] + racc[0]); rhs[1] = -(pa.y + lamG[1] + racc[1]);
            rhs[2] = -(pa.z + lamG[2] + racc[2]); rhs[3] = -(pa.w + lamG[3] + racc[3]);
            rhs[4] = -(pb.x + lamG[4] + racc[4]); rhs[5] = -(pb.y + lamG[5] + racc[5]);
            rhs[6] = -(pb.z + lamG[6] + racc[6]); rhs[7] = -(pb.w + lamG[7] + racc[7]);
            rhs[8] = -(pc.x + lamG8 + racc8);     rhs[9] = -(pc.y + lamG9 + racc9);
        }
        #pragma unroll
        for (int j = 0; j < 10; ++j){
            float4 qa = sQm4[j*3+0], qb = sQm4[j*3+1], qc = sQm4[j*3+2];
            float q[10] = {qa.x,qa.y,qa.z,qa.w, qb.x,qb.y,qb.z,qb.w, qc.x,qc.y};
            float zj = z[j];
            #pragma unroll
            for (int i = 0; i < 10; ++i) rhs[i] = fmaf(-zj, q[i], rhs[i]);
            if (j < 8){
                #pragma unroll
                for (int i = 0; i <= j; ++i) Hm[TIX(j,i)] += q[i];
            } else {
                #pragma unroll
                for (int i = 0; i <= j; ++i) Hm[TIX(j,i)] = q[i];
            }
        }
        Hm[TIX(8,8)] += d88;
        Hm[TIX(9,9)] += d99;
        // ---- Cholesky (reciprocal diag in place)
        #pragma unroll
        for (int j = 0; j < 10; ++j){
            float d = Hm[TIX(j,j)];
            #pragma unroll
            for (int k2 = 0; k2 < j; ++k2){ float v = Hm[TIX(j,k2)]; d = fmaf(-v, v, d); }
            d = fmaxf(d, 1e-30f);
            float rinv = frsq(d);
            Hm[TIX(j,j)] = rinv;
            #pragma unroll
            for (int i = j+1; i < 10; ++i){
                float v2 = Hm[TIX(i,j)];
                #pragma unroll
                for (int k2 = 0; k2 < j; ++k2) v2 = fmaf(-Hm[TIX(i,k2)], Hm[TIX(j,k2)], v2);
                Hm[TIX(i,j)] = v2 * rinv;
            }
        }
        #pragma unroll
        for (int i = 0; i < 10; ++i){
            float v2 = rhs[i];
            #pragma unroll
            for (int k2 = 0; k2 < i; ++k2) v2 = fmaf(-Hm[TIX(i,k2)], rhs[k2], v2);
            rhs[i] = v2 * Hm[TIX(i,i)];
        }
        float dz[10];
        #pragma unroll
        for (int i = 9; i >= 0; --i){
            float v2 = rhs[i];
            #pragma unroll
            for (int k2 = i+1; k2 < 10; ++k2) v2 = fmaf(-Hm[TIX(k2,i)], dz[k2], v2);
            dz[i] = v2 * Hm[TIX(i,i)];
        }
        __asm__ __volatile__("" ::: "memory");
        // ---- loop C: steps + alpha (max-of-inverse-ratios)
        float ds_[9], dl_[9];
        float ainv = 0.0f;
        STEPC(0, 2, g0)  STEPC(1, 2, g1)
        STEPC(2, 4, g2r) STEPC(3, 4, g3)
        STEPC(4, 6, g4)  STEPC(5, 6, g5)
        { LOAD_G6(g6v) STEPC(6, 8, g6v) }
        { LOAD_G7(g7v) STEPC(7, 8, g7v) }
        {
            float dzs = dz[0];
            #pragma unroll
            for (int i = 1; i < 10; ++i) dzs = (lg == i) ? dz[i] : dzs;
            bool val = lg < 10;
            float dsk = val ? (-rp8 - dzs) : 0.0f;
            float sk = s[8], lk = lam[8];
            float isk = frcp(sk);
            float rc = fmaf(sk, lk, -smu);
            float dlk = -(rc + lk * dsk) * isk;
            dlk = val ? dlk : 0.0f;
            ds_[8] = dsk; dl_[8] = dlk;
            float cand = fmaxf(-dsk * isk, -dlk * frcp(lk));
            ainv = fmaxf(ainv, val ? cand : 0.0f);
        }
        ainv = red16_max(ainv);
        float alpha = fminf(1.0f, 0.99f * frcp(fmaxf(ainv, 1e-30f)));
        // ---- updates
        #pragma unroll
        for (int i = 0; i < 10; ++i) z[i] = fmaf(alpha, dz[i], z[i]);
        #pragma unroll
        for (int k = 0; k < 9; ++k){
            s[k]   = fmaf(alpha, ds_[k], s[k]);
            lam[k] = fmaf(alpha, dl_[k], lam[k]);
        }
    }
    if (lg == 0) out[elem] = z[0];
}

extern "C" void kernel_launch(void* const* d_in, const int* in_sizes, int n_in,
                              void* d_out, int out_size, void* d_ws, size_t ws_size,
                              hipStream_t stream){
    const float* x   = (const float*)d_in[0];
    const float* w1  = (const float*)d_in[1];
    const float* b1  = (const float*)d_in[2];
    const float* w2  = (const float*)d_in[3];
    const float* b2  = (const float*)d_in[4];
    const float* g1  = (const float*)d_in[5];
    const float* bb1 = (const float*)d_in[6];
    const float* g2  = (const float*)d_in[7];
    const float* bb2 = (const float*)d_in[8];
    const float* L   = (const float*)d_in[9];
    const float* LP  = (const float*)d_in[10];
    const float* LR  = (const float*)d_in[11];
    const float* A   = (const float*)d_in[12];
    const float* Bm  = (const float*)d_in[13];
    const float* u0  = (const float*)d_in[14];
    const float* s0  = (const float*)d_in[15];
    float* ws  = (float*)d_ws;
    float* out = (float*)d_out;

    // zero P2 + P1 partial accumulators (floats 2048..10560)
    hipMemsetAsync(ws + P2_OFF, 0, (P1Q_OFF + 4096 - P2_OFF) * sizeof(float), stream);
    hipLaunchKernelGGL(k_buildstats, dim3(513), dim3(256), 0, stream,
                       L, LP, LR, A, Bm, u0, s0, x, w1, b1, ws);
    hipLaunchKernelGGL(k_fc2, dim3(256), dim3(512), 0, stream, x, w1, w2, b1, b2, g1, bb1, ws);
    hipLaunchKernelGGL(k_ipm, dim3(4096), dim3(64), 0, stream, ws, g2, bb2, out);
}

// Round 9
// 512.606 us; speedup vs baseline: 3.9626x; 1.0703x over previous
//
#include <hip/hip_runtime.h>
#include <math.h>

#define NIx 32
#define NOx 2
#define NUx 10
#define NHx 1024
#define NBx 16384
#define MIx 138
#define EPSQ 1e-4f
#define BNEPS 1e-5f
#define ITERS 30
#define SLOPE 0.2f
#define SIGMA_C 0.1f

// workspace layout (float offsets). Max = 174400 floats = 697.6 KB (< proven 723 KB).
#define QM_OFF 0        // 120 (pad 128)
#define G_OFF 128       // 144 x 12 -> 1856
#define H_OFF 1856      // 144 (pad 2048)
#define P2_OFF 2048     // 16 bufs x 20 (sum[10],sq[10]) = 320 (pad 2368)
#define P1S_OFF 2368    // 4 bufs x 1024 col-sums
#define P1Q_OFF 6464    // 4 bufs x 1024 col-sumsq -> 10560
#define PRAW_OFF 10560  // 16384 x 10 -> 174400
// memset zeroes [P2_OFF, P1Q_OFF+4096) = floats 2048..10560

__device__ __forceinline__ float frcp(float x){ return __builtin_amdgcn_rcpf(x); }
__device__ __forceinline__ float frsq(float x){ return __builtin_amdgcn_rsqf(x); }
__device__ __forceinline__ float lrelu(float x){ return x > 0.0f ? x : SLOPE * x; }

// ---- DPP 16-lane reductions (VALU, no LDS pipe) ----
template<int CTRL>
__device__ __forceinline__ float dpp_mov(float x){
    int y = __builtin_amdgcn_update_dpp(0, __float_as_int(x), CTRL, 0xF, 0xF, true);
    return __int_as_float(y);
}
__device__ __forceinline__ float red16_add(float x){
    x += dpp_mov<0xB1>(x);
    x += dpp_mov<0x4E>(x);
    x += dpp_mov<0x124>(x);
    x += dpp_mov<0x128>(x);
    return x;
}
__device__ __forceinline__ float red16_max(float x){
    x = fmaxf(x, dpp_mov<0xB1>(x));
    x = fmaxf(x, dpp_mov<0x4E>(x));
    x = fmaxf(x, dpp_mov<0x124>(x));
    x = fmaxf(x, dpp_mov<0x128>(x));
    return x;
}

// ---------- merged: blocks 0..511 BN1-stats, block 512 QP-build (independent work) ----------
__global__ __launch_bounds__(256) void k_buildstats(const float* L, const float* LP, const float* LR,
                                                    const float* A, const float* Bm,
                                                    const float* u0, const float* s0,
                                                    const float* x, const float* w1, const float* b1,
                                                    float* ws){
    __shared__ float sL[1024], sLP[1024], sA[1024], sQ[1024], sP[1024];
    __shared__ float sPow[4][64];
    __shared__ float sBh[128*10];
    __shared__ float sQB[128*10];
    __shared__ float sR[3];
    int t = threadIdx.x;
    if (blockIdx.x < 512){
        // ---- BN1 stats path: partial col sum/sumsq into 4 spread buffers ----
        int rb = blockIdx.x >> 2;        // 128 row-groups of 128 rows
        int cb = blockIdx.x & 3;         // 4 col-groups of 256 cols
        int c = cb * 256 + t;
        const float4* wg4 = (const float4*)(w1 + (size_t)c * 32);
        float4 wr[8];
        #pragma unroll
        for (int q = 0; q < 8; ++q) wr[q] = wg4[q];
        float bc = b1[c];
        int r0 = rb * 128;
        float sum = 0.0f, sq = 0.0f;
        #pragma unroll 2
        for (int r = 0; r < 128; ++r){
            const float4* xr4 = (const float4*)(x + (size_t)(r0 + r) * 32);
            float a0 = 0, a1 = 0, a2 = 0, a3 = 0;
            #pragma unroll
            for (int q = 0; q < 8; ++q){
                float4 v = xr4[q];
                a0 = fmaf(v.x, wr[q].x, a0);
                a1 = fmaf(v.y, wr[q].y, a1);
                a2 = fmaf(v.z, wr[q].z, a2);
                a3 = fmaf(v.w, wr[q].w, a3);
            }
            float h = lrelu((a0 + a1) + (a2 + a3) + bc);
            sum += h; sq = fmaf(h, h, sq);
        }
        int buf = (rb & 3) * 1024 + c;
        atomicAdd(&ws[P1S_OFF + buf], sum);
        atomicAdd(&ws[P1Q_OFF + buf], sq);
        return;
    }
    // ---- QP build path (single block) ----
    for (int idx = t; idx < 1024; idx += 256){
        int i = idx >> 5, j = idx & 31;
        sL[idx]  = (j <= i) ? L[idx]  : 0.0f;
        sLP[idx] = (j <= i) ? LP[idx] : 0.0f;
        sA[idx]  = A[idx];
    }
    if (t < 64) sPow[0][t] = Bm[t];
    if (t == 0){
        float a = LR[0], b = LR[2], c = LR[3];   // tril: [[a,0],[b,c]]
        sR[0] = a*a + EPSQ; sR[1] = a*b; sR[2] = b*b + c*c + EPSQ;
    }
    __syncthreads();
    for (int idx = t; idx < 1024; idx += 256){
        int i = idx >> 5, j = idx & 31;
        float q = 0.0f, p = 0.0f;
        for (int k = 0; k < 32; ++k){
            q = fmaf(sL[i*32+k],  sL[j*32+k],  q);
            p = fmaf(sLP[i*32+k], sLP[j*32+k], p);
        }
        if (i == j){ q += EPSQ; p += EPSQ; }
        sQ[idx] = q; sP[idx] = p;
    }
    for (int kp = 1; kp < 4; ++kp){
        __syncthreads();
        if (t < 64){
            int i = t >> 1, c = t & 1;
            float a = 0.0f;
            for (int j = 0; j < 32; ++j) a = fmaf(sA[i*32+j], sPow[kp-1][j*2+c], a);
            sPow[kp][t] = a;
        }
    }
    __syncthreads();
    for (int idx = t; idx < 1280; idx += 256){
        int r = idx / 10, c = idx % 10;
        int bi = r >> 5, ri = r & 31, bj = c >> 1, cj = c & 1;
        sBh[idx] = (bj <= bi) ? sPow[bi-bj][ri*2+cj] : 0.0f;
    }
    __syncthreads();
    for (int idx = t; idx < 1280; idx += 256){
        int r = idx / 10, c = idx % 10;
        int bi = r >> 5, ri = r & 31;
        const float* Qd = (bi < 3) ? sQ : sP;
        float a = 0.0f;
        for (int k = 0; k < 32; ++k) a = fmaf(Qd[ri*32+k], sBh[(bi*32+k)*10+c], a);
        sQB[idx] = a;
    }
    __syncthreads();
    if (t < 120){
        int i = t / 12, j = t % 12;
        float a = 0.0f;
        if (j < 10){
            for (int r = 0; r < 128; ++r) a = fmaf(sBh[r*10+i], sQB[r*10+j], a);
            if ((i >> 1) == (j >> 1)) a += sR[(i&1)+(j&1)];
        }
        ws[QM_OFF + t] = a;
    }
    for (int idx = t; idx < 144*12; idx += 256){
        int m = idx / 12, i = idx % 12;
        float v = 0.0f;
        if (i < 10 && m < MIx) v = (m < 10) ? ((i == m) ? 1.0f : 0.0f) : sBh[(m-10)*10 + i];
        ws[G_OFF + idx] = v;
    }
    for (int m = t; m < 144; m += 256){
        float hv = 0.0f;
        if (m < MIx){
            hv = s0[m];
            if (m < 10) hv += u0[m];
            else { for (int i = 0; i < 10; ++i) hv = fmaf(sBh[(m-10)*10+i], u0[i], hv); }
        }
        ws[H_OFF + m] = hv;
    }
}

// ---------- fc2 with BN1-finalize folded in-block ----------
__global__ __launch_bounds__(512) void k_fc2(const float* x, const float* w1, const float* w2,
                                             const float* b1v, const float* b2v,
                                             const float* g1, const float* bb1, float* ws){
    __shared__ float sA1[1024], sC1[1024];
    __shared__ float pacc[512*10];   // 20 KB
    int t = threadIdx.x;
    #pragma unroll
    for (int k = t; k < 1024; k += 512){
        float ssum = 0.0f, qsum = 0.0f;
        #pragma unroll
        for (int b = 0; b < 4; ++b){
            ssum += ws[P1S_OFF + b*1024 + k];
            qsum += ws[P1Q_OFF + b*1024 + k];
        }
        float mu  = ssum * (1.0f/16384.0f);
        float var = qsum * (1.0f/16384.0f) - mu*mu;
        float a1 = g1[k] / sqrtf(var + BNEPS);
        sA1[k] = a1;
        sC1[k] = bb1[k] - mu * a1;
    }
    int r = t & 63;
    int q = t >> 6;                  // 0..7: wave owns k-eighth
    int row = blockIdx.x * 64 + r;
    const float4* xg4 = (const float4*)(x + (size_t)row * 32);
    float4 xr[8];
    #pragma unroll
    for (int i = 0; i < 8; ++i) xr[i] = xg4[i];
    float acc[10];
    #pragma unroll
    for (int j = 0; j < 10; ++j) acc[j] = 0.0f;
    const float4* w1g = (const float4*)w1;
    __syncthreads();
    #pragma unroll 2
    for (int kk = 0; kk < 128; ++kk){
        int kl = q*128 + kk;         // wave-uniform
        float a0 = 0, a1 = 0, a2 = 0, a3 = 0;
        #pragma unroll
        for (int i = 0; i < 8; ++i){
            float4 wv = w1g[kl*8 + i];
            float4 xv = xr[i];
            a0 = fmaf(xv.x, wv.x, a0);
            a1 = fmaf(xv.y, wv.y, a1);
            a2 = fmaf(xv.z, wv.z, a2);
            a3 = fmaf(xv.w, wv.w, a3);
        }
        float h = fmaf(lrelu((a0 + a1) + (a2 + a3) + b1v[kl]), sA1[kl], sC1[kl]);
        #pragma unroll
        for (int j = 0; j < 10; ++j) acc[j] = fmaf(h, w2[j*1024 + kl], acc[j]);
    }
    #pragma unroll
    for (int j = 0; j < 10; ++j) pacc[t*10 + j] = acc[j];
    __syncthreads();
    if (t < 64){
        float pv[10];
        #pragma unroll
        for (int j = 0; j < 10; ++j){
            float a = b2v[j];
            #pragma unroll
            for (int w = 0; w < 8; ++w) a += pacc[(w*64 + t)*10 + j];
            pv[j] = lrelu(a);
        }
        #pragma unroll
        for (int j = 0; j < 10; ++j) ws[PRAW_OFF + (size_t)(blockIdx.x*64 + t)*10 + j] = pv[j];
        float sv[10], qv[10];
        #pragma unroll
        for (int j = 0; j < 10; ++j){ sv[j] = pv[j]; qv[j] = pv[j]*pv[j]; }
        #pragma unroll
        for (int m = 1; m < 64; m <<= 1){
            #pragma unroll
            for (int j = 0; j < 10; ++j){
                sv[j] += __shfl_xor(sv[j], m);
                qv[j] += __shfl_xor(qv[j], m);
            }
        }
        if (t == 0){
            int base = P2_OFF + (blockIdx.x & 15) * 20;
            #pragma unroll
            for (int j = 0; j < 10; ++j){
                atomicAdd(&ws[base + j], sv[j]);
                atomicAdd(&ws[base + 10 + j], qv[j]);
            }
        }
    }
}

// ---------- batched IPM (BN2-finalize folded in-block) ----------
// Round-9 algebra: lamG eliminated (lamG+racc == sum_k g_k*(lam_k*rp_k+smu)/s_k);
// Hm rows 0..7 pre-initialized with Q/16 (16-lane butterfly sums to Q exactly),
// removing the H+=Q pass for those rows; h rows in registers (VGPR headroom to 128).
#define TIX(i,j) ((i)*((i)+1)/2 + (j))

#define STEPA(K, B, g) { \
    float sk = s[K], lk = lam[K]; \
    float isk = frcp(sk); \
    float r = sk - hh[K]; \
    float w = lk * isk; \
    sl = fmaf(sk, lk, sl); \
    _Pragma("unroll") \
    for (int i = 0; i < B; ++i) r = fmaf(z[i], g[i], r); \
    sRPp[K] = r; \
    _Pragma("unroll") \
    for (int i = 0; i < B; ++i){ \
        float wgi = w * g[i]; \
        _Pragma("unroll") \
        for (int j = 0; j <= i; ++j) Hm[TIX(i,j)] = fmaf(wgi, g[j], Hm[TIX(i,j)]); \
    } }

#define STEPB(K, B, g) { \
    float rpk = sRPp[K]; \
    float sk = s[K], lk = lam[K]; \
    float isk = frcp(sk); \
    float coef = isk * fmaf(lk, rpk, smu); \
    _Pragma("unroll") \
    for (int i = 0; i < B; ++i) racc[i] = fmaf(coef, g[i], racc[i]); }

#define STEPC(K, B, g) { \
    float rpk = sRPp[K]; \
    float dot = 0.0f; \
    _Pragma("unroll") \
    for (int i = 0; i < B; ++i) dot = fmaf(dz[i], g[i], dot); \
    float dsk = -rpk - dot; \
    float sk = s[K], lk = lam[K]; \
    float isk = frcp(sk); \
    float rc = fmaf(sk, lk, -smu); \
    float dlk = -(rc + lk * dsk) * isk; \
    ds_[K] = dsk; dl_[K] = dlk; \
    float ilk = frcp(lk); \
    ainv = fmaxf(ainv, fmaxf(-dsk * isk, -dlk * ilk)); }

#define LDG(g, c, B) { _Pragma("unroll") for (int i = 0; i < B; ++i) g[i] = GB[(c)*12 + i]; }

#define LOAD_G6(arr) float arr[8]; { const float4* _gq = (const float4*)(sG67 + lg*20); \
    float4 _a = _gq[0], _b = _gq[1]; \
    arr[0]=_a.x; arr[1]=_a.y; arr[2]=_a.z; arr[3]=_a.w; arr[4]=_b.x; arr[5]=_b.y; arr[6]=_b.z; arr[7]=_b.w; }
#define LOAD_G7(arr) float arr[8]; { const float4* _gq = (const float4*)(sG67 + lg*20); \
    float4 _a = _gq[2], _b = _gq[3]; \
    arr[0]=_a.x; arr[1]=_a.y; arr[2]=_a.z; arr[3]=_a.w; arr[4]=_b.x; arr[5]=_b.y; arr[6]=_b.z; arr[7]=_b.w; }

__global__ __launch_bounds__(64) void k_ipm(const float* ws, const float* g2v, const float* bb2, float* out){
    __shared__ __align__(16) float sQm[120];
    __shared__ __align__(16) float sQt[36];     // tri-packed Q/16, rows 0..7
    __shared__ __align__(16) float sPV[4*12];
    __shared__ float sRP[64*9];
    __shared__ __align__(16) float sG67[16*20];
    __shared__ float sA2[10], sC2[10];
    int t = threadIdx.x;
    for (int i = t; i < 120; i += 64) sQm[i] = ws[QM_OFF + i];
    if (t < 36){
        int i = 0;
        #pragma unroll
        for (int r = 1; r < 8; ++r) if (TIX(r,0) <= t) i = r;
        int j = t - TIX(i,0);
        sQt[t] = ws[QM_OFF + i*12 + j] * (1.0f/16.0f);
    }
    if (t < 10){   // BN2 finalize (redundant per block — 320 loads, trivial)
        float ssum = 0.0f, qsum = 0.0f;
        #pragma unroll
        for (int b = 0; b < 16; ++b){
            ssum += ws[P2_OFF + b*20 + t];
            qsum += ws[P2_OFF + b*20 + 10 + t];
        }
        float mu  = ssum * (1.0f/16384.0f);
        float var = qsum * (1.0f/16384.0f) - mu*mu;
        float a2 = g2v[t] / sqrtf(var + BNEPS);
        sA2[t] = a2;
        sC2[t] = bb2[t] - mu * a2;
    }
    __syncthreads();

    int lg = t & 15;
    int eidx = t >> 4;
    int elem = blockIdx.x * 4 + eidx;
    const float* GB = ws + G_OFF;
    float* sRPp = sRP + t * 9;
    const float4* sQm4 = (const float4*)sQm;
    const float4* sQt4 = (const float4*)sQt;

    if (t < 40){
        int e = t / 10, i = t - e*10;
        int el = blockIdx.x * 4 + e;
        sPV[e*12 + i] = fmaf(ws[PRAW_OFF + (size_t)el*10 + i], sA2[i], sC2[i]);
    }
    if (t < 16){
        #pragma unroll
        for (int i = 0; i < 8; ++i) sG67[t*20 + i]     = GB[(10 + 96 + t)*12 + i];
        #pragma unroll
        for (int i = 0; i < 8; ++i) sG67[t*20 + 8 + i] = GB[(10 + 112 + t)*12 + i];
    }
    float g0[2], g1[2], g2r[4], g3[4], g4[6], g5[6];
    float hh[8];
    {
        int c = 10 + lg;   LDG(g0, c, 2);  hh[0] = ws[H_OFF + c];
        c = 10 + 16 + lg;  LDG(g1, c, 2);  hh[1] = ws[H_OFF + c];
        c = 10 + 32 + lg;  LDG(g2r, c, 4); hh[2] = ws[H_OFF + c];
        c = 10 + 48 + lg;  LDG(g3, c, 4);  hh[3] = ws[H_OFF + c];
        c = 10 + 64 + lg;  LDG(g4, c, 6);  hh[4] = ws[H_OFF + c];
        c = 10 + 80 + lg;  LDG(g5, c, 6);  hh[5] = ws[H_OFF + c];
        hh[6] = ws[H_OFF + 10 + 96 + lg];
        hh[7] = ws[H_OFF + 10 + 112 + lg];
    }
    float h8 = (lg < 10) ? ws[H_OFF + lg] : 1.0f;
    __syncthreads();

    float z[10];
    #pragma unroll
    for (int i = 0; i < 10; ++i) z[i] = 0.0f;
    float s[9], lam[9];
    #pragma unroll
    for (int k = 0; k < 9; ++k){ s[k] = 1.0f; lam[k] = 1.0f; }
    lam[8] = (lg < 10) ? 1.0f : 0.0f;

    #pragma unroll 1
    for (int it = 0; it < ITERS; ++it){
        float Hm[55], sl = 0.0f, rp8;
        // pre-init rows 0..7 with Q/16 (butterfly over 16 lanes restores Q)
        #pragma unroll
        for (int i = 0; i < 9; ++i){
            float4 v = sQt4[i];
            Hm[4*i] = v.x; Hm[4*i+1] = v.y; Hm[4*i+2] = v.z; Hm[4*i+3] = v.w;
        }
        // ---- loop A (B_hat rows, compile-time col bounds)
        STEPA(0, 2, g0)  STEPA(1, 2, g1)
        STEPA(2, 4, g2r) STEPA(3, 4, g3)
        STEPA(4, 6, g4)  STEPA(5, 6, g5)
        { LOAD_G6(g6v) STEPA(6, 8, g6v) }
        { LOAD_G7(g7v) STEPA(7, 8, g7v) }
        // ---- identity row (slot 8)
        float zs = z[0];
        #pragma unroll
        for (int i = 1; i < 10; ++i) zs = (lg == i) ? z[i] : zs;
        float w8;
        {
            float sk = s[8], lk = lam[8];
            rp8 = zs + sk - h8;
            sl = fmaf(sk, lk, sl);
            w8 = lk * frcp(sk);
        }
        // ---- fold identity diag contributions pre-reduce
        #pragma unroll
        for (int i = 0; i < 8; ++i) Hm[TIX(i,i)] += (lg == i) ? w8 : 0.0f;
        float d88 = (lg == 8) ? w8 : 0.0f;
        float d99 = (lg == 9) ? w8 : 0.0f;
        // ---- DPP all-reduce
        #pragma unroll
        for (int i = 0; i < 36; ++i) Hm[i] = red16_add(Hm[i]);
        d88 = red16_add(d88);
        d99 = red16_add(d99);
        sl = red16_add(sl);
        float smu = SIGMA_C * sl * (1.0f/138.0f);
        __asm__ __volatile__("" ::: "memory");   // keep g6/g7 transient
        // ---- loop B: racc = sum_k g_k*(lam_k*rp_k+smu)/s_k  (includes old lamG)
        float racc[8];
        #pragma unroll
        for (int i = 0; i < 8; ++i) racc[i] = 0.0f;
        STEPB(0, 2, g0)  STEPB(1, 2, g1)
        STEPB(2, 4, g2r) STEPB(3, 4, g3)
        STEPB(4, 6, g4)  STEPB(5, 6, g5)
        { LOAD_G6(g6v) STEPB(6, 8, g6v) }
        { LOAD_G7(g7v) STEPB(7, 8, g7v) }
        float coef8;
        {
            float sk = s[8], lk = lam[8];
            float isk = frcp(sk);
            coef8 = isk * fmaf(lk, rp8, smu);
            coef8 = (lg < 10) ? coef8 : 0.0f;
        }
        #pragma unroll
        for (int i = 0; i < 8; ++i) racc[i] += (lg == i) ? coef8 : 0.0f;
        float racc8 = (lg == 8) ? coef8 : 0.0f;
        float racc9 = (lg == 9) ? coef8 : 0.0f;
        #pragma unroll
        for (int i = 0; i < 8; ++i) racc[i] = red16_add(racc[i]);
        racc8 = red16_add(racc8); racc9 = red16_add(racc9);
        // ---- rhs base = -(p + racc); Q-pass subtracts Qz; rows 8,9 of H assigned
        float rhs[10];
        {
            const float4* pv4 = (const float4*)(sPV + eidx*12);
            float4 pa = pv4[0], pb = pv4[1];
            const float2* pv2 = (const float2*)(sPV + eidx*12 + 8);
            float2 pc = pv2[0];
            rhs[0] = -(pa.x + racc[0]); rhs[1] = -(pa.y + racc[1]);
            rhs[2] = -(pa.z + racc[2]); rhs[3] = -(pa.w + racc[3]);
            rhs[4] = -(pb.x + racc[4]); rhs[5] = -(pb.y + racc[5]);
            rhs[6] = -(pb.z + racc[6]); rhs[7] = -(pb.w + racc[7]);
            rhs[8] = -(pc.x + racc8);   rhs[9] = -(pc.y + racc9);
        }
        #pragma unroll
        for (int j = 0; j < 10; ++j){
            float4 qa = sQm4[j*3+0], qb = sQm4[j*3+1], qc = sQm4[j*3+2];
            float q[10] = {qa.x,qa.y,qa.z,qa.w, qb.x,qb.y,qb.z,qb.w, qc.x,qc.y};
            float zj = z[j];
            #pragma unroll
            for (int i = 0; i < 10; ++i) rhs[i] = fmaf(-zj, q[i], rhs[i]);
            if (j >= 8){
                #pragma unroll
                for (int i = 0; i <= j; ++i) Hm[TIX(j,i)] = q[i];
            }
        }
        Hm[TIX(8,8)] += d88;
        Hm[TIX(9,9)] += d99;
        // ---- Cholesky (reciprocal diag in place)
        #pragma unroll
        for (int j = 0; j < 10; ++j){
            float d = Hm[TIX(j,j)];
            #pragma unroll
            for (int k2 = 0; k2 < j; ++k2){ float v = Hm[TIX(j,k2)]; d = fmaf(-v, v, d); }
            d = fmaxf(d, 1e-30f);
            float rinv = frsq(d);
            Hm[TIX(j,j)] = rinv;
            #pragma unroll
            for (int i = j+1; i < 10; ++i){
                float v2 = Hm[TIX(i,j)];
                #pragma unroll
                for (int k2 = 0; k2 < j; ++k2) v2 = fmaf(-Hm[TIX(i,k2)], Hm[TIX(j,k2)], v2);
                Hm[TIX(i,j)] = v2 * rinv;
            }
        }
        #pragma unroll
        for (int i = 0; i < 10; ++i){
            float v2 = rhs[i];
            #pragma unroll
            for (int k2 = 0; k2 < i; ++k2) v2 = fmaf(-Hm[TIX(i,k2)], rhs[k2], v2);
            rhs[i] = v2 * Hm[TIX(i,i)];
        }
        float dz[10];
        #pragma unroll
        for (int i = 9; i >= 0; --i){
            float v2 = rhs[i];
            #pragma unroll
            for (int k2 = i+1; k2 < 10; ++k2) v2 = fmaf(-Hm[TIX(k2,i)], dz[k2], v2);
            dz[i] = v2 * Hm[TIX(i,i)];
        }
        __asm__ __volatile__("" ::: "memory");
        // ---- loop C: steps + alpha (max-of-inverse-ratios)
        float ds_[9], dl_[9];
        float ainv = 0.0f;
        STEPC(0, 2, g0)  STEPC(1, 2, g1)
        STEPC(2, 4, g2r) STEPC(3, 4, g3)
        STEPC(4, 6, g4)  STEPC(5, 6, g5)
        { LOAD_G6(g6v) STEPC(6, 8, g6v) }
        { LOAD_G7(g7v) STEPC(7, 8, g7v) }
        {
            float dzs = dz[0];
            #pragma unroll
            for (int i = 1; i < 10; ++i) dzs = (lg == i) ? dz[i] : dzs;
            bool val = lg < 10;
            float dsk = val ? (-rp8 - dzs) : 0.0f;
            float sk = s[8], lk = lam[8];
            float isk = frcp(sk);
            float rc = fmaf(sk, lk, -smu);
            float dlk = -(rc + lk * dsk) * isk;
            dlk = val ? dlk : 0.0f;
            ds_[8] = dsk; dl_[8] = dlk;
            float cand = fmaxf(-dsk * isk, -dlk * frcp(lk));
            ainv = fmaxf(ainv, val ? cand : 0.0f);
        }
        ainv = red16_max(ainv);
        float alpha = fminf(1.0f, 0.99f * frcp(fmaxf(ainv, 1e-30f)));
        // ---- updates
        #pragma unroll
        for (int i = 0; i < 10; ++i) z[i] = fmaf(alpha, dz[i], z[i]);
        #pragma unroll
        for (int k = 0; k < 9; ++k){
            s[k]   = fmaf(alpha, ds_[k], s[k]);
            lam[k] = fmaf(alpha, dl_[k], lam[k]);
        }
    }
    if (lg == 0) out[elem] = z[0];
}

extern "C" void kernel_launch(void* const* d_in, const int* in_sizes, int n_in,
                              void* d_out, int out_size, void* d_ws, size_t ws_size,
                              hipStream_t stream){
    const float* x   = (const float*)d_in[0];
    const float* w1  = (const float*)d_in[1];
    const float* b1  = (const float*)d_in[2];
    const float* w2  = (const float*)d_in[3];
    const float* b2  = (const float*)d_in[4];
    const float* g1  = (const float*)d_in[5];
    const float* bb1 = (const float*)d_in[6];
    const float* g2  = (const float*)d_in[7];
    const float* bb2 = (const float*)d_in[8];
    const float* L   = (const float*)d_in[9];
    const float* LP  = (const float*)d_in[10];
    const float* LR  = (const float*)d_in[11];
    const float* A   = (const float*)d_in[12];
    const float* Bm  = (const float*)d_in[13];
    const float* u0  = (const float*)d_in[14];
    const float* s0  = (const float*)d_in[15];
    float* ws  = (float*)d_ws;
    float* out = (float*)d_out;

    // zero P2 + P1 partial accumulators (floats 2048..10560)
    hipMemsetAsync(ws + P2_OFF, 0, (P1Q_OFF + 4096 - P2_OFF) * sizeof(float), stream);
    hipLaunchKernelGGL(k_buildstats, dim3(513), dim3(256), 0, stream,
                       L, LP, LR, A, Bm, u0, s0, x, w1, b1, ws);
    hipLaunchKernelGGL(k_fc2, dim3(256), dim3(512), 0, stream, x, w1, w2, b1, b2, g1, bb1, ws);
    hipLaunchKernelGGL(k_ipm, dim3(4096), dim3(64), 0, stream, ws, g2, bb2, out);
}

// Round 10
// 457.199 us; speedup vs baseline: 4.4428x; 1.1212x over previous
//
#include <hip/hip_runtime.h>
#include <math.h>

#define NIx 32
#define NOx 2
#define NUx 10
#define NHx 1024
#define NBx 16384
#define MIx 138
#define EPSQ 1e-4f
#define BNEPS 1e-5f
#define ITERS 30
#define SLOPE 0.2f
#define SIGMA_C 0.1f

// workspace layout (float offsets). Max = 174400 floats = 697.6 KB (< proven 723 KB).
#define QM_OFF 0        // 120 (pad 128)
#define G_OFF 128       // 144 x 12 -> 1856
#define H_OFF 1856      // 144 (pad 2048)
#define P2_OFF 2048     // 16 bufs x 20 (sum[10],sq[10]) = 320 (pad 2368)
#define P1S_OFF 2368    // 4 bufs x 1024 col-sums
#define P1Q_OFF 6464    // 4 bufs x 1024 col-sumsq -> 10560
#define PRAW_OFF 10560  // 16384 x 10 -> 174400
// memset zeroes [P2_OFF, P1Q_OFF+4096) = floats 2048..10560

__device__ __forceinline__ float frcp(float x){ return __builtin_amdgcn_rcpf(x); }
__device__ __forceinline__ float frsq(float x){ return __builtin_amdgcn_rsqf(x); }
__device__ __forceinline__ float lrelu(float x){ return x > 0.0f ? x : SLOPE * x; }

// ---- DPP cross-lane reductions (VALU, no LDS pipe) ----
template<int CTRL>
__device__ __forceinline__ float dpp_mov(float x){
    int y = __builtin_amdgcn_update_dpp(0, __float_as_int(x), CTRL, 0xF, 0xF, true);
    return __int_as_float(y);
}
// 8-lane all-reduce: xor1 (quad_perm[1,0,3,2]), xor2 (quad_perm[2,3,0,1]),
// then row_half_mirror (0x141: i -> 7-i within each 8 = xor-7) closes the group.
__device__ __forceinline__ float red8_add(float x){
    x += dpp_mov<0xB1>(x);
    x += dpp_mov<0x4E>(x);
    x += dpp_mov<0x141>(x);
    return x;
}
__device__ __forceinline__ float red8_max(float x){
    x = fmaxf(x, dpp_mov<0xB1>(x));
    x = fmaxf(x, dpp_mov<0x4E>(x));
    x = fmaxf(x, dpp_mov<0x141>(x));
    return x;
}

// ---------- merged: blocks 0..511 BN1-stats, block 512 QP-build (independent work) ----------
__global__ __launch_bounds__(256) void k_buildstats(const float* L, const float* LP, const float* LR,
                                                    const float* A, const float* Bm,
                                                    const float* u0, const float* s0,
                                                    const float* x, const float* w1, const float* b1,
                                                    float* ws){
    __shared__ float sL[1024], sLP[1024], sA[1024], sQ[1024], sP[1024];
    __shared__ float sPow[4][64];
    __shared__ float sBh[128*10];
    __shared__ float sQB[128*10];
    __shared__ float sR[3];
    int t = threadIdx.x;
    if (blockIdx.x < 512){
        // ---- BN1 stats path: partial col sum/sumsq into 4 spread buffers ----
        int rb = blockIdx.x >> 2;        // 128 row-groups of 128 rows
        int cb = blockIdx.x & 3;         // 4 col-groups of 256 cols
        int c = cb * 256 + t;
        const float4* wg4 = (const float4*)(w1 + (size_t)c * 32);
        float4 wr[8];
        #pragma unroll
        for (int q = 0; q < 8; ++q) wr[q] = wg4[q];
        float bc = b1[c];
        int r0 = rb * 128;
        float sum = 0.0f, sq = 0.0f;
        #pragma unroll 2
        for (int r = 0; r < 128; ++r){
            const float4* xr4 = (const float4*)(x + (size_t)(r0 + r) * 32);
            float a0 = 0, a1 = 0, a2 = 0, a3 = 0;
            #pragma unroll
            for (int q = 0; q < 8; ++q){
                float4 v = xr4[q];
                a0 = fmaf(v.x, wr[q].x, a0);
                a1 = fmaf(v.y, wr[q].y, a1);
                a2 = fmaf(v.z, wr[q].z, a2);
                a3 = fmaf(v.w, wr[q].w, a3);
            }
            float h = lrelu((a0 + a1) + (a2 + a3) + bc);
            sum += h; sq = fmaf(h, h, sq);
        }
        int buf = (rb & 3) * 1024 + c;
        atomicAdd(&ws[P1S_OFF + buf], sum);
        atomicAdd(&ws[P1Q_OFF + buf], sq);
        return;
    }
    // ---- QP build path (single block) ----
    for (int idx = t; idx < 1024; idx += 256){
        int i = idx >> 5, j = idx & 31;
        sL[idx]  = (j <= i) ? L[idx]  : 0.0f;
        sLP[idx] = (j <= i) ? LP[idx] : 0.0f;
        sA[idx]  = A[idx];
    }
    if (t < 64) sPow[0][t] = Bm[t];
    if (t == 0){
        float a = LR[0], b = LR[2], c = LR[3];   // tril: [[a,0],[b,c]]
        sR[0] = a*a + EPSQ; sR[1] = a*b; sR[2] = b*b + c*c + EPSQ;
    }
    __syncthreads();
    for (int idx = t; idx < 1024; idx += 256){
        int i = idx >> 5, j = idx & 31;
        float q = 0.0f, p = 0.0f;
        for (int k = 0; k < 32; ++k){
            q = fmaf(sL[i*32+k],  sL[j*32+k],  q);
            p = fmaf(sLP[i*32+k], sLP[j*32+k], p);
        }
        if (i == j){ q += EPSQ; p += EPSQ; }
        sQ[idx] = q; sP[idx] = p;
    }
    for (int kp = 1; kp < 4; ++kp){
        __syncthreads();
        if (t < 64){
            int i = t >> 1, c = t & 1;
            float a = 0.0f;
            for (int j = 0; j < 32; ++j) a = fmaf(sA[i*32+j], sPow[kp-1][j*2+c], a);
            sPow[kp][t] = a;
        }
    }
    __syncthreads();
    for (int idx = t; idx < 1280; idx += 256){
        int r = idx / 10, c = idx % 10;
        int bi = r >> 5, ri = r & 31, bj = c >> 1, cj = c & 1;
        sBh[idx] = (bj <= bi) ? sPow[bi-bj][ri*2+cj] : 0.0f;
    }
    __syncthreads();
    for (int idx = t; idx < 1280; idx += 256){
        int r = idx / 10, c = idx % 10;
        int bi = r >> 5, ri = r & 31;
        const float* Qd = (bi < 3) ? sQ : sP;
        float a = 0.0f;
        for (int k = 0; k < 32; ++k) a = fmaf(Qd[ri*32+k], sBh[(bi*32+k)*10+c], a);
        sQB[idx] = a;
    }
    __syncthreads();
    if (t < 120){
        int i = t / 12, j = t % 12;
        float a = 0.0f;
        if (j < 10){
            for (int r = 0; r < 128; ++r) a = fmaf(sBh[r*10+i], sQB[r*10+j], a);
            if ((i >> 1) == (j >> 1)) a += sR[(i&1)+(j&1)];
        }
        ws[QM_OFF + t] = a;
    }
    for (int idx = t; idx < 144*12; idx += 256){
        int m = idx / 12, i = idx % 12;
        float v = 0.0f;
        if (i < 10 && m < MIx) v = (m < 10) ? ((i == m) ? 1.0f : 0.0f) : sBh[(m-10)*10 + i];
        ws[G_OFF + idx] = v;
    }
    for (int m = t; m < 144; m += 256){
        float hv = 0.0f;
        if (m < MIx){
            hv = s0[m];
            if (m < 10) hv += u0[m];
            else { for (int i = 0; i < 10; ++i) hv = fmaf(sBh[(m-10)*10+i], u0[i], hv); }
        }
        ws[H_OFF + m] = hv;
    }
}

// ---------- fc2 with BN1-finalize folded in-block ----------
__global__ __launch_bounds__(512) void k_fc2(const float* x, const float* w1, const float* w2,
                                             const float* b1v, const float* b2v,
                                             const float* g1, const float* bb1, float* ws){
    __shared__ float sA1[1024], sC1[1024];
    __shared__ float pacc[512*10];   // 20 KB
    int t = threadIdx.x;
    #pragma unroll
    for (int k = t; k < 1024; k += 512){
        float ssum = 0.0f, qsum = 0.0f;
        #pragma unroll
        for (int b = 0; b < 4; ++b){
            ssum += ws[P1S_OFF + b*1024 + k];
            qsum += ws[P1Q_OFF + b*1024 + k];
        }
        float mu  = ssum * (1.0f/16384.0f);
        float var = qsum * (1.0f/16384.0f) - mu*mu;
        float a1 = g1[k] / sqrtf(var + BNEPS);
        sA1[k] = a1;
        sC1[k] = bb1[k] - mu * a1;
    }
    int r = t & 63;
    int q = t >> 6;                  // 0..7: wave owns k-eighth
    int row = blockIdx.x * 64 + r;
    const float4* xg4 = (const float4*)(x + (size_t)row * 32);
    float4 xr[8];
    #pragma unroll
    for (int i = 0; i < 8; ++i) xr[i] = xg4[i];
    float acc[10];
    #pragma unroll
    for (int j = 0; j < 10; ++j) acc[j] = 0.0f;
    const float4* w1g = (const float4*)w1;
    __syncthreads();
    #pragma unroll 2
    for (int kk = 0; kk < 128; ++kk){
        int kl = q*128 + kk;         // wave-uniform
        float a0 = 0, a1 = 0, a2 = 0, a3 = 0;
        #pragma unroll
        for (int i = 0; i < 8; ++i){
            float4 wv = w1g[kl*8 + i];
            float4 xv = xr[i];
            a0 = fmaf(xv.x, wv.x, a0);
            a1 = fmaf(xv.y, wv.y, a1);
            a2 = fmaf(xv.z, wv.z, a2);
            a3 = fmaf(xv.w, wv.w, a3);
        }
        float h = fmaf(lrelu((a0 + a1) + (a2 + a3) + b1v[kl]), sA1[kl], sC1[kl]);
        #pragma unroll
        for (int j = 0; j < 10; ++j) acc[j] = fmaf(h, w2[j*1024 + kl], acc[j]);
    }
    #pragma unroll
    for (int j = 0; j < 10; ++j) pacc[t*10 + j] = acc[j];
    __syncthreads();
    if (t < 64){
        float pv[10];
        #pragma unroll
        for (int j = 0; j < 10; ++j){
            float a = b2v[j];
            #pragma unroll
            for (int w = 0; w < 8; ++w) a += pacc[(w*64 + t)*10 + j];
            pv[j] = lrelu(a);
        }
        #pragma unroll
        for (int j = 0; j < 10; ++j) ws[PRAW_OFF + (size_t)(blockIdx.x*64 + t)*10 + j] = pv[j];
        float sv[10], qv[10];
        #pragma unroll
        for (int j = 0; j < 10; ++j){ sv[j] = pv[j]; qv[j] = pv[j]*pv[j]; }
        #pragma unroll
        for (int m = 1; m < 64; m <<= 1){
            #pragma unroll
            for (int j = 0; j < 10; ++j){
                sv[j] += __shfl_xor(sv[j], m);
                qv[j] += __shfl_xor(qv[j], m);
            }
        }
        if (t == 0){
            int base = P2_OFF + (blockIdx.x & 15) * 20;
            #pragma unroll
            for (int j = 0; j < 10; ++j){
                atomicAdd(&ws[base + j], sv[j]);
                atomicAdd(&ws[base + 10 + j], qv[j]);
            }
        }
    }
}

// ---------- batched IPM: 8 lanes/element, 8 elements per 64-thread block ----------
// Round-10 restructure: shared per-element work (Cholesky/solves/Q-pass, ~500 inst)
// was replicated 16x per element; with L=8 its per-element tax halves. Slot map:
//   slots 0..15: B_hat block b=k>>2 (col bound 2(b+1)), row = 10 + b*32 + (k&3)*8 + lg.
//   slot 16: identity row lg (all 8 lanes, rows 0..7); slot 17: rows 8,9 on lanes 0,1.
// Blocks 0,1 of G in regs (24 f); blocks 2,3 in LDS (lg-indexed, stride 68 floats ->
// b128 phases cover all 32 banks, 8-way same-address broadcast). Butterfly = 3 DPP
// steps (xor1, xor2, row_half_mirror). Hm rows 0..7 pre-init with Q/8.
#define TIX(i,j) ((i)*((i)+1)/2 + (j))

#define STEPA(K, B, g) { \
    float sk = s[K], lk = lam[K]; \
    float isk = frcp(sk); \
    float r = sk - hhp[(K)*8]; \
    float w = lk * isk; \
    sl = fmaf(sk, lk, sl); \
    _Pragma("unroll") \
    for (int i = 0; i < B; ++i) r = fmaf(z[i], g[i], r); \
    sRPp[K] = r; \
    _Pragma("unroll") \
    for (int i = 0; i < B; ++i){ \
        float wgi = w * g[i]; \
        _Pragma("unroll") \
        for (int j = 0; j <= i; ++j) Hm[TIX(i,j)] = fmaf(wgi, g[j], Hm[TIX(i,j)]); \
    } }

#define STEPB(K, B, g) { \
    float rpk = sRPp[K]; \
    float sk = s[K], lk = lam[K]; \
    float isk = frcp(sk); \
    float coef = isk * fmaf(lk, rpk, smu); \
    _Pragma("unroll") \
    for (int i = 0; i < B; ++i) racc[i] = fmaf(coef, g[i], racc[i]); }

#define STEPC(K, B, g) { \
    float rpk = sRPp[K]; \
    float dot = 0.0f; \
    _Pragma("unroll") \
    for (int i = 0; i < B; ++i) dot = fmaf(dz[i], g[i], dot); \
    float dsk = -rpk - dot; \
    float sk = s[K], lk = lam[K]; \
    float isk = frcp(sk); \
    float rc = fmaf(sk, lk, -smu); \
    float dlk = -(rc + lk * dsk) * isk; \
    ds_[K] = dsk; dl_[K] = dlk; \
    float ilk = frcp(lk); \
    ainv = fmaxf(ainv, fmaxf(-dsk * isk, -dlk * ilk)); }

#define LDG(g, c, B) { _Pragma("unroll") for (int i = 0; i < B; ++i) g[i] = GB[(c)*12 + i]; }

#define LOAD_B2(arr, r) float arr[8]; { const float4* _gq = (const float4*)(sG23 + lg*68 + (r)*8); \
    float4 _a = _gq[0], _b = _gq[1]; \
    arr[0]=_a.x; arr[1]=_a.y; arr[2]=_a.z; arr[3]=_a.w; arr[4]=_b.x; arr[5]=_b.y; arr[6]=_b.z; arr[7]=_b.w; }
#define LOAD_B3(arr, r) float arr[8]; { const float4* _gq = (const float4*)(sG23 + lg*68 + 32 + (r)*8); \
    float4 _a = _gq[0], _b = _gq[1]; \
    arr[0]=_a.x; arr[1]=_a.y; arr[2]=_a.z; arr[3]=_a.w; arr[4]=_b.x; arr[5]=_b.y; arr[6]=_b.z; arr[7]=_b.w; }

__global__ __launch_bounds__(64) void k_ipm(const float* ws, const float* g2v, const float* bb2, float* out){
    __shared__ __align__(16) float sQm[120];
    __shared__ __align__(16) float sQt[36];     // tri-packed Q/8, rows 0..7
    __shared__ __align__(16) float sPV[8*12];
    __shared__ float sRP[64*19];                // rp, stride 19 (2-way max alias)
    __shared__ __align__(16) float sG23[8*68];  // G blocks 2,3 by lg
    __shared__ float sHH[128];                  // h for B_hat slots: sHH[k*8+lg]
    __shared__ float sA2[10], sC2[10];
    int t = threadIdx.x;
    for (int i = t; i < 120; i += 64) sQm[i] = ws[QM_OFF + i];
    if (t < 36){
        int i = 0;
        #pragma unroll
        for (int r = 1; r < 8; ++r) if (TIX(r,0) <= t) i = r;
        int j = t - TIX(i,0);
        sQt[t] = ws[QM_OFF + i*12 + j] * (1.0f/8.0f);
    }
    if (t < 10){   // BN2 finalize (redundant per block — trivial)
        float ssum = 0.0f, qsum = 0.0f;
        #pragma unroll
        for (int b = 0; b < 16; ++b){
            ssum += ws[P2_OFF + b*20 + t];
            qsum += ws[P2_OFF + b*20 + 10 + t];
        }
        float mu  = ssum * (1.0f/16384.0f);
        float var = qsum * (1.0f/16384.0f) - mu*mu;
        float a2 = g2v[t] / sqrtf(var + BNEPS);
        sA2[t] = a2;
        sC2[t] = bb2[t] - mu * a2;
    }
    __syncthreads();

    int lg = t & 7;
    int eidx = t >> 3;
    int elem = blockIdx.x * 8 + eidx;
    const float* GB = ws + G_OFF;
    const float* hhp = sHH + lg;
    float* sRPp = sRP + t * 19;
    const float4* sQm4 = (const float4*)sQm;
    const float4* sQt4 = (const float4*)sQt;

    for (int i = t; i < 80; i += 64){
        int e = i / 10, c = i - e*10;
        int el = blockIdx.x * 8 + e;
        sPV[e*12 + c] = fmaf(ws[PRAW_OFF + (size_t)el*10 + c], sA2[c], sC2[c]);
    }
    for (int i = t; i < 128; i += 64){
        int sslot = i >> 3, l = i & 7;
        int row = 10 + (sslot >> 2)*32 + (sslot & 3)*8 + l;
        sHH[i] = ws[H_OFF + row];
    }
    if (t < 8){
        #pragma unroll
        for (int r = 0; r < 4; ++r){
            #pragma unroll
            for (int i = 0; i < 6; ++i) sG23[t*68 + r*8 + i] = GB[(10 + 64 + r*8 + t)*12 + i];
            sG23[t*68 + r*8 + 6] = 0.0f; sG23[t*68 + r*8 + 7] = 0.0f;
            #pragma unroll
            for (int i = 0; i < 8; ++i) sG23[t*68 + 32 + r*8 + i] = GB[(10 + 96 + r*8 + t)*12 + i];
        }
    }
    // G blocks 0,1 in registers
    float g00[2], g01[2], g02[2], g03[2];
    float g10[4], g11[4], g12[4], g13[4];
    {
        int c = 10 + lg;        LDG(g00, c, 2);
        c = 10 + 8 + lg;        LDG(g01, c, 2);
        c = 10 + 16 + lg;       LDG(g02, c, 2);
        c = 10 + 24 + lg;       LDG(g03, c, 2);
        c = 10 + 32 + lg;       LDG(g10, c, 4);
        c = 10 + 40 + lg;       LDG(g11, c, 4);
        c = 10 + 48 + lg;       LDG(g12, c, 4);
        c = 10 + 56 + lg;       LDG(g13, c, 4);
    }
    float h16 = ws[H_OFF + lg];                          // identity rows 0..7
    float h17 = (lg < 2) ? ws[H_OFF + 8 + lg] : 1.0f;    // identity rows 8,9
    __syncthreads();

    float z[10];
    #pragma unroll
    for (int i = 0; i < 10; ++i) z[i] = 0.0f;
    float s[18], lam[18];
    #pragma unroll
    for (int k = 0; k < 18; ++k){ s[k] = 1.0f; lam[k] = 1.0f; }
    lam[17] = (lg < 2) ? 1.0f : 0.0f;

    #pragma unroll 1
    for (int it = 0; it < ITERS; ++it){
        float Hm[55], sl = 0.0f, rp16, rp17;
        // pre-init rows 0..7 with Q/8 (8-lane butterfly restores Q)
        #pragma unroll
        for (int i = 0; i < 9; ++i){
            float4 v = sQt4[i];
            Hm[4*i] = v.x; Hm[4*i+1] = v.y; Hm[4*i+2] = v.z; Hm[4*i+3] = v.w;
        }
        // ---- loop A
        STEPA(0, 2, g00)  STEPA(1, 2, g01)  STEPA(2, 2, g02)  STEPA(3, 2, g03)
        STEPA(4, 4, g10)  STEPA(5, 4, g11)  STEPA(6, 4, g12)  STEPA(7, 4, g13)
        { LOAD_B2(gv, 0) STEPA(8, 6, gv) }  { LOAD_B2(gv, 1) STEPA(9, 6, gv) }
        { LOAD_B2(gv, 2) STEPA(10, 6, gv) } { LOAD_B2(gv, 3) STEPA(11, 6, gv) }
        { LOAD_B3(gv, 0) STEPA(12, 8, gv) } { LOAD_B3(gv, 1) STEPA(13, 8, gv) }
        { LOAD_B3(gv, 2) STEPA(14, 8, gv) } { LOAD_B3(gv, 3) STEPA(15, 8, gv) }
        // ---- identity slots 16 (rows 0..7) and 17 (rows 8,9 on lanes 0,1)
        float zs = z[0];
        #pragma unroll
        for (int i = 1; i < 8; ++i) zs = (lg == i) ? z[i] : zs;
        float zs17 = (lg == 1) ? z[9] : z[8];
        float w16, w17;
        {
            float sk = s[16], lk = lam[16];
            rp16 = zs + sk - h16;
            sl = fmaf(sk, lk, sl);
            w16 = lk * frcp(sk);
        }
        {
            float sk = s[17], lk = lam[17];
            rp17 = zs17 + sk - h17;
            sl = fmaf(sk, lk, sl);
            w17 = lk * frcp(sk);
        }
        #pragma unroll
        for (int i = 0; i < 8; ++i) Hm[TIX(i,i)] += (lg == i) ? w16 : 0.0f;
        float d88 = (lg == 0) ? w17 : 0.0f;
        float d99 = (lg == 1) ? w17 : 0.0f;
        // ---- DPP 8-lane all-reduce
        #pragma unroll
        for (int i = 0; i < 36; ++i) Hm[i] = red8_add(Hm[i]);
        d88 = red8_add(d88);
        d99 = red8_add(d99);
        sl = red8_add(sl);
        float smu = SIGMA_C * sl * (1.0f/138.0f);
        __asm__ __volatile__("" ::: "memory");   // keep LDS G-rows transient
        // ---- loop B: racc = sum_k g_k*(lam_k*rp_k+smu)/s_k
        float racc[8];
        #pragma unroll
        for (int i = 0; i < 8; ++i) racc[i] = 0.0f;
        STEPB(0, 2, g00)  STEPB(1, 2, g01)  STEPB(2, 2, g02)  STEPB(3, 2, g03)
        STEPB(4, 4, g10)  STEPB(5, 4, g11)  STEPB(6, 4, g12)  STEPB(7, 4, g13)
        { LOAD_B2(gv, 0) STEPB(8, 6, gv) }  { LOAD_B2(gv, 1) STEPB(9, 6, gv) }
        { LOAD_B2(gv, 2) STEPB(10, 6, gv) } { LOAD_B2(gv, 3) STEPB(11, 6, gv) }
        { LOAD_B3(gv, 0) STEPB(12, 8, gv) } { LOAD_B3(gv, 1) STEPB(13, 8, gv) }
        { LOAD_B3(gv, 2) STEPB(14, 8, gv) } { LOAD_B3(gv, 3) STEPB(15, 8, gv) }
        float coef16 = frcp(s[16]) * fmaf(lam[16], rp16, smu);
        float coef17 = frcp(s[17]) * fmaf(lam[17], rp17, smu);
        coef17 = (lg < 2) ? coef17 : 0.0f;
        #pragma unroll
        for (int i = 0; i < 8; ++i) racc[i] += (lg == i) ? coef16 : 0.0f;
        float racc8 = (lg == 0) ? coef17 : 0.0f;
        float racc9 = (lg == 1) ? coef17 : 0.0f;
        #pragma unroll
        for (int i = 0; i < 8; ++i) racc[i] = red8_add(racc[i]);
        racc8 = red8_add(racc8); racc9 = red8_add(racc9);
        // ---- rhs base = -(p + racc); Q-pass subtracts Qz; rows 8,9 of H assigned
        float rhs[10];
        {
            const float4* pv4 = (const float4*)(sPV + eidx*12);
            float4 pa = pv4[0], pb = pv4[1];
            const float2* pv2 = (const float2*)(sPV + eidx*12 + 8);
            float2 pc = pv2[0];
            rhs[0] = -(pa.x + racc[0]); rhs[1] = -(pa.y + racc[1]);
            rhs[2] = -(pa.z + racc[2]); rhs[3] = -(pa.w + racc[3]);
            rhs[4] = -(pb.x + racc[4]); rhs[5] = -(pb.y + racc[5]);
            rhs[6] = -(pb.z + racc[6]); rhs[7] = -(pb.w + racc[7]);
            rhs[8] = -(pc.x + racc8);   rhs[9] = -(pc.y + racc9);
        }
        #pragma unroll
        for (int j = 0; j < 10; ++j){
            float4 qa = sQm4[j*3+0], qb = sQm4[j*3+1], qc = sQm4[j*3+2];
            float q[10] = {qa.x,qa.y,qa.z,qa.w, qb.x,qb.y,qb.z,qb.w, qc.x,qc.y};
            float zj = z[j];
            #pragma unroll
            for (int i = 0; i < 10; ++i) rhs[i] = fmaf(-zj, q[i], rhs[i]);
            if (j >= 8){
                #pragma unroll
                for (int i = 0; i <= j; ++i) Hm[TIX(j,i)] = q[i];
            }
        }
        Hm[TIX(8,8)] += d88;
        Hm[TIX(9,9)] += d99;
        // ---- Cholesky (reciprocal diag in place)
        #pragma unroll
        for (int j = 0; j < 10; ++j){
            float d = Hm[TIX(j,j)];
            #pragma unroll
            for (int k2 = 0; k2 < j; ++k2){ float v = Hm[TIX(j,k2)]; d = fmaf(-v, v, d); }
            d = fmaxf(d, 1e-30f);
            float rinv = frsq(d);
            Hm[TIX(j,j)] = rinv;
            #pragma unroll
            for (int i = j+1; i < 10; ++i){
                float v2 = Hm[TIX(i,j)];
                #pragma unroll
                for (int k2 = 0; k2 < j; ++k2) v2 = fmaf(-Hm[TIX(i,k2)], Hm[TIX(j,k2)], v2);
                Hm[TIX(i,j)] = v2 * rinv;
            }
        }
        #pragma unroll
        for (int i = 0; i < 10; ++i){
            float v2 = rhs[i];
            #pragma unroll
            for (int k2 = 0; k2 < i; ++k2) v2 = fmaf(-Hm[TIX(i,k2)], rhs[k2], v2);
            rhs[i] = v2 * Hm[TIX(i,i)];
        }
        float dz[10];
        #pragma unroll
        for (int i = 9; i >= 0; --i){
            float v2 = rhs[i];
            #pragma unroll
            for (int k2 = i+1; k2 < 10; ++k2) v2 = fmaf(-Hm[TIX(k2,i)], dz[k2], v2);
            dz[i] = v2 * Hm[TIX(i,i)];
        }
        __asm__ __volatile__("" ::: "memory");
        // ---- loop C: steps + alpha (max-of-inverse-ratios)
        float ds_[18], dl_[18];
        float ainv = 0.0f;
        STEPC(0, 2, g00)  STEPC(1, 2, g01)  STEPC(2, 2, g02)  STEPC(3, 2, g03)
        STEPC(4, 4, g10)  STEPC(5, 4, g11)  STEPC(6, 4, g12)  STEPC(7, 4, g13)
        { LOAD_B2(gv, 0) STEPC(8, 6, gv) }  { LOAD_B2(gv, 1) STEPC(9, 6, gv) }
        { LOAD_B2(gv, 2) STEPC(10, 6, gv) } { LOAD_B2(gv, 3) STEPC(11, 6, gv) }
        { LOAD_B3(gv, 0) STEPC(12, 8, gv) } { LOAD_B3(gv, 1) STEPC(13, 8, gv) }
        { LOAD_B3(gv, 2) STEPC(14, 8, gv) } { LOAD_B3(gv, 3) STEPC(15, 8, gv) }
        {
            float dzs = dz[0];
            #pragma unroll
            for (int i = 1; i < 8; ++i) dzs = (lg == i) ? dz[i] : dzs;
            float dsk = -rp16 - dzs;
            float sk = s[16], lk = lam[16];
            float isk = frcp(sk);
            float rc = fmaf(sk, lk, -smu);
            float dlk = -(rc + lk * dsk) * isk;
            ds_[16] = dsk; dl_[16] = dlk;
            ainv = fmaxf(ainv, fmaxf(-dsk * isk, -dlk * frcp(lk)));
        }
        {
            float dzs = (lg == 1) ? dz[9] : dz[8];
            bool val = lg < 2;
            float dsk = val ? (-rp17 - dzs) : 0.0f;
            float sk = s[17], lk = lam[17];
            float isk = frcp(sk);
            float rc = fmaf(sk, lk, -smu);
            float dlk = -(rc + lk * dsk) * isk;
            dlk = val ? dlk : 0.0f;
            ds_[17] = dsk; dl_[17] = dlk;
            float cand = fmaxf(-dsk * isk, -dlk * frcp(lk));
            ainv = fmaxf(ainv, val ? cand : 0.0f);
        }
        ainv = red8_max(ainv);
        float alpha = fminf(1.0f, 0.99f * frcp(fmaxf(ainv, 1e-30f)));
        // ---- updates
        #pragma unroll
        for (int i = 0; i < 10; ++i) z[i] = fmaf(alpha, dz[i], z[i]);
        #pragma unroll
        for (int k = 0; k < 18; ++k){
            s[k]   = fmaf(alpha, ds_[k], s[k]);
            lam[k] = fmaf(alpha, dl_[k], lam[k]);
        }
    }
    if (lg == 0) out[elem] = z[0];
}

extern "C" void kernel_launch(void* const* d_in, const int* in_sizes, int n_in,
                              void* d_out, int out_size, void* d_ws, size_t ws_size,
                              hipStream_t stream){
    const float* x   = (const float*)d_in[0];
    const float* w1  = (const float*)d_in[1];
    const float* b1  = (const float*)d_in[2];
    const float* w2  = (const float*)d_in[3];
    const float* b2  = (const float*)d_in[4];
    const float* g1  = (const float*)d_in[5];
    const float* bb1 = (const float*)d_in[6];
    const float* g2  = (const float*)d_in[7];
    const float* bb2 = (const float*)d_in[8];
    const float* L   = (const float*)d_in[9];
    const float* LP  = (const float*)d_in[10];
    const float* LR  = (const float*)d_in[11];
    const float* A   = (const float*)d_in[12];
    const float* Bm  = (const float*)d_in[13];
    const float* u0  = (const float*)d_in[14];
    const float* s0  = (const float*)d_in[15];
    float* ws  = (float*)d_ws;
    float* out = (float*)d_out;

    // zero P2 + P1 partial accumulators (floats 2048..10560)
    hipMemsetAsync(ws + P2_OFF, 0, (P1Q_OFF + 4096 - P2_OFF) * sizeof(float), stream);
    hipLaunchKernelGGL(k_buildstats, dim3(513), dim3(256), 0, stream,
                       L, LP, LR, A, Bm, u0, s0, x, w1, b1, ws);
    hipLaunchKernelGGL(k_fc2, dim3(256), dim3(512), 0, stream, x, w1, w2, b1, b2, g1, bb1, ws);
    hipLaunchKernelGGL(k_ipm, dim3(2048), dim3(64), 0, stream, ws, g2, bb2, out);
}